// Round 11
// baseline (534.638 us; speedup 1.0000x reference)
//
#include <hip/hip_runtime.h>
#include <hip/hip_bf16.h>

#define BDIM 4
#define VDIM 20000
#define DDIM 64
#define RDIM 64
#define EDIM 200000
#define BV (BDIM*VDIM)
#define LN_EPS 1e-5f
#define NBB 125           // kvred blocks per batch
#define NTILE 1250        // BV/64 row-tiles
#define NDB 625           // dense blocks per chain (2 tiles each)
#define NRB (VDIM/8)      // rspmm blocks per chain
#define NSC ((EDIM+255)/256)  // scatter blocks (782)

typedef __hip_bfloat16 bf16;
typedef __attribute__((ext_vector_type(8))) short short8v;
typedef __attribute__((ext_vector_type(4))) float floatx4;

__device__ __forceinline__ float ldf(const float* p, size_t i){ return p[i]; }
__device__ __forceinline__ float ldf(const bf16* p, size_t i){ return __bfloat162float(p[i]); }
__device__ __forceinline__ void stf(float* p, size_t i, float v){ p[i] = v; }
__device__ __forceinline__ void stf(bf16* p, size_t i, float v){ p[i] = __float2bfloat16(v); }

__device__ __forceinline__ unsigned short f2b(float f){
  unsigned u = __builtin_bit_cast(unsigned, f);
  u += 0x7fffu + ((u >> 16) & 1u);
  return (unsigned short)(u >> 16);
}
__device__ __forceinline__ float b2f(unsigned short h){
  unsigned u = ((unsigned)h) << 16;
  return __builtin_bit_cast(float, u);
}
__device__ __forceinline__ float4 ldf4(const float* p, size_t i){ return *(const float4*)(p+i); }
__device__ __forceinline__ float4 ldf4(const bf16* p, size_t i){
  ushort4 u = *(const ushort4*)(p+i);
  return make_float4(b2f(u.x), b2f(u.y), b2f(u.z), b2f(u.w));
}
// LDS tile swizzle: element index for [16][64] bf16 tile, 16B-unit XOR on row
__device__ __forceinline__ int swz(int r, int c){ return r*64 + (c ^ ((r & 7) << 3)); }

__device__ __forceinline__ float dot4(float4 a, float4 b){
  return a.x*b.x + a.y*b.y + a.z*b.z + a.w*b.w;
}

// Wave-private LDS ordering: DS ops from one wave execute in order; just fence compiler.
__device__ __forceinline__ void wsync(){
  __builtin_amdgcn_wave_barrier();
  __asm__ volatile("" ::: "memory");
}

__device__ __forceinline__ ushort4 packb(float4 v){
  ushort4 t; t.x = f2b(v.x); t.y = f2b(v.y); t.z = f2b(v.z); t.w = f2b(v.w); return t;
}

// ---- diagnostic fill ----
__global__ void fill_kernel(float* __restrict__ out, float v, int n){
  int t = blockIdx.x * 256 + threadIdx.x;
  if (t < n) out[t] = v;
}

// ---- setup: block 272 = detect64, blocks 0..79 = zero counts, 80..271 = zcalc ----
__global__ void setup_kernel(const int* __restrict__ ei_raw, int* __restrict__ flag,
                             int* __restrict__ counts,
                             const float* __restrict__ z,
                             const float* __restrict__ qkzw, const float* __restrict__ qkzb,
                             const float* __restrict__ vfw,  const float* __restrict__ vfb,
                             float* __restrict__ qk_z, float* __restrict__ zr){
  int bid = blockIdx.x, tid = threadIdx.x;
  if (bid == 272){
    int nz = 0;
    for (int j = 2*tid + 1; j < 1024; j += 512) nz |= (ei_raw[j] != 0);
    nz = __any(nz);
    __shared__ int r[4];
    if ((tid & 63) == 0) r[tid >> 6] = nz;
    __syncthreads();
    if (tid == 0) flag[0] = (r[0] | r[1] | r[2] | r[3]) ? 0 : 1;   // 1 => 64-bit
    return;
  }
  if (bid < 80){
    int i = bid*256 + tid;
    if (i < VDIM + 1) counts[i] = 0;
    return;
  }
  int idx = (bid - 80)*256 + tid;
  if (idx >= 49152) return;
  int which = idx >> 14;
  int r = idx & 16383;
  int b = r >> 12;
  int j = r & 4095;
  const float* wrow; float bias; float* outp;
  if (which == 0){ wrow = qkzw + (size_t)j*DDIM; bias = qkzb[j]; outp = qk_z; }
  else { int i = which - 1; wrow = vfw + (size_t)(i*4096 + j)*DDIM; bias = vfb[i*4096 + j]; outp = zr + i*16384; }
  const float4* zr4 = (const float4*)(z + (size_t)b*DDIM);
  const float4* wr4 = (const float4*)wrow;
  float acc = bias;
  #pragma unroll
  for (int i = 0; i < 16; i++) acc += dot4(zr4[i], wr4[i]);
  outp[r] = acc;
}

// ---- count directly from raw edges (is64-aware) + hi normalize ----
__global__ void prep_count_kernel(const int* __restrict__ ei_raw, const int* __restrict__ hi_raw,
                                  const int* __restrict__ flag,
                                  int* __restrict__ hi, int* __restrict__ counts){
  int is64 = flag[0];
  int e = blockIdx.x * 256 + threadIdx.x;
  if (e < EDIM){
    int dst = is64 ? ei_raw[6*e]   : ei_raw[3*e];
    int rel = is64 ? ei_raw[6*e+2] : ei_raw[3*e+1];
    int src = is64 ? ei_raw[6*e+4] : ei_raw[3*e+2];
    if ((unsigned)dst < VDIM && (unsigned)rel < RDIM && (unsigned)src < VDIM)
      atomicAdd(&counts[dst], 1);
  }
  if (e < BDIM) hi[e] = is64 ? hi_raw[2*e] : hi_raw[e];
}

// ---- scan: per-thread segments + one wave scan, 1 barrier total ----
__global__ void scan_kernel(const int* __restrict__ counts, int* __restrict__ row_ptr, int* __restrict__ cursor){
  __shared__ int wsum[4];
  int tid = threadIdx.x, lane = tid & 63, wid = tid >> 6;
  const int SEG = (VDIM + 255) / 256;        // 79
  int lo = tid * SEG;
  int hi = lo + SEG; if (hi > VDIM) hi = VDIM;
  int s = 0;
  for (int i = lo; i < hi; i++) s += counts[i];
  int x = s;
  #pragma unroll
  for (int o = 1; o < 64; o <<= 1){
    int t = __shfl_up(x, o, 64);
    if (lane >= o) x += t;
  }
  if (lane == 63) wsum[wid] = x;
  __syncthreads();
  int wo = 0;
  for (int w = 0; w < wid; w++) wo += wsum[w];
  int run = wo + x - s;                      // exclusive prefix of this thread's segment
  for (int i = lo; i < hi; i++){
    row_ptr[i] = run; cursor[i] = run; run += counts[i];
  }
  if (tid == 255) row_ptr[VDIM] = run;       // total
}

// ---- fused scatter + init_both: blocks [0,NSC) scatter, [NSC,NSC+NDB) init ----
// init: phase-major over 2 tiles; H tiles reuse Tl (fragments held in regs).
template<typename T>
__global__ __launch_bounds__(256) void scatter_init_kernel(
    const int* __restrict__ ei_raw, const int* __restrict__ flag,
    int* __restrict__ cursor, int2* __restrict__ pk,
    const float* __restrict__ x, const float* __restrict__ noise, const int* __restrict__ h_index,
    const float* __restrict__ qw1, const float* __restrict__ qb1,
    const float* __restrict__ qw2, const float* __restrict__ qb2,
    const float* __restrict__ vw1, const float* __restrict__ vb1,
    const float* __restrict__ vw2, const float* __restrict__ vb2,
    T* __restrict__ A, T* __restrict__ B){
  if (blockIdx.x < NSC){
    int is64 = flag[0];
    int e = blockIdx.x * 256 + threadIdx.x;
    if (e < EDIM){
      int dst = is64 ? ei_raw[6*e]   : ei_raw[3*e];
      int rel = is64 ? ei_raw[6*e+2] : ei_raw[3*e+1];
      int src = is64 ? ei_raw[6*e+4] : ei_raw[3*e+2];
      if ((unsigned)dst < VDIM && (unsigned)rel < RDIM && (unsigned)src < VDIM){
        int p = atomicAdd(&cursor[dst], 1);
        pk[p] = make_int2(rel, src);
      }
    }
    return;
  }
  __shared__ unsigned short Tl[4][2048];
  __shared__ float Nl[4][32];
  int tid = threadIdx.x, lane = tid & 63, wid = tid >> 6;
  int lr = lane & 15, lg = lane >> 4;
  unsigned short* Tw = Tl[wid];
  floatx4 zz = {0.f, 0.f, 0.f, 0.f};
  int t0 = (blockIdx.x - NSC)*2;
  // stage both x tiles + noise
  #pragma unroll
  for (int tt = 0; tt < 2; tt++){
    int row0 = (t0 + tt)*64 + wid*16;
    #pragma unroll
    for (int it = 0; it < 4; it++){
      int rl = it*4 + lg;
      size_t gi = (size_t)(row0 + rl)*64 + 4*lr;
      float4 x4 = ldf4(x, gi);
      *(ushort4*)&Tw[tt*1024 + swz(rl, 4*lr)] = packb(x4);
      if (lr == 0) Nl[wid][tt*16 + rl] = noise[row0 + rl];
    }
  }
  wsync();
  short8v a0[2], a1[2];
  #pragma unroll
  for (int tt = 0; tt < 2; tt++){
    a0[tt] = *(const short8v*)&Tw[tt*1024 + swz(lr, lg*8)];
    a1[tt] = *(const short8v*)&Tw[tt*1024 + swz(lr, 32 + lg*8)];
  }
  wsync();                                   // fragment reads done; Tl reusable as H
  // ---- qk branch (phase-major over tiles) ----
  {
    short8v w1f[4][2], w2f[4][2];
    float wnl[4], b1l[4], b2l[4];
    #pragma unroll
    for (int nt = 0; nt < 4; nt++){
      int col = lr + 16*nt;
      wnl[nt] = qw1[col*65 + 64];
      b1l[nt] = qb1[col]; b2l[nt] = qb2[col];
      #pragma unroll
      for (int ks = 0; ks < 2; ks++){
        const float* p1 = qw1 + col*65 + ks*32 + lg*8;
        const float* p2 = qw2 + col*64 + ks*32 + lg*8;
        short8v f, gg;
        #pragma unroll
        for (int j = 0; j < 8; j++){ f[j] = (short)f2b(p1[j]); gg[j] = (short)f2b(p2[j]); }
        w1f[nt][ks] = f; w2f[nt][ks] = gg;
      }
    }
    #pragma unroll
    for (int tt = 0; tt < 2; tt++){
      float nzq[4];
      #pragma unroll
      for (int q = 0; q < 4; q++) nzq[q] = Nl[wid][tt*16 + lg*4 + q];
      #pragma unroll
      for (int nt = 0; nt < 4; nt++){
        floatx4 acc = zz;
        acc = __builtin_amdgcn_mfma_f32_16x16x32_bf16(a0[tt], w1f[nt][0], acc, 0, 0, 0);
        acc = __builtin_amdgcn_mfma_f32_16x16x32_bf16(a1[tt], w1f[nt][1], acc, 0, 0, 0);
        #pragma unroll
        for (int q = 0; q < 4; q++)
          Tw[tt*1024 + swz(lg*4 + q, lr + 16*nt)] = f2b(fmaxf(acc[q] + b1l[nt] + wnl[nt]*nzq[q], 0.f));
      }
    }
    wsync();
    short8v h0[2], h1[2];
    #pragma unroll
    for (int tt = 0; tt < 2; tt++){
      h0[tt] = *(const short8v*)&Tw[tt*1024 + swz(lr, lg*8)];
      h1[tt] = *(const short8v*)&Tw[tt*1024 + swz(lr, 32 + lg*8)];
    }
    #pragma unroll
    for (int tt = 0; tt < 2; tt++){
      int row0 = (t0 + tt)*64 + wid*16;
      #pragma unroll
      for (int nt = 0; nt < 4; nt++){
        floatx4 acc = zz;
        acc = __builtin_amdgcn_mfma_f32_16x16x32_bf16(h0[tt], w2f[nt][0], acc, 0, 0, 0);
        acc = __builtin_amdgcn_mfma_f32_16x16x32_bf16(h1[tt], w2f[nt][1], acc, 0, 0, 0);
        #pragma unroll
        for (int q = 0; q < 4; q++){
          int rl = lg*4 + q, c = lr + 16*nt;
          stf(A, (size_t)(row0 + rl)*64 + c, acc[q] + b2l[nt]);
        }
      }
    }
    wsync();                                 // h reads done; Tl reusable again
  }
  // ---- v branch (phase-major over tiles) ----
  {
    short8v w1f[4][2], w2f[4][2];
    float rsvl[4], b1l[4], b2l[4];
    #pragma unroll
    for (int nt = 0; nt < 4; nt++){
      int col = lr + 16*nt;
      b1l[nt] = vb1[col]; b2l[nt] = vb2[col];
      const float4* r4 = (const float4*)(vw1 + col*128 + 64);
      float rsv = 0.f;
      #pragma unroll
      for (int i = 0; i < 16; i++){ float4 t = r4[i]; rsv += t.x + t.y + t.z + t.w; }
      rsvl[nt] = rsv;
      #pragma unroll
      for (int ks = 0; ks < 2; ks++){
        const float* p1 = vw1 + col*128 + ks*32 + lg*8;
        const float* p2 = vw2 + col*64 + ks*32 + lg*8;
        short8v f, gg;
        #pragma unroll
        for (int j = 0; j < 8; j++){ f[j] = (short)f2b(p1[j]); gg[j] = (short)f2b(p2[j]); }
        w1f[nt][ks] = f; w2f[nt][ks] = gg;
      }
    }
    #pragma unroll
    for (int tt = 0; tt < 2; tt++){
      int row0 = (t0 + tt)*64 + wid*16;
      int b = row0 / VDIM;
      int vb = row0 - b*VDIM;
      int hv = h_index[b];
      #pragma unroll
      for (int nt = 0; nt < 4; nt++){
        floatx4 acc = zz;
        acc = __builtin_amdgcn_mfma_f32_16x16x32_bf16(a0[tt], w1f[nt][0], acc, 0, 0, 0);
        acc = __builtin_amdgcn_mfma_f32_16x16x32_bf16(a1[tt], w1f[nt][1], acc, 0, 0, 0);
        #pragma unroll
        for (int q = 0; q < 4; q++){
          bool cq = (vb + lg*4 + q) == hv;
          Tw[tt*1024 + swz(lg*4 + q, lr + 16*nt)] = f2b(fmaxf(acc[q] + b1l[nt] + (cq ? rsvl[nt] : 0.f), 0.f));
        }
      }
    }
    wsync();
    short8v h0[2], h1[2];
    #pragma unroll
    for (int tt = 0; tt < 2; tt++){
      h0[tt] = *(const short8v*)&Tw[tt*1024 + swz(lr, lg*8)];
      h1[tt] = *(const short8v*)&Tw[tt*1024 + swz(lr, 32 + lg*8)];
    }
    #pragma unroll
    for (int tt = 0; tt < 2; tt++){
      int row0 = (t0 + tt)*64 + wid*16;
      #pragma unroll
      for (int nt = 0; nt < 4; nt++){
        floatx4 acc = zz;
        acc = __builtin_amdgcn_mfma_f32_16x16x32_bf16(h0[tt], w2f[nt][0], acc, 0, 0, 0);
        acc = __builtin_amdgcn_mfma_f32_16x16x32_bf16(h1[tt], w2f[nt][1], acc, 0, 0, 0);
        #pragma unroll
        for (int q = 0; q < 4; q++){
          int rl = lg*4 + q, c = lr + 16*nt;
          stf(B, (size_t)(row0 + rl)*64 + c, acc[q] + b2l[nt]);
        }
      }
    }
  }
}

// ---- rspmm gather, dual-chain: blocks [0,NRB) = chain A, [NRB,2NRB) = chain B ----
// 8 vertices/block, 4 edges in flight
template<typename T>
__global__ __launch_bounds__(256) void rspmm_dual(
    const int* __restrict__ row_ptr, const int2* __restrict__ pk,
    const float* __restrict__ zA, const float* __restrict__ zB,
    const T* __restrict__ XA, const T* __restrict__ XB,
    T* __restrict__ outA, T* __restrict__ outB){
  int bid = blockIdx.x;
  bool cb = bid >= NRB;
  int v0 = (cb ? bid - NRB : bid) * 8;
  const float* zrel = cb ? zB : zA;
  const T* X = cb ? XB : XA;
  T* out = cb ? outB : outA;
  int btch = threadIdx.x >> 6, d = threadIdx.x & 63;
  int rp[9];
  #pragma unroll
  for (int i = 0; i < 9; i++) rp[i] = row_ptr[v0 + i];
  const float* zb = zrel + btch*RDIM*DDIM + d;
  size_t xb = (size_t)btch*VDIM*64 + d;
  size_t ob = ((size_t)btch*VDIM + v0)*64 + d;
  #pragma unroll 1
  for (int vi = 0; vi < 8; vi++){
    int s = rp[vi], e = rp[vi+1];
    float a0 = 0.f, a1 = 0.f, a2 = 0.f, a3 = 0.f;
    int i = s;
    for (; i + 4 <= e; i += 4){
      int2 e0 = pk[i], e1 = pk[i+1], e2 = pk[i+2], e3 = pk[i+3];
      float x0 = ldf(X, xb + (size_t)e0.y*64);
      float x1 = ldf(X, xb + (size_t)e1.y*64);
      float x2 = ldf(X, xb + (size_t)e2.y*64);
      float x3 = ldf(X, xb + (size_t)e3.y*64);
      a0 += zb[(size_t)e0.x*64] * x0;
      a1 += zb[(size_t)e1.x*64] * x1;
      a2 += zb[(size_t)e2.x*64] * x2;
      a3 += zb[(size_t)e3.x*64] * x3;
    }
    for (; i < e; i++){
      int2 ed = pk[i];
      a0 += zb[(size_t)ed.x*64] * ldf(X, xb + (size_t)ed.y*64);
    }
    stf(out, ob + (size_t)vi*64, a0 + a1 + a2 + a3);
  }
}

// ================= MFMA dense kernels =================
// Per wave: 16-row x 64-col tile. A-frag: lane holds row (lane&15), k-slice (lane>>4).
// B-frag (weights): lane holds W[col=(lane&15)+16nt][k-slice]. C/D: col=lane&15,
// row=(lane>>4)*4+q (m89-verified). LDS tiles [16][64] bf16 with row-XOR swizzle.

// ---- loop body, dual-chain, 2 tiles/block, phase-major; H reuses Tl ----
template<typename T>
__global__ __launch_bounds__(256) void loop_dual_kernel(
    const T* __restrict__ OA, T* __restrict__ XA,
    const T* __restrict__ OB, T* __restrict__ XB,
    const float* __restrict__ alA, const float* __restrict__ w1A, const float* __restrict__ b1A,
    const float* __restrict__ w2A, const float* __restrict__ b2A,
    const float* __restrict__ ngA, const float* __restrict__ nbA,
    const float* __restrict__ alB, const float* __restrict__ w1B, const float* __restrict__ b1B,
    const float* __restrict__ w2B, const float* __restrict__ b2B,
    const float* __restrict__ ngB, const float* __restrict__ nbB){
  __shared__ unsigned short Tl[4][2048];
  __shared__ unsigned short Xl[4][2048];
  int bid = blockIdx.x;
  bool cb = bid >= NDB;
  int pb = cb ? bid - NDB : bid;
  const T* O = cb ? OB : OA;
  T* X = cb ? XB : XA;
  const float* alpha = cb ? alB : alA;
  const float* w1 = cb ? w1B : w1A;
  const float* b1 = cb ? b1B : b1A;
  const float* w2 = cb ? w2B : w2A;
  const float* b2 = cb ? b2B : b2A;
  const float* ng = cb ? ngB : ngA;
  const float* nb = cb ? nbB : nbA;
  int tid = threadIdx.x, lane = tid & 63, wid = tid >> 6;
  int lr = lane & 15, lg = lane >> 4;
  short8v w1f[4][2], w2f[4][2];
  #pragma unroll
  for (int nt = 0; nt < 4; nt++){
    int col = lr + 16*nt;
    #pragma unroll
    for (int ks = 0; ks < 2; ks++){
      const float* p1 = w1 + col*64 + ks*32 + lg*8;
      const float* p2 = w2 + col*64 + ks*32 + lg*8;
      short8v f, g;
      #pragma unroll
      for (int j = 0; j < 8; j++){ f[j] = (short)f2b(p1[j]); g[j] = (short)f2b(p2[j]); }
      w1f[nt][ks] = f; w2f[nt][ks] = g;
    }
  }
  float4 al = ((const float4*)alpha)[lr];
  float b1l[4], b2l[4], ngl[4], nbl[4];
  #pragma unroll
  for (int nt = 0; nt < 4; nt++){
    int c = lr + 16*nt;
    b1l[nt] = b1[c]; b2l[nt] = b2[c]; ngl[nt] = ng[c]; nbl[nt] = nb[c];
  }
  unsigned short* Tw = Tl[wid];
  unsigned short* Xw = Xl[wid];
  floatx4 zz = {0.f, 0.f, 0.f, 0.f};
  int t0 = pb*2;
  // stage both tiles (16 loads in flight)
  #pragma unroll
  for (int tt = 0; tt < 2; tt++){
    int row0 = (t0 + tt)*64 + wid*16;
    #pragma unroll
    for (int it = 0; it < 4; it++){
      int rl = it*4 + lg;
      size_t gi = (size_t)(row0 + rl)*64 + 4*lr;
      float4 xs4 = ldf4(X, gi);
      float4 ov4 = ldf4(O, gi);
      int si = tt*1024 + swz(rl, 4*lr);
      float4 tv;
      tv.x = ov4.x + al.x*xs4.x;
      tv.y = ov4.y + al.y*xs4.y;
      tv.z = ov4.z + al.z*xs4.z;
      tv.w = ov4.w + al.w*xs4.w;
      *(ushort4*)&Tw[si] = packb(tv);
      *(ushort4*)&Xw[si] = packb(xs4);
    }
  }
  wsync();
  short8v a0[2], a1[2];
  #pragma unroll
  for (int tt = 0; tt < 2; tt++){
    a0[tt] = *(const short8v*)&Tw[tt*1024 + swz(lr, lg*8)];
    a1[tt] = *(const short8v*)&Tw[tt*1024 + swz(lr, 32 + lg*8)];
  }
  wsync();                                   // fragment reads done; Tl reusable as H
  // MFMA1 both tiles -> H into Tl halves
  #pragma unroll
  for (int tt = 0; tt < 2; tt++){
    #pragma unroll
    for (int nt = 0; nt < 4; nt++){
      floatx4 acc = zz;
      acc = __builtin_amdgcn_mfma_f32_16x16x32_bf16(a0[tt], w1f[nt][0], acc, 0, 0, 0);
      acc = __builtin_amdgcn_mfma_f32_16x16x32_bf16(a1[tt], w1f[nt][1], acc, 0, 0, 0);
      #pragma unroll
      for (int q = 0; q < 4; q++)
        Tw[tt*1024 + swz(lg*4 + q, lr + 16*nt)] = f2b(fmaxf(acc[q] + b1l[nt], 0.f));
    }
  }
  wsync();
  short8v h0[2], h1[2];
  #pragma unroll
  for (int tt = 0; tt < 2; tt++){
    h0[tt] = *(const short8v*)&Tw[tt*1024 + swz(lr, lg*8)];
    h1[tt] = *(const short8v*)&Tw[tt*1024 + swz(lr, 32 + lg*8)];
  }
  // barrier-free tail: MFMA2 + LN + writeback, both tiles interleaved by scheduler
  #pragma unroll
  for (int tt = 0; tt < 2; tt++){
    int row0 = (t0 + tt)*64 + wid*16;
    float y[4][4];
    float s[4] = {0.f,0.f,0.f,0.f}, ss[4] = {0.f,0.f,0.f,0.f};
    #pragma unroll
    for (int nt = 0; nt < 4; nt++){
      floatx4 acc = zz;
      acc = __builtin_amdgcn_mfma_f32_16x16x32_bf16(h0[tt], w2f[nt][0], acc, 0, 0, 0);
      acc = __builtin_amdgcn_mfma_f32_16x16x32_bf16(h1[tt], w2f[nt][1], acc, 0, 0, 0);
      #pragma unroll
      for (int q = 0; q < 4; q++){
        float v = acc[q] + b2l[nt];
        y[nt][q] = v; s[q] += v; ss[q] += v*v;
      }
    }
    #pragma unroll
    for (int o = 1; o < 16; o <<= 1){
      #pragma unroll
      for (int q = 0; q < 4; q++){
        s[q] += __shfl_xor(s[q], o, 64);
        ss[q] += __shfl_xor(ss[q], o, 64);
      }
    }
    #pragma unroll
    for (int q = 0; q < 4; q++){
      float mu = s[q]*(1.f/64.f);
      float var = fmaxf(ss[q]*(1.f/64.f) - mu*mu, 0.f);
      float rs = rsqrtf(var + LN_EPS);
      #pragma unroll
      for (int nt = 0; nt < 4; nt++){
        int rl = lg*4 + q, c = lr + 16*nt;
        float xs = b2f(Xw[tt*1024 + swz(rl, c)]);
        float v = (y[nt][q] - mu)*rs*ngl[nt] + nbl[nt] + xs;
        stf(X, (size_t)(row0 + rl)*64 + c, v);
      }
    }
  }
}

// ---- kvred (MFMA): k-proj + head-norm + kv += kn^T·vx + ksum/vsum partials ----
template<typename T>
__global__ __launch_bounds__(256) void kvred_mfma_kernel(
    const T* __restrict__ Xqk, const T* __restrict__ Xv,
    const float* __restrict__ w, const float* __restrict__ bias,
    float* __restrict__ partial){
  __shared__ unsigned short T1[4][1024];   // Xqk stage (swz) then kn_t [64][16]
  __shared__ unsigned short T2[4][1024];   // Xv stage (swz)
  __shared__ float red[4*1536];
  int tid = threadIdx.x, lane = tid & 63, wid = tid >> 6;
  int lr = lane & 15, lg = lane >> 4;
  short8v wkf[4][2];
  #pragma unroll
  for (int nt = 0; nt < 4; nt++){
    int col = 64 + lr + 16*nt;               // k-half of fc_to_qk
    #pragma unroll
    for (int ks = 0; ks < 2; ks++){
      const float* p = w + col*64 + ks*32 + lg*8;
      short8v f;
      #pragma unroll
      for (int j = 0; j < 8; j++) f[j] = (short)f2b(p[j]);
      wkf[nt][ks] = f;
    }
  }
  float bk[4];
  #pragma unroll
  for (int nt = 0; nt < 4; nt++) bk[nt] = bias[64 + lr + 16*nt];
  int b = blockIdx.x / NBB, blk = blockIdx.x % NBB;
  unsigned short* Tw = T1[wid];
  unsigned short* Vw = T2[wid];
  floatx4 zz = {0.f, 0.f, 0.f, 0.f};
  floatx4 kvacc[4] = {zz, zz, zz, zz};
  float ksp[4] = {0.f,0.f,0.f,0.f};
  float vsp[4] = {0.f,0.f,0.f,0.f};
  const short8v z8 = {0,0,0,0,0,0,0,0};
  for (int st = blk*4 + wid; st < 1250; st += NBB*4){
    size_t gr = (size_t)b*VDIM + (size_t)st*16;
    #pragma unroll
    for (int it = 0; it < 4; it++){
      int rl = it*4 + lg;
      size_t gi = (gr + rl)*64 + 4*lr;
      float4 xq4 = ldf4(Xqk, gi);
      float4 xv4 = ldf4(Xv, gi);
      int si = swz(rl, 4*lr);
      *(ushort4*)&Tw[si] = packb(xq4);
      *(ushort4*)&Vw[si] = packb(xv4);
      vsp[0] += xv4.x; vsp[1] += xv4.y; vsp[2] += xv4.z; vsp[3] += xv4.w;
    }
    wsync();
    short8v a0 = *(const short8v*)&Tw[swz(lr, lg*8)];
    short8v a1 = *(const short8v*)&Tw[swz(lr, 32 + lg*8)];
    // k-projection + head norm -> kn (C-layout regs), store kn_t to T1
    float kn[4][4];
    #pragma unroll
    for (int nt = 0; nt < 4; nt++){
      floatx4 acc = zz;
      acc = __builtin_amdgcn_mfma_f32_16x16x32_bf16(a0, wkf[nt][0], acc, 0, 0, 0);
      acc = __builtin_amdgcn_mfma_f32_16x16x32_bf16(a1, wkf[nt][1], acc, 0, 0, 0);
      #pragma unroll
      for (int q = 0; q < 4; q++) kn[nt][q] = acc[q] + bk[nt];
    }
    #pragma unroll
    for (int nt = 0; nt < 4; nt++){
      float n0 = kn[nt][0]*kn[nt][0], n1 = kn[nt][1]*kn[nt][1];
      float n2 = kn[nt][2]*kn[nt][2], n3 = kn[nt][3]*kn[nt][3];
      #pragma unroll
      for (int o = 1; o < 16; o <<= 1){
        n0 += __shfl_xor(n0, o, 64); n1 += __shfl_xor(n1, o, 64);
        n2 += __shfl_xor(n2, o, 64); n3 += __shfl_xor(n3, o, 64);
      }
      kn[nt][0] /= fmaxf(sqrtf(n0), 1e-12f);
      kn[nt][1] /= fmaxf(sqrtf(n1), 1e-12f);
      kn[nt][2] /= fmaxf(sqrtf(n2), 1e-12f);
      kn[nt][3] /= fmaxf(sqrtf(n3), 1e-12f);
      ksp[nt] += kn[nt][0] + kn[nt][1] + kn[nt][2] + kn[nt][3];
    }
    wsync();   // a0/a1 consumed; safe to overwrite T1 with kn_t
    #pragma unroll
    for (int nt = 0; nt < 4; nt++){
      int c = lr + 16*nt;
      #pragma unroll
      for (int q = 0; q < 4; q++)
        Tw[c*16 + lg*4 + q] = f2b(kn[nt][q]);
    }
    wsync();
    // kv += kn^T (A) x vx (B), per head, K=16 rows zero-padded to 32
    #pragma unroll
    for (int nt = 0; nt < 4; nt++){
      short8v af = z8, bf = z8;
      if (lg < 2){
        af = *(const short8v*)&Tw[(nt*16 + lr)*16 + lg*8];
        #pragma unroll
        for (int j = 0; j < 8; j++)
          bf[j] = (short)Vw[swz(lg*8 + j, nt*16 + lr)];
      }
      kvacc[nt] = __builtin_amdgcn_mfma_f32_16x16x32_bf16(af, bf, kvacc[nt], 0, 0, 0);
    }
    wsync();   // LDS reads done before next stripe overwrites tiles
  }
  // write per-wave partials
  float* rw = red + wid*1536;
  #pragma unroll
  for (int nt = 0; nt < 4; nt++){
    #pragma unroll
    for (int q = 0; q < 4; q++)
      rw[(nt*16 + lg*4 + q)*16 + lr] = kvacc[nt][q];
    rw[1024 + lg*64 + lr + 16*nt] = ksp[nt];
  }
  #pragma unroll
  for (int m = 0; m < 4; m++)
    rw[1280 + lg*64 + 4*lr + m] = vsp[m];
  __syncthreads();
  float* P = partial + (size_t)blockIdx.x*1152;
  for (int j = tid; j < 1152; j += 256){
    float s = 0.f;
    if (j < 1024){
      #pragma unroll
      for (int wv = 0; wv < 4; wv++) s += red[wv*1536 + j];
    } else if (j < 1088){
      int c = j - 1024;
      #pragma unroll
      for (int wv = 0; wv < 4; wv++)
        #pragma unroll
        for (int gg = 0; gg < 4; gg++) s += red[wv*1536 + 1024 + gg*64 + c];
    } else {
      int c = j - 1088;
      #pragma unroll
      for (int wv = 0; wv < 4; wv++)
        #pragma unroll
        for (int gg = 0; gg < 4; gg++) s += red[wv*1536 + 1280 + gg*64 + c];
    }
    P[j] = s;
  }
}

// ---- reduce kvred partials; also emit bf16 copies for attn fragments ----
__global__ void qkred_kernel(const float* __restrict__ partial,
                             float* __restrict__ kvs, float* __restrict__ ksum, float* __restrict__ vsum,
                             unsigned short* __restrict__ kvsb, unsigned short* __restrict__ ksb){
  int b = blockIdx.x / 5, ch = blockIdx.x % 5;
  int j = ch*256 + threadIdx.x;
  if (j >= 1152) return;
  const float* P = partial + (size_t)b*NBB*1152;
  float s = 0.f;
  for (int t = 0; t < NBB; t++) s += P[(size_t)t*1152 + j];
  if (j < 1024){      kvs[b*1024 + j] = s; kvsb[b*1024 + j] = f2b(s); }
  else if (j < 1088){ ksum[b*64 + (j-1024)] = s; ksb[b*64 + (j-1024)] = f2b(s); }
  else                vsum[b*64 + (j-1088)] = s;
}

// ---- fused attention + final FFN, 2 tiles/block, phase-major; all LDS in Ql ----
template<typename T>
__global__ __launch_bounds__(256) void attn_final_kernel(
    const float* __restrict__ x, const T* __restrict__ A, const T* __restrict__ Xv,
    const unsigned short* __restrict__ kvsb, const unsigned short* __restrict__ ksb,
    const float* __restrict__ vsum,
    const float* __restrict__ w, const float* __restrict__ bias,
    const float* __restrict__ ag, const float* __restrict__ ab,
    const float* __restrict__ fw1, const float* __restrict__ fb1,
    const float* __restrict__ fw2, const float* __restrict__ fb2,
    const float* __restrict__ g, const float* __restrict__ bb,
    float* __restrict__ out){
  __shared__ unsigned short Ql[4][2048];
  int tid = threadIdx.x, lane = tid & 63, wid = tid >> 6;
  int lr = lane & 15, lg = lane >> 4;
  // q-proj weights
  short8v wqf[4][2];
  #pragma unroll
  for (int nt = 0; nt < 4; nt++){
    int col = lr + 16*nt;
    #pragma unroll
    for (int ks = 0; ks < 2; ks++){
      const float* p = w + col*64 + ks*32 + lg*8;
      short8v f;
      #pragma unroll
      for (int j = 0; j < 8; j++) f[j] = (short)f2b(p[j]);
      wqf[nt][ks] = f;
    }
  }
  // FFN weights
  short8v f1f[4][2], f2f[4][2];
  float bq[4], agl[4], abl[4], b1l[4], b2l[4], gl[4], bl[4];
  #pragma unroll
  for (int nt = 0; nt < 4; nt++){
    int col = lr + 16*nt;
    bq[nt] = bias[col]; agl[nt] = ag[col]; abl[nt] = ab[col];
    b1l[nt] = fb1[col]; b2l[nt] = fb2[col]; gl[nt] = g[col]; bl[nt] = bb[col];
    #pragma unroll
    for (int ks = 0; ks < 2; ks++){
      const float* p1 = fw1 + col*64 + ks*32 + lg*8;
      const float* p2 = fw2 + col*64 + ks*32 + lg*8;
      short8v f, gg;
      #pragma unroll
      for (int j = 0; j < 8; j++){ f[j] = (short)f2b(p1[j]); gg[j] = (short)f2b(p2[j]); }
      f1f[nt][ks] = f; f2f[nt][ks] = gg;
    }
  }
  unsigned short* Qw = Ql[wid];
  floatx4 zz = {0.f, 0.f, 0.f, 0.f};
  const short8v z8 = {0,0,0,0,0,0,0,0};
  int t0 = blockIdx.x*2;
  int row0[2], bb_[2];
  #pragma unroll
  for (int tt = 0; tt < 2; tt++){
    row0[tt] = (t0 + tt)*64 + wid*16;
    bb_[tt] = row0[tt] / VDIM;               // wave-uniform (16 | 20000)
  }
  // stage both A tiles
  #pragma unroll
  for (int tt = 0; tt < 2; tt++){
    #pragma unroll
    for (int it = 0; it < 4; it++){
      int rl = it*4 + lg;
      size_t gi = (size_t)(row0[tt] + rl)*64 + 4*lr;
      *(ushort4*)&Qw[tt*1024 + swz(rl, 4*lr)] = packb(ldf4(A, gi));
    }
  }
  wsync();
  short8v a0[2], a1[2];
  #pragma unroll
  for (int tt = 0; tt < 2; tt++){
    a0[tt] = *(const short8v*)&Qw[tt*1024 + swz(lr, lg*8)];
    a1[tt] = *(const short8v*)&Qw[tt*1024 + swz(lr, 32 + lg*8)];
  }
  wsync();                                   // fragment reads done
  // q projection + head norm, both tiles
  float qn[2][4][4];
  #pragma unroll
  for (int tt = 0; tt < 2; tt++){
    #pragma unroll
    for (int nt = 0; nt < 4; nt++){
      floatx4 acc = zz;
      acc = __builtin_amdgcn_mfma_f32_16x16x32_bf16(a0[tt], wqf[nt][0], acc, 0, 0, 0);
      acc = __builtin_amdgcn_mfma_f32_16x16x32_bf16(a1[tt], wqf[nt][1], acc, 0, 0, 0);
      #pragma unroll
      for (int q = 0; q < 4; q++) qn[tt][nt][q] = acc[q] + bq[nt];
    }
  }
  #pragma unroll
  for (int tt = 0; tt < 2; tt++){
    #pragma unroll
    for (int nt = 0; nt < 4; nt++){
      float n0 = qn[tt][nt][0]*qn[tt][nt][0], n1 = qn[tt][nt][1]*qn[tt][nt][1];
      float n2 = qn[tt][nt][2]*qn[tt][nt][2], n3 = qn[tt][nt][3]*qn[tt][nt][3];
      #pragma unroll
      for (int o = 1; o < 16; o <<= 1){
        n0 += __shfl_xor(n0, o, 64); n1 += __shfl_xor(n1, o, 64);
        n2 += __shfl_xor(n2, o, 64); n3 += __shfl_xor(n3, o, 64);
      }
      qn[tt][nt][0] /= fmaxf(sqrtf(n0), 1e-12f);
      qn[tt][nt][1] /= fmaxf(sqrtf(n1), 1e-12f);
      qn[tt][nt][2] /= fmaxf(sqrtf(n2), 1e-12f);
      qn[tt][nt][3] /= fmaxf(sqrtf(n3), 1e-12f);
    }
  }
  // write qn tiles (swizzled)
  #pragma unroll
  for (int tt = 0; tt < 2; tt++)
    #pragma unroll
    for (int nt = 0; nt < 4; nt++)
      #pragma unroll
      for (int q = 0; q < 4; q++)
        Qw[tt*1024 + swz(lg*4 + q, lr + 16*nt)] = f2b(qn[tt][nt][q]);
  wsync();
  // per-head attention, both tiles
  float y[2][4][4];
  float s[2][4] = {{0.f,0.f,0.f,0.f},{0.f,0.f,0.f,0.f}};
  float ss[2][4] = {{0.f,0.f,0.f,0.f},{0.f,0.f,0.f,0.f}};
  #pragma unroll
  for (int tt = 0; tt < 2; tt++){
    int b = bb_[tt];
    #pragma unroll
    for (int nt = 0; nt < 4; nt++){
      short8v af = z8, bn = z8, bd = z8;
      if (lg < 2){
        af = *(const short8v*)&Qw[tt*1024 + swz(lr, nt*16 + lg*8)];
        bd = *(const short8v*)&ksb[b*64 + nt*16 + lg*8];
        #pragma unroll
        for (int j = 0; j < 8; j++)
          bn[j] = (short)kvsb[b*1024 + (nt*16 + lg*8 + j)*16 + lr];
      }
      int c = lr + 16*nt;
      float vsb = vsum[b*64 + c];
      floatx4 numc, denc;
      #pragma unroll
      for (int q = 0; q < 4; q++){
        float vv = ldf(Xv, (size_t)(row0[tt] + lg*4 + q)*64 + c);
        numc[q] = vsb + vv*(float)VDIM;
        denc[q] = 2.0f*(float)VDIM;
      }
      numc = __builtin_amdgcn_mfma_f32_16x16x32_bf16(af, bn, numc, 0, 0, 0);
      denc = __builtin_amdgcn_mfma_f32_16x16x32_bf16(af, bd, denc, 0, 0, 0);
      #pragma unroll
      for (int q = 0; q < 4; q++){
        float xv = x[(size_t)(row0[tt] + lg*4 + q)*64 + c];
        float v = xv + numc[q]/denc[q];
        y[tt][nt][q] = v; s[tt][q] += v; ss[tt][q] += v*v;
      }
    }
  }
  #pragma unroll
  for (int o = 1; o < 16; o <<= 1){
    #pragma unroll
    for (int tt = 0; tt < 2; tt++)
      #pragma unroll
      for (int q = 0; q < 4; q++){
        s[tt][q] += __shfl_xor(s[tt][q], o, 64);
        ss[tt][q] += __shfl_xor(ss[tt][q], o, 64);
      }
  }
  #pragma unroll
  for (int tt = 0; tt < 2; tt++)
    #pragma unroll
    for (int q = 0; q < 4; q++){
      float mu = s[tt][q]*(1.f/64.f);
      float var = fmaxf(ss[tt][q]*(1.f/64.f) - mu*mu, 0.f);
      float rs = rsqrtf(var + LN_EPS);
      #pragma unroll
      for (int nt = 0; nt < 4; nt++)
        y[tt][nt][q] = (y[tt][nt][q] - mu)*rs*agl[nt] + abl[nt];
    }
  wsync();   // per-head Qw reads done; overwrite with xa
  #pragma unroll
  for (int tt = 0; tt < 2; tt++)
    #pragma unroll
    for (int nt = 0; nt < 4; nt++)
      #pragma unroll
      for (int q = 0; q < 4; q++)
        Qw[tt*1024 + swz(lg*4 + q, lr + 16*nt)] = f2b(y[tt][nt][q]);
  wsync();
  short8v xa0[2], xa1[2];
  #pragma unroll
  for (int tt = 0; tt < 2; tt++){
    xa0[tt] = *(const short8v*)&Qw[tt*1024 + swz(lr, lg*8)];
    xa1[tt] = *(const short8v*)&Qw[tt*1024 + swz(lr, 32 + lg*8)];
  }
  wsync();                                   // xa reads done; Qw reusable as H
  #pragma unroll
  for (int tt = 0; tt < 2; tt++){
    #pragma unroll
    for (int nt = 0; nt < 4; nt++){
      floatx4 acc = zz;
      acc = __builtin_amdgcn_mfma_f32_16x16x32_bf16(xa0[tt], f1f[nt][0], acc, 0, 0, 0);
      acc = __builtin_amdgcn_mfma_f32_16x16x32_bf16(xa1[tt], f1f[nt][1], acc, 0, 0, 0);
      #pragma unroll
      for (int q = 0; q < 4; q++)
        Qw[tt*1024 + swz(lg*4 + q, lr + 16*nt)] = f2b(fmaxf(acc[q] + b1l[nt], 0.f));
    }
  }
  wsync();
  short8v h0[2], h1[2];
  #pragma unroll
  for (int tt = 0; tt < 2; tt++){
    h0[tt] = *(const short8v*)&Qw[tt*1024 + swz(lr, lg*8)];
    h1[tt] = *(const short8v*)&Qw[tt*1024 + swz(lr, 32 + lg*8)];
  }
  // barrier-free tail: MFMA2 + LN2 + store, both tiles
  #pragma unroll
  for (int tt = 0; tt < 2; tt++){
    float t[4][4];
    float s2[4] = {0.f,0.f,0.f,0.f}, ss2[4] = {0.f,0.f,0.f,0.f};
    #pragma unroll
    for (int nt = 0; nt < 4; nt++){
      floatx4 acc = zz;
      acc = __builtin_amdgcn_mfma_f32_16x16x32_bf16(h0[tt], f2f[nt][0], acc, 0, 0, 0);
      acc = __builtin_amdgcn_mfma_f32_16x16x32_bf16(h1[tt], f2f[nt][1], acc, 0, 0, 0);
      #pragma unroll
      for (int q = 0; q < 4; q++){
        float v = acc[q] + b2l[nt] + y[tt][nt][q];
        t[nt][q] = v; s2[q] += v; ss2[q] += v*v;
      }
    }
    #pragma unroll
    for (int o = 1; o < 16; o <<= 1){
      #pragma unroll
      for (int q = 0; q < 4; q++){
        s2[q] += __shfl_xor(s2[q], o, 64);
        ss2[q] += __shfl_xor(ss2[q], o, 64);
      }
    }
    #pragma unroll
    for (int q = 0; q < 4; q++){
      float mu = s2[q]*(1.f/64.f);
      float var = fmaxf(ss2[q]*(1.f/64.f) - mu*mu, 0.f);
      float rs = rsqrtf(var + LN_EPS);
      #pragma unroll
      for (int nt = 0; nt < 4; nt++){
        int c = lr + 16*nt;
        out[(size_t)(row0[tt] + lg*4 + q)*64 + c] = (t[nt][q] - mu)*rs*gl[nt] + bl[nt];
      }
    }
  }
}

// ================= host side =================
static const int DICT_SIZES[42] = {
  5120000,256,256,80000,262144,4096,4160,64,4096,64,
  8192,64,4096,64,8192,128,8192,128,8192,128,
  128,128,128,524288,8192,8192,128,8192,128,128,
  128,128,4096,64,4096,64,64,64,64,64,
  4,600000};

template<typename T>
static void run_pipeline(const float* const* N, const int* hi,
                         const int* ei_raw, const int* eflag,
                         int* cursor, int2* pk, const int* row_ptr,
                         float* qk_z, float* zr, float* kvs, float* part,
                         unsigned short* kvsb,
                         T* A, T* B, T* OA, T* OB, bool dual,
                         float* outp, hipStream_t stream){
  float* ksum = kvs + 4096;
  float* vsum = kvs + 4352;
  unsigned short* ksb = kvsb + 4096;

  // fused: scatter (needs scan done) + init_both (independent) in one dispatch
  scatter_init_kernel<T><<<NSC + NDB, 256, 0, stream>>>(ei_raw, eflag, cursor, pk,
      N[0], N[3], hi, N[6], N[7], N[8], N[9], N[10], N[11], N[12], N[13], A, B);

  if (dual){
    for (int i = 0; i < 2; i++){
      rspmm_dual<T><<<2*NRB, 256, 0, stream>>>(row_ptr, pk, qk_z, zr + i*16384, A, B, OA, OB);
      loop_dual_kernel<T><<<2*NDB, 256, 0, stream>>>(OA, A, OB, B,
          N[20] + i*64, N[16] + i*4096, N[17] + i*64, N[18] + i*4096, N[19] + i*64, N[21] + i*64, N[22] + i*64,
          N[29] + i*64, N[25] + i*4096, N[26] + i*64, N[27] + i*4096, N[28] + i*64, N[30] + i*64, N[31] + i*64);
    }
  } else {
    for (int i = 0; i < 2; i++){
      rspmm_dual<T><<<NRB, 256, 0, stream>>>(row_ptr, pk, qk_z, qk_z, A, A, OA, OA);
      loop_dual_kernel<T><<<NDB, 256, 0, stream>>>(OA, A, OA, A,
          N[20] + i*64, N[16] + i*4096, N[17] + i*64, N[18] + i*4096, N[19] + i*64, N[21] + i*64, N[22] + i*64,
          N[20] + i*64, N[16] + i*4096, N[17] + i*64, N[18] + i*4096, N[19] + i*64, N[21] + i*64, N[22] + i*64);
    }
    for (int i = 0; i < 2; i++){
      rspmm_dual<T><<<NRB, 256, 0, stream>>>(row_ptr, pk, zr + i*16384, zr + i*16384, B, B, OA, OA);
      loop_dual_kernel<T><<<NDB, 256, 0, stream>>>(OA, B, OA, B,
          N[29] + i*64, N[25] + i*4096, N[26] + i*64, N[27] + i*4096, N[28] + i*64, N[30] + i*64, N[31] + i*64,
          N[29] + i*64, N[25] + i*4096, N[26] + i*64, N[27] + i*4096, N[28] + i*64, N[30] + i*64, N[31] + i*64);
    }
  }

  kvred_mfma_kernel<T><<<BDIM*NBB, 256, 0, stream>>>(A, B, N[14], N[15], part);
  qkred_kernel<<<20, 256, 0, stream>>>(part, kvs, ksum, vsum, kvsb, ksb);
  attn_final_kernel<T><<<NDB, 256, 0, stream>>>(N[0], A, B, kvsb, ksb, vsum,
      N[14], N[15], N[36], N[37], N[32], N[33], N[34], N[35], N[38], N[39], outp);
}

extern "C" void kernel_launch(void* const* d_in, const int* in_sizes, int n_in,
                              void* d_out, int out_size, void* d_ws, size_t ws_size,
                              hipStream_t stream){
  float* outp = (float*)d_out;
  const int GOUT = (out_size + 255) / 256;

  if (n_in != 42){
    fill_kernel<<<GOUT, 256, 0, stream>>>(outp, 2000.0f + (float)n_in, out_size);
    return;
  }
  auto sz_ok = [&](int s, int e)->bool{
    if (s == e) return true;
    if ((e == 4 || e == 600000) && s == 2*e) return true;
    return false;
  };
  int bad = -1;
  for (int i = 0; i < 42 && bad < 0; i++)
    if (!sz_ok(in_sizes[i], DICT_SIZES[i])) bad = i;
  if (bad >= 0){
    fill_kernel<<<GOUT, 256, 0, stream>>>(outp, 1000.0f + (float)bad, out_size);
    return;
  }

  const float* N[40];
  for (int i = 0; i < 40; i++) N[i] = (const float*)d_in[i];
  const int* hi_raw = (const int*)d_in[40];
  const int* ei_raw = (const int*)d_in[41];

  char* p = (char*)d_ws;
  auto alloc = [&](size_t bytes)->char*{ char* r = p; p += (bytes + 255) / 256 * 256; return r; };
  int* hi      = (int*)alloc(256);
  int* eflag   = (int*)alloc(256);
  int* counts  = (int*)alloc((VDIM+1)*4);
  int* row_ptr = (int*)alloc((VDIM+1)*4);
  int* cursor  = (int*)alloc((VDIM+1)*4);
  int2* pk     = (int2*)alloc((size_t)EDIM*8);
  float* qk_z  = (float*)alloc(16384u*4);
  float* zr    = (float*)alloc(32768u*4);
  float* kvs   = (float*)alloc(4608u*4);
  unsigned short* kvsb = (unsigned short*)alloc(4352u*2);
  float* part  = (float*)alloc((size_t)BDIM*NBB*1152*4);
  size_t fixed = (size_t)(p - (char*)d_ws);
  const size_t bufH = (size_t)BV*64*2;

  // setup: detect64 + zero counts + zcalc, one dispatch
  setup_kernel<<<273, 256, 0, stream>>>(ei_raw, eflag, counts,
      N[1], N[4], N[5], N[23], N[24], qk_z, zr);
  prep_count_kernel<<<(EDIM+255)/256, 256, 0, stream>>>(ei_raw, hi_raw, eflag, hi, counts);
  scan_kernel<<<1, 256, 0, stream>>>(counts, row_ptr, cursor);

  // bf16 workspace: halves intermediate traffic, makes rspmm X L2-resident.
  if (ws_size >= fixed + 4*bufH + 1024){
    bf16* A  = (bf16*)alloc(bufH);
    bf16* B  = (bf16*)alloc(bufH);
    bf16* OA = (bf16*)alloc(bufH);
    bf16* OB = (bf16*)alloc(bufH);
    run_pipeline<bf16>(N, hi, ei_raw, eflag, cursor, pk, row_ptr,
                       qk_z, zr, kvs, part, kvsb, A, B, OA, OB, true, outp, stream);
  } else {
    bf16* A  = (bf16*)alloc(bufH);
    bf16* B  = (bf16*)alloc(bufH);
    bf16* OA = (bf16*)alloc(bufH);
    run_pipeline<bf16>(N, hi, ei_raw, eflag, cursor, pk, row_ptr,
                       qk_z, zr, kvs, part, kvsb, A, B, OA, OA, false, outp, stream);
  }
}

// Round 12
// 517.696 us; speedup vs baseline: 1.0327x; 1.0327x over previous
//
#include <hip/hip_runtime.h>
#include <hip/hip_bf16.h>

#define BDIM 4
#define VDIM 20000
#define DDIM 64
#define RDIM 64
#define EDIM 200000
#define BV (BDIM*VDIM)
#define LN_EPS 1e-5f
#define NBB 125           // kvred blocks per batch
#define NTILE 1250        // BV/64 row-tiles
#define NDB 625           // dense blocks per chain (2 tiles each)
#define NRB (VDIM/8)      // rspmm blocks per chain
#define NSC ((EDIM+255)/256)  // scatter blocks (782)
#define NKV (BDIM*NBB)    // kvred blocks (500)

typedef __hip_bfloat16 bf16;
typedef __attribute__((ext_vector_type(8))) short short8v;
typedef __attribute__((ext_vector_type(4))) float floatx4;

__device__ __forceinline__ float ldf(const float* p, size_t i){ return p[i]; }
__device__ __forceinline__ float ldf(const bf16* p, size_t i){ return __bfloat162float(p[i]); }
__device__ __forceinline__ void stf(float* p, size_t i, float v){ p[i] = v; }
__device__ __forceinline__ void stf(bf16* p, size_t i, float v){ p[i] = __float2bfloat16(v); }

__device__ __forceinline__ unsigned short f2b(float f){
  unsigned u = __builtin_bit_cast(unsigned, f);
  u += 0x7fffu + ((u >> 16) & 1u);
  return (unsigned short)(u >> 16);
}
__device__ __forceinline__ float b2f(unsigned short h){
  unsigned u = ((unsigned)h) << 16;
  return __builtin_bit_cast(float, u);
}
__device__ __forceinline__ float4 ldf4(const float* p, size_t i){ return *(const float4*)(p+i); }
__device__ __forceinline__ float4 ldf4(const bf16* p, size_t i){
  ushort4 u = *(const ushort4*)(p+i);
  return make_float4(b2f(u.x), b2f(u.y), b2f(u.z), b2f(u.w));
}
// LDS tile swizzle: element index for [16][64] bf16 tile, 16B-unit XOR on row
__device__ __forceinline__ int swz(int r, int c){ return r*64 + (c ^ ((r & 7) << 3)); }

__device__ __forceinline__ float dot4(float4 a, float4 b){
  return a.x*b.x + a.y*b.y + a.z*b.z + a.w*b.w;
}

// Wave-private LDS ordering: DS ops from one wave execute in order; just fence compiler.
__device__ __forceinline__ void wsync(){
  __builtin_amdgcn_wave_barrier();
  __asm__ volatile("" ::: "memory");
}

__device__ __forceinline__ ushort4 packb(float4 v){
  ushort4 t; t.x = f2b(v.x); t.y = f2b(v.y); t.z = f2b(v.z); t.w = f2b(v.w); return t;
}

// ---- diagnostic fill ----
__global__ void fill_kernel(float* __restrict__ out, float v, int n){
  int t = blockIdx.x * 256 + threadIdx.x;
  if (t < n) out[t] = v;
}

// ---- setup: block 272 = detect64, blocks 0..79 = zero counts, 80..271 = zcalc ----
__global__ void setup_kernel(const int* __restrict__ ei_raw, int* __restrict__ flag,
                             int* __restrict__ counts,
                             const float* __restrict__ z,
                             const float* __restrict__ qkzw, const float* __restrict__ qkzb,
                             const float* __restrict__ vfw,  const float* __restrict__ vfb,
                             float* __restrict__ qk_z, float* __restrict__ zr){
  int bid = blockIdx.x, tid = threadIdx.x;
  if (bid == 272){
    int nz = 0;
    for (int j = 2*tid + 1; j < 1024; j += 512) nz |= (ei_raw[j] != 0);
    nz = __any(nz);
    __shared__ int r[4];
    if ((tid & 63) == 0) r[tid >> 6] = nz;
    __syncthreads();
    if (tid == 0) flag[0] = (r[0] | r[1] | r[2] | r[3]) ? 0 : 1;   // 1 => 64-bit
    return;
  }
  if (bid < 80){
    int i = bid*256 + tid;
    if (i < VDIM + 1) counts[i] = 0;
    return;
  }
  int idx = (bid - 80)*256 + tid;
  if (idx >= 49152) return;
  int which = idx >> 14;
  int r = idx & 16383;
  int b = r >> 12;
  int j = r & 4095;
  const float* wrow; float bias; float* outp;
  if (which == 0){ wrow = qkzw + (size_t)j*DDIM; bias = qkzb[j]; outp = qk_z; }
  else { int i = which - 1; wrow = vfw + (size_t)(i*4096 + j)*DDIM; bias = vfb[i*4096 + j]; outp = zr + i*16384; }
  const float4* zr4 = (const float4*)(z + (size_t)b*DDIM);
  const float4* wr4 = (const float4*)wrow;
  float acc = bias;
  #pragma unroll
  for (int i = 0; i < 16; i++) acc += dot4(zr4[i], wr4[i]);
  outp[r] = acc;
}

// ---- count directly from raw edges (is64-aware) + hi normalize ----
__global__ void prep_count_kernel(const int* __restrict__ ei_raw, const int* __restrict__ hi_raw,
                                  const int* __restrict__ flag,
                                  int* __restrict__ hi, int* __restrict__ counts){
  int is64 = flag[0];
  int e = blockIdx.x * 256 + threadIdx.x;
  if (e < EDIM){
    int dst = is64 ? ei_raw[6*e]   : ei_raw[3*e];
    int rel = is64 ? ei_raw[6*e+2] : ei_raw[3*e+1];
    int src = is64 ? ei_raw[6*e+4] : ei_raw[3*e+2];
    if ((unsigned)dst < VDIM && (unsigned)rel < RDIM && (unsigned)src < VDIM)
      atomicAdd(&counts[dst], 1);
  }
  if (e < BDIM) hi[e] = is64 ? hi_raw[2*e] : hi_raw[e];
}

// ---- scan: per-thread segments + one wave scan, 1 barrier total ----
__global__ void scan_kernel(const int* __restrict__ counts, int* __restrict__ row_ptr, int* __restrict__ cursor){
  __shared__ int wsum[4];
  int tid = threadIdx.x, lane = tid & 63, wid = tid >> 6;
  const int SEG = (VDIM + 255) / 256;        // 79
  int lo = tid * SEG;
  int hi = lo + SEG; if (hi > VDIM) hi = VDIM;
  int s = 0;
  for (int i = lo; i < hi; i++) s += counts[i];
  int x = s;
  #pragma unroll
  for (int o = 1; o < 64; o <<= 1){
    int t = __shfl_up(x, o, 64);
    if (lane >= o) x += t;
  }
  if (lane == 63) wsum[wid] = x;
  __syncthreads();
  int wo = 0;
  for (int w = 0; w < wid; w++) wo += wsum[w];
  int run = wo + x - s;                      // exclusive prefix of this thread's segment
  for (int i = lo; i < hi; i++){
    row_ptr[i] = run; cursor[i] = run; run += counts[i];
  }
  if (tid == 255) row_ptr[VDIM] = run;       // total
}

// ---- fused scatter + init_both: blocks [0,NSC) scatter, [NSC,NSC+NDB) init ----
template<typename T>
__global__ __launch_bounds__(256) void scatter_init_kernel(
    const int* __restrict__ ei_raw, const int* __restrict__ flag,
    int* __restrict__ cursor, int2* __restrict__ pk,
    const float* __restrict__ x, const float* __restrict__ noise, const int* __restrict__ h_index,
    const float* __restrict__ qw1, const float* __restrict__ qb1,
    const float* __restrict__ qw2, const float* __restrict__ qb2,
    const float* __restrict__ vw1, const float* __restrict__ vb1,
    const float* __restrict__ vw2, const float* __restrict__ vb2,
    T* __restrict__ A, T* __restrict__ B){
  if (blockIdx.x < NSC){
    int is64 = flag[0];
    int e = blockIdx.x * 256 + threadIdx.x;
    if (e < EDIM){
      int dst = is64 ? ei_raw[6*e]   : ei_raw[3*e];
      int rel = is64 ? ei_raw[6*e+2] : ei_raw[3*e+1];
      int src = is64 ? ei_raw[6*e+4] : ei_raw[3*e+2];
      if ((unsigned)dst < VDIM && (unsigned)rel < RDIM && (unsigned)src < VDIM){
        int p = atomicAdd(&cursor[dst], 1);
        pk[p] = make_int2(rel, src);
      }
    }
    return;
  }
  __shared__ unsigned short Tl[4][2048];
  __shared__ unsigned short Hl[4][1024];
  __shared__ float Nl[4][32];
  int tid = threadIdx.x, lane = tid & 63, wid = tid >> 6;
  int lr = lane & 15, lg = lane >> 4;
  unsigned short* Tw = Tl[wid];
  unsigned short* Hw = Hl[wid];
  floatx4 zz = {0.f, 0.f, 0.f, 0.f};
  int t0 = (blockIdx.x - NSC)*2;
  // stage both x tiles + noise
  #pragma unroll
  for (int tt = 0; tt < 2; tt++){
    int row0 = (t0 + tt)*64 + wid*16;
    #pragma unroll
    for (int it = 0; it < 4; it++){
      int rl = it*4 + lg;
      size_t gi = (size_t)(row0 + rl)*64 + 4*lr;
      float4 x4 = ldf4(x, gi);
      *(ushort4*)&Tw[tt*1024 + swz(rl, 4*lr)] = packb(x4);
      if (lr == 0) Nl[wid][tt*16 + rl] = noise[row0 + rl];
    }
  }
  wsync();
  short8v a0[2], a1[2];
  #pragma unroll
  for (int tt = 0; tt < 2; tt++){
    a0[tt] = *(const short8v*)&Tw[tt*1024 + swz(lr, lg*8)];
    a1[tt] = *(const short8v*)&Tw[tt*1024 + swz(lr, 32 + lg*8)];
  }
  // ---- qk branch (both tiles) ----
  {
    short8v w1f[4][2], w2f[4][2];
    float wnl[4], b1l[4], b2l[4];
    #pragma unroll
    for (int nt = 0; nt < 4; nt++){
      int col = lr + 16*nt;
      wnl[nt] = qw1[col*65 + 64];
      b1l[nt] = qb1[col]; b2l[nt] = qb2[col];
      #pragma unroll
      for (int ks = 0; ks < 2; ks++){
        const float* p1 = qw1 + col*65 + ks*32 + lg*8;
        const float* p2 = qw2 + col*64 + ks*32 + lg*8;
        short8v f, gg;
        #pragma unroll
        for (int j = 0; j < 8; j++){ f[j] = (short)f2b(p1[j]); gg[j] = (short)f2b(p2[j]); }
        w1f[nt][ks] = f; w2f[nt][ks] = gg;
      }
    }
    #pragma unroll
    for (int tt = 0; tt < 2; tt++){
      int row0 = (t0 + tt)*64 + wid*16;
      float nzq[4];
      #pragma unroll
      for (int q = 0; q < 4; q++) nzq[q] = Nl[wid][tt*16 + lg*4 + q];
      #pragma unroll
      for (int nt = 0; nt < 4; nt++){
        floatx4 acc = zz;
        acc = __builtin_amdgcn_mfma_f32_16x16x32_bf16(a0[tt], w1f[nt][0], acc, 0, 0, 0);
        acc = __builtin_amdgcn_mfma_f32_16x16x32_bf16(a1[tt], w1f[nt][1], acc, 0, 0, 0);
        #pragma unroll
        for (int q = 0; q < 4; q++)
          Hw[swz(lg*4 + q, lr + 16*nt)] = f2b(fmaxf(acc[q] + b1l[nt] + wnl[nt]*nzq[q], 0.f));
      }
      wsync();
      short8v h0 = *(const short8v*)&Hw[swz(lr, lg*8)];
      short8v h1 = *(const short8v*)&Hw[swz(lr, 32 + lg*8)];
      #pragma unroll
      for (int nt = 0; nt < 4; nt++){
        floatx4 acc = zz;
        acc = __builtin_amdgcn_mfma_f32_16x16x32_bf16(h0, w2f[nt][0], acc, 0, 0, 0);
        acc = __builtin_amdgcn_mfma_f32_16x16x32_bf16(h1, w2f[nt][1], acc, 0, 0, 0);
        #pragma unroll
        for (int q = 0; q < 4; q++){
          int rl = lg*4 + q, c = lr + 16*nt;
          stf(A, (size_t)(row0 + rl)*64 + c, acc[q] + b2l[nt]);
        }
      }
      wsync();
    }
  }
  // ---- v branch (both tiles) ----
  {
    short8v w1f[4][2], w2f[4][2];
    float rsvl[4], b1l[4], b2l[4];
    #pragma unroll
    for (int nt = 0; nt < 4; nt++){
      int col = lr + 16*nt;
      b1l[nt] = vb1[col]; b2l[nt] = vb2[col];
      const float4* r4 = (const float4*)(vw1 + col*128 + 64);
      float rsv = 0.f;
      #pragma unroll
      for (int i = 0; i < 16; i++){ float4 t = r4[i]; rsv += t.x + t.y + t.z + t.w; }
      rsvl[nt] = rsv;
      #pragma unroll
      for (int ks = 0; ks < 2; ks++){
        const float* p1 = vw1 + col*128 + ks*32 + lg*8;
        const float* p2 = vw2 + col*64 + ks*32 + lg*8;
        short8v f, gg;
        #pragma unroll
        for (int j = 0; j < 8; j++){ f[j] = (short)f2b(p1[j]); gg[j] = (short)f2b(p2[j]); }
        w1f[nt][ks] = f; w2f[nt][ks] = gg;
      }
    }
    #pragma unroll
    for (int tt = 0; tt < 2; tt++){
      int row0 = (t0 + tt)*64 + wid*16;
      int b = row0 / VDIM;
      int vb = row0 - b*VDIM;
      int hv = h_index[b];
      bool cq[4];
      #pragma unroll
      for (int q = 0; q < 4; q++) cq[q] = (vb + lg*4 + q) == hv;
      #pragma unroll
      for (int nt = 0; nt < 4; nt++){
        floatx4 acc = zz;
        acc = __builtin_amdgcn_mfma_f32_16x16x32_bf16(a0[tt], w1f[nt][0], acc, 0, 0, 0);
        acc = __builtin_amdgcn_mfma_f32_16x16x32_bf16(a1[tt], w1f[nt][1], acc, 0, 0, 0);
        #pragma unroll
        for (int q = 0; q < 4; q++)
          Hw[swz(lg*4 + q, lr + 16*nt)] = f2b(fmaxf(acc[q] + b1l[nt] + (cq[q] ? rsvl[nt] : 0.f), 0.f));
      }
      wsync();
      short8v h0 = *(const short8v*)&Hw[swz(lr, lg*8)];
      short8v h1 = *(const short8v*)&Hw[swz(lr, 32 + lg*8)];
      #pragma unroll
      for (int nt = 0; nt < 4; nt++){
        floatx4 acc = zz;
        acc = __builtin_amdgcn_mfma_f32_16x16x32_bf16(h0, w2f[nt][0], acc, 0, 0, 0);
        acc = __builtin_amdgcn_mfma_f32_16x16x32_bf16(h1, w2f[nt][1], acc, 0, 0, 0);
        #pragma unroll
        for (int q = 0; q < 4; q++){
          int rl = lg*4 + q, c = lr + 16*nt;
          stf(B, (size_t)(row0 + rl)*64 + c, acc[q] + b2l[nt]);
        }
      }
      wsync();
    }
  }
}

// ---- rspmm gather, dual-chain: blocks [0,NRB) = chain A, [NRB,2NRB) = chain B ----
// 8 vertices/block, 4 edges in flight
template<typename T>
__global__ __launch_bounds__(256) void rspmm_dual(
    const int* __restrict__ row_ptr, const int2* __restrict__ pk,
    const float* __restrict__ zA, const float* __restrict__ zB,
    const T* __restrict__ XA, const T* __restrict__ XB,
    T* __restrict__ outA, T* __restrict__ outB){
  int bid = blockIdx.x;
  bool cb = bid >= NRB;
  int v0 = (cb ? bid - NRB : bid) * 8;
  const float* zrel = cb ? zB : zA;
  const T* X = cb ? XB : XA;
  T* out = cb ? outB : outA;
  int btch = threadIdx.x >> 6, d = threadIdx.x & 63;
  int rp[9];
  #pragma unroll
  for (int i = 0; i < 9; i++) rp[i] = row_ptr[v0 + i];
  const float* zb = zrel + btch*RDIM*DDIM + d;
  size_t xb = (size_t)btch*VDIM*64 + d;
  size_t ob = ((size_t)btch*VDIM + v0)*64 + d;
  #pragma unroll 1
  for (int vi = 0; vi < 8; vi++){
    int s = rp[vi], e = rp[vi+1];
    float a0 = 0.f, a1 = 0.f, a2 = 0.f, a3 = 0.f;
    int i = s;
    for (; i + 4 <= e; i += 4){
      int2 e0 = pk[i], e1 = pk[i+1], e2 = pk[i+2], e3 = pk[i+3];
      float x0 = ldf(X, xb + (size_t)e0.y*64);
      float x1 = ldf(X, xb + (size_t)e1.y*64);
      float x2 = ldf(X, xb + (size_t)e2.y*64);
      float x3 = ldf(X, xb + (size_t)e3.y*64);
      a0 += zb[(size_t)e0.x*64] * x0;
      a1 += zb[(size_t)e1.x*64] * x1;
      a2 += zb[(size_t)e2.x*64] * x2;
      a3 += zb[(size_t)e3.x*64] * x3;
    }
    for (; i < e; i++){
      int2 ed = pk[i];
      a0 += zb[(size_t)ed.x*64] * ldf(X, xb + (size_t)ed.y*64);
    }
    stf(out, ob + (size_t)vi*64, a0 + a1 + a2 + a3);
  }
}

// ================= MFMA dense kernels =================
// Per wave: 16-row x 64-col tile. A-frag: lane holds row (lane&15), k-slice (lane>>4).
// B-frag (weights): lane holds W[col=(lane&15)+16nt][k-slice]. C/D: col=lane&15,
// row=(lane>>4)*4+q (m89-verified). LDS tiles [16][64] bf16 with row-XOR swizzle.

// ---- loop body, dual-chain, 2 tiles/block: X = LN(mlp2(O + alpha*X))*ng + nb + X ----
template<typename T>
__global__ __launch_bounds__(256) void loop_dual_kernel(
    const T* __restrict__ OA, T* __restrict__ XA,
    const T* __restrict__ OB, T* __restrict__ XB,
    const float* __restrict__ alA, const float* __restrict__ w1A, const float* __restrict__ b1A,
    const float* __restrict__ w2A, const float* __restrict__ b2A,
    const float* __restrict__ ngA, const float* __restrict__ nbA,
    const float* __restrict__ alB, const float* __restrict__ w1B, const float* __restrict__ b1B,
    const float* __restrict__ w2B, const float* __restrict__ b2B,
    const float* __restrict__ ngB, const float* __restrict__ nbB){
  __shared__ unsigned short Tl[4][2048];
  __shared__ unsigned short Xl[4][2048];
  __shared__ unsigned short Hl[4][1024];
  int bid = blockIdx.x;
  bool cb = bid >= NDB;
  int pb = cb ? bid - NDB : bid;
  const T* O = cb ? OB : OA;
  T* X = cb ? XB : XA;
  const float* alpha = cb ? alB : alA;
  const float* w1 = cb ? w1B : w1A;
  const float* b1 = cb ? b1B : b1A;
  const float* w2 = cb ? w2B : w2A;
  const float* b2 = cb ? b2B : b2A;
  const float* ng = cb ? ngB : ngA;
  const float* nb = cb ? nbB : nbA;
  int tid = threadIdx.x, lane = tid & 63, wid = tid >> 6;
  int lr = lane & 15, lg = lane >> 4;
  short8v w1f[4][2], w2f[4][2];
  #pragma unroll
  for (int nt = 0; nt < 4; nt++){
    int col = lr + 16*nt;
    #pragma unroll
    for (int ks = 0; ks < 2; ks++){
      const float* p1 = w1 + col*64 + ks*32 + lg*8;
      const float* p2 = w2 + col*64 + ks*32 + lg*8;
      short8v f, g;
      #pragma unroll
      for (int j = 0; j < 8; j++){ f[j] = (short)f2b(p1[j]); g[j] = (short)f2b(p2[j]); }
      w1f[nt][ks] = f; w2f[nt][ks] = g;
    }
  }
  float4 al = ((const float4*)alpha)[lr];
  float b1l[4], b2l[4], ngl[4], nbl[4];
  #pragma unroll
  for (int nt = 0; nt < 4; nt++){
    int c = lr + 16*nt;
    b1l[nt] = b1[c]; b2l[nt] = b2[c]; ngl[nt] = ng[c]; nbl[nt] = nb[c];
  }
  unsigned short* Tw = Tl[wid];
  unsigned short* Xw = Xl[wid];
  unsigned short* Hw = Hl[wid];
  floatx4 zz = {0.f, 0.f, 0.f, 0.f};
  int t0 = pb*2;
  // stage both tiles (16 loads in flight)
  #pragma unroll
  for (int tt = 0; tt < 2; tt++){
    int row0 = (t0 + tt)*64 + wid*16;
    #pragma unroll
    for (int it = 0; it < 4; it++){
      int rl = it*4 + lg;
      size_t gi = (size_t)(row0 + rl)*64 + 4*lr;
      float4 xs4 = ldf4(X, gi);
      float4 ov4 = ldf4(O, gi);
      int si = tt*1024 + swz(rl, 4*lr);
      float4 tv;
      tv.x = ov4.x + al.x*xs4.x;
      tv.y = ov4.y + al.y*xs4.y;
      tv.z = ov4.z + al.z*xs4.z;
      tv.w = ov4.w + al.w*xs4.w;
      *(ushort4*)&Tw[si] = packb(tv);
      *(ushort4*)&Xw[si] = packb(xs4);
    }
  }
  wsync();
  #pragma unroll
  for (int tt = 0; tt < 2; tt++){
    int row0 = (t0 + tt)*64 + wid*16;
    short8v a0 = *(const short8v*)&Tw[tt*1024 + swz(lr, lg*8)];
    short8v a1 = *(const short8v*)&Tw[tt*1024 + swz(lr, 32 + lg*8)];
    #pragma unroll
    for (int nt = 0; nt < 4; nt++){
      floatx4 acc = zz;
      acc = __builtin_amdgcn_mfma_f32_16x16x32_bf16(a0, w1f[nt][0], acc, 0, 0, 0);
      acc = __builtin_amdgcn_mfma_f32_16x16x32_bf16(a1, w1f[nt][1], acc, 0, 0, 0);
      #pragma unroll
      for (int q = 0; q < 4; q++)
        Hw[swz(lg*4 + q, lr + 16*nt)] = f2b(fmaxf(acc[q] + b1l[nt], 0.f));
    }
    wsync();
    short8v h0 = *(const short8v*)&Hw[swz(lr, lg*8)];
    short8v h1 = *(const short8v*)&Hw[swz(lr, 32 + lg*8)];
    float y[4][4];
    float s[4] = {0.f,0.f,0.f,0.f}, ss[4] = {0.f,0.f,0.f,0.f};
    #pragma unroll
    for (int nt = 0; nt < 4; nt++){
      floatx4 acc = zz;
      acc = __builtin_amdgcn_mfma_f32_16x16x32_bf16(h0, w2f[nt][0], acc, 0, 0, 0);
      acc = __builtin_amdgcn_mfma_f32_16x16x32_bf16(h1, w2f[nt][1], acc, 0, 0, 0);
      #pragma unroll
      for (int q = 0; q < 4; q++){
        float v = acc[q] + b2l[nt];
        y[nt][q] = v; s[q] += v; ss[q] += v*v;
      }
    }
    #pragma unroll
    for (int o = 1; o < 16; o <<= 1){
      #pragma unroll
      for (int q = 0; q < 4; q++){
        s[q] += __shfl_xor(s[q], o, 64);
        ss[q] += __shfl_xor(ss[q], o, 64);
      }
    }
    float mu[4], rs[4];
    #pragma unroll
    for (int q = 0; q < 4; q++){
      mu[q] = s[q]*(1.f/64.f);
      float var = fmaxf(ss[q]*(1.f/64.f) - mu[q]*mu[q], 0.f);
      rs[q] = rsqrtf(var + LN_EPS);
    }
    #pragma unroll
    for (int nt = 0; nt < 4; nt++){
      #pragma unroll
      for (int q = 0; q < 4; q++){
        int rl = lg*4 + q, c = lr + 16*nt;
        float xs = b2f(Xw[tt*1024 + swz(rl, c)]);
        float v = (y[nt][q] - mu[q])*rs[q]*ngl[nt] + nbl[nt] + xs;
        stf(X, (size_t)(row0 + rl)*64 + c, v);
      }
    }
    wsync();
  }
}

// ---- kvred + qproj fused dispatch: blocks [0,NKV) kvred; [NKV,NKV+NTILE) qproj ----
template<typename T>
__global__ __launch_bounds__(256) void kvred_qproj_kernel(
    const T* __restrict__ Xqk, const T* __restrict__ Xv,
    const float* __restrict__ w, const float* __restrict__ bias,
    float* __restrict__ partial, T* __restrict__ qn_out){
  __shared__ unsigned short T1[4][1024];   // Xqk stage (swz) then kn_t [64][16]
  __shared__ unsigned short T2[4][1024];   // Xv stage (swz)
  __shared__ float red[4*1536];
  int tid = threadIdx.x, lane = tid & 63, wid = tid >> 6;
  int lr = lane & 15, lg = lane >> 4;
  floatx4 zz = {0.f, 0.f, 0.f, 0.f};
  const short8v z8 = {0,0,0,0,0,0,0,0};

  if (blockIdx.x >= NKV){
    // ---- qproj: one 64-row tile of Xqk -> head-normalized q (bf16) ----
    int tile = blockIdx.x - NKV;
    unsigned short* Tw = T1[wid];
    short8v wqf[4][2];
    float bq[4];
    #pragma unroll
    for (int nt = 0; nt < 4; nt++){
      int col = lr + 16*nt;                  // q-half of fc_to_qk
      bq[nt] = bias[col];
      #pragma unroll
      for (int ks = 0; ks < 2; ks++){
        const float* p = w + col*64 + ks*32 + lg*8;
        short8v f;
        #pragma unroll
        for (int j = 0; j < 8; j++) f[j] = (short)f2b(p[j]);
        wqf[nt][ks] = f;
      }
    }
    int row0 = tile*64 + wid*16;
    #pragma unroll
    for (int it = 0; it < 4; it++){
      int rl = it*4 + lg;
      size_t gi = (size_t)(row0 + rl)*64 + 4*lr;
      *(ushort4*)&Tw[swz(rl, 4*lr)] = packb(ldf4(Xqk, gi));
    }
    wsync();
    short8v a0 = *(const short8v*)&Tw[swz(lr, lg*8)];
    short8v a1 = *(const short8v*)&Tw[swz(lr, 32 + lg*8)];
    float qn[4][4];
    #pragma unroll
    for (int nt = 0; nt < 4; nt++){
      floatx4 acc = zz;
      acc = __builtin_amdgcn_mfma_f32_16x16x32_bf16(a0, wqf[nt][0], acc, 0, 0, 0);
      acc = __builtin_amdgcn_mfma_f32_16x16x32_bf16(a1, wqf[nt][1], acc, 0, 0, 0);
      #pragma unroll
      for (int q = 0; q < 4; q++) qn[nt][q] = acc[q] + bq[nt];
    }
    #pragma unroll
    for (int nt = 0; nt < 4; nt++){
      float n0 = qn[nt][0]*qn[nt][0], n1 = qn[nt][1]*qn[nt][1];
      float n2 = qn[nt][2]*qn[nt][2], n3 = qn[nt][3]*qn[nt][3];
      #pragma unroll
      for (int o = 1; o < 16; o <<= 1){
        n0 += __shfl_xor(n0, o, 64); n1 += __shfl_xor(n1, o, 64);
        n2 += __shfl_xor(n2, o, 64); n3 += __shfl_xor(n3, o, 64);
      }
      qn[nt][0] /= fmaxf(sqrtf(n0), 1e-12f);
      qn[nt][1] /= fmaxf(sqrtf(n1), 1e-12f);
      qn[nt][2] /= fmaxf(sqrtf(n2), 1e-12f);
      qn[nt][3] /= fmaxf(sqrtf(n3), 1e-12f);
    }
    #pragma unroll
    for (int nt = 0; nt < 4; nt++)
      #pragma unroll
      for (int q = 0; q < 4; q++)
        stf(qn_out, (size_t)(row0 + lg*4 + q)*64 + lr + 16*nt, qn[nt][q]);
    return;
  }

  // ---- kvred ----
  short8v wkf[4][2];
  #pragma unroll
  for (int nt = 0; nt < 4; nt++){
    int col = 64 + lr + 16*nt;               // k-half of fc_to_qk
    #pragma unroll
    for (int ks = 0; ks < 2; ks++){
      const float* p = w + col*64 + ks*32 + lg*8;
      short8v f;
      #pragma unroll
      for (int j = 0; j < 8; j++) f[j] = (short)f2b(p[j]);
      wkf[nt][ks] = f;
    }
  }
  float bk[4];
  #pragma unroll
  for (int nt = 0; nt < 4; nt++) bk[nt] = bias[64 + lr + 16*nt];
  int b = blockIdx.x / NBB, blk = blockIdx.x % NBB;
  unsigned short* Tw = T1[wid];
  unsigned short* Vw = T2[wid];
  floatx4 kvacc[4] = {zz, zz, zz, zz};
  float ksp[4] = {0.f,0.f,0.f,0.f};
  float vsp[4] = {0.f,0.f,0.f,0.f};
  for (int st = blk*4 + wid; st < 1250; st += NBB*4){
    size_t gr = (size_t)b*VDIM + (size_t)st*16;
    #pragma unroll
    for (int it = 0; it < 4; it++){
      int rl = it*4 + lg;
      size_t gi = (gr + rl)*64 + 4*lr;
      float4 xq4 = ldf4(Xqk, gi);
      float4 xv4 = ldf4(Xv, gi);
      int si = swz(rl, 4*lr);
      *(ushort4*)&Tw[si] = packb(xq4);
      *(ushort4*)&Vw[si] = packb(xv4);
      vsp[0] += xv4.x; vsp[1] += xv4.y; vsp[2] += xv4.z; vsp[3] += xv4.w;
    }
    wsync();
    short8v a0 = *(const short8v*)&Tw[swz(lr, lg*8)];
    short8v a1 = *(const short8v*)&Tw[swz(lr, 32 + lg*8)];
    // k-projection + head norm -> kn (C-layout regs), store kn_t to T1
    float kn[4][4];
    #pragma unroll
    for (int nt = 0; nt < 4; nt++){
      floatx4 acc = zz;
      acc = __builtin_amdgcn_mfma_f32_16x16x32_bf16(a0, wkf[nt][0], acc, 0, 0, 0);
      acc = __builtin_amdgcn_mfma_f32_16x16x32_bf16(a1, wkf[nt][1], acc, 0, 0, 0);
      #pragma unroll
      for (int q = 0; q < 4; q++) kn[nt][q] = acc[q] + bk[nt];
    }
    #pragma unroll
    for (int nt = 0; nt < 4; nt++){
      float n0 = kn[nt][0]*kn[nt][0], n1 = kn[nt][1]*kn[nt][1];
      float n2 = kn[nt][2]*kn[nt][2], n3 = kn[nt][3]*kn[nt][3];
      #pragma unroll
      for (int o = 1; o < 16; o <<= 1){
        n0 += __shfl_xor(n0, o, 64); n1 += __shfl_xor(n1, o, 64);
        n2 += __shfl_xor(n2, o, 64); n3 += __shfl_xor(n3, o, 64);
      }
      kn[nt][0] /= fmaxf(sqrtf(n0), 1e-12f);
      kn[nt][1] /= fmaxf(sqrtf(n1), 1e-12f);
      kn[nt][2] /= fmaxf(sqrtf(n2), 1e-12f);
      kn[nt][3] /= fmaxf(sqrtf(n3), 1e-12f);
      ksp[nt] += kn[nt][0] + kn[nt][1] + kn[nt][2] + kn[nt][3];
    }
    wsync();   // a0/a1 consumed; safe to overwrite T1 with kn_t
    #pragma unroll
    for (int nt = 0; nt < 4; nt++){
      int c = lr + 16*nt;
      #pragma unroll
      for (int q = 0; q < 4; q++)
        Tw[c*16 + lg*4 + q] = f2b(kn[nt][q]);
    }
    wsync();
    // kv += kn^T (A) x vx (B), per head, K=16 rows zero-padded to 32
    #pragma unroll
    for (int nt = 0; nt < 4; nt++){
      short8v af = z8, bf = z8;
      if (lg < 2){
        af = *(const short8v*)&Tw[(nt*16 + lr)*16 + lg*8];
        #pragma unroll
        for (int j = 0; j < 8; j++)
          bf[j] = (short)Vw[swz(lg*8 + j, nt*16 + lr)];
      }
      kvacc[nt] = __builtin_amdgcn_mfma_f32_16x16x32_bf16(af, bf, kvacc[nt], 0, 0, 0);
    }
    wsync();   // LDS reads done before next stripe overwrites tiles
  }
  // write per-wave partials
  float* rw = red + wid*1536;
  #pragma unroll
  for (int nt = 0; nt < 4; nt++){
    #pragma unroll
    for (int q = 0; q < 4; q++)
      rw[(nt*16 + lg*4 + q)*16 + lr] = kvacc[nt][q];
    rw[1024 + lg*64 + lr + 16*nt] = ksp[nt];
  }
  #pragma unroll
  for (int m = 0; m < 4; m++)
    rw[1280 + lg*64 + 4*lr + m] = vsp[m];
  __syncthreads();
  float* P = partial + (size_t)blockIdx.x*1152;
  for (int j = tid; j < 1152; j += 256){
    float s = 0.f;
    if (j < 1024){
      #pragma unroll
      for (int wv = 0; wv < 4; wv++) s += red[wv*1536 + j];
    } else if (j < 1088){
      int c = j - 1024;
      #pragma unroll
      for (int wv = 0; wv < 4; wv++)
        #pragma unroll
        for (int gg = 0; gg < 4; gg++) s += red[wv*1536 + 1024 + gg*64 + c];
    } else {
      int c = j - 1088;
      #pragma unroll
      for (int wv = 0; wv < 4; wv++)
        #pragma unroll
        for (int gg = 0; gg < 4; gg++) s += red[wv*1536 + 1280 + gg*64 + c];
    }
    P[j] = s;
  }
}

// ---- reduce kvred partials; also emit bf16 copies for attn fragments ----
__global__ void qkred_kernel(const float* __restrict__ partial,
                             float* __restrict__ kvs, float* __restrict__ ksum, float* __restrict__ vsum,
                             unsigned short* __restrict__ kvsb, unsigned short* __restrict__ ksb){
  int b = blockIdx.x / 5, ch = blockIdx.x % 5;
  int j = ch*256 + threadIdx.x;
  if (j >= 1152) return;
  const float* P = partial + (size_t)b*NBB*1152;
  float s = 0.f;
  for (int t = 0; t < NBB; t++) s += P[(size_t)t*1152 + j];
  if (j < 1024){      kvs[b*1024 + j] = s; kvsb[b*1024 + j] = f2b(s); }
  else if (j < 1088){ ksum[b*64 + (j-1024)] = s; ksb[b*64 + (j-1024)] = f2b(s); }
  else                vsum[b*64 + (j-1088)] = s;
}

// ---- fused attention + final FFN, 2 tiles/block; qn precomputed (no q-proj) ----
template<typename T>
__global__ __launch_bounds__(256) void attn_final_kernel(
    const float* __restrict__ x, const T* __restrict__ QN, const T* __restrict__ Xv,
    const unsigned short* __restrict__ kvsb, const unsigned short* __restrict__ ksb,
    const float* __restrict__ vsum,
    const float* __restrict__ ag, const float* __restrict__ ab,
    const float* __restrict__ fw1, const float* __restrict__ fb1,
    const float* __restrict__ fw2, const float* __restrict__ fb2,
    const float* __restrict__ g, const float* __restrict__ bb,
    float* __restrict__ out){
  __shared__ unsigned short Ql[4][2048];
  __shared__ unsigned short Hl[4][1024];
  int tid = threadIdx.x, lane = tid & 63, wid = tid >> 6;
  int lr = lane & 15, lg = lane >> 4;
  // FFN weights
  short8v f1f[4][2], f2f[4][2];
  float agl[4], abl[4], b1l[4], b2l[4], gl[4], bl[4];
  #pragma unroll
  for (int nt = 0; nt < 4; nt++){
    int col = lr + 16*nt;
    agl[nt] = ag[col]; abl[nt] = ab[col];
    b1l[nt] = fb1[col]; b2l[nt] = fb2[col]; gl[nt] = g[col]; bl[nt] = bb[col];
    #pragma unroll
    for (int ks = 0; ks < 2; ks++){
      const float* p1 = fw1 + col*64 + ks*32 + lg*8;
      const float* p2 = fw2 + col*64 + ks*32 + lg*8;
      short8v f, gg;
      #pragma unroll
      for (int j = 0; j < 8; j++){ f[j] = (short)f2b(p1[j]); gg[j] = (short)f2b(p2[j]); }
      f1f[nt][ks] = f; f2f[nt][ks] = gg;
    }
  }
  unsigned short* Qw = Ql[wid];
  unsigned short* Hw = Hl[wid];
  floatx4 zz = {0.f, 0.f, 0.f, 0.f};
  const short8v z8 = {0,0,0,0,0,0,0,0};
  int t0 = blockIdx.x*2;
  // stage both qn tiles (already bf16)
  #pragma unroll
  for (int tt = 0; tt < 2; tt++){
    int row0 = (t0 + tt)*64 + wid*16;
    #pragma unroll
    for (int it = 0; it < 4; it++){
      int rl = it*4 + lg;
      size_t gi = (size_t)(row0 + rl)*64 + 4*lr;
      *(ushort4*)&Qw[tt*1024 + swz(rl, 4*lr)] = *(const ushort4*)&QN[gi];
    }
  }
  wsync();
  #pragma unroll
  for (int tt = 0; tt < 2; tt++){
    int row0 = (t0 + tt)*64 + wid*16;
    int b = row0 / VDIM;                     // wave-uniform (16 | 20000)
    // per-head attention: num/den via zero-padded 16x16x32 MFMAs; kv frags from global
    float y[4][4];
    float s[4] = {0.f,0.f,0.f,0.f}, ss[4] = {0.f,0.f,0.f,0.f};
    #pragma unroll
    for (int nt = 0; nt < 4; nt++){
      short8v af = z8, bn = z8, bd = z8;
      if (lg < 2){
        af = *(const short8v*)&Qw[tt*1024 + swz(lr, nt*16 + lg*8)];
        bd = *(const short8v*)&ksb[b*64 + nt*16 + lg*8];
        #pragma unroll
        for (int j = 0; j < 8; j++)
          bn[j] = (short)kvsb[b*1024 + (nt*16 + lg*8 + j)*16 + lr];
      }
      int c = lr + 16*nt;
      float vsb = vsum[b*64 + c];
      floatx4 numc, denc;
      #pragma unroll
      for (int q = 0; q < 4; q++){
        float vv = ldf(Xv, (size_t)(row0 + lg*4 + q)*64 + c);
        numc[q] = vsb + vv*(float)VDIM;
        denc[q] = 2.0f*(float)VDIM;
      }
      numc = __builtin_amdgcn_mfma_f32_16x16x32_bf16(af, bn, numc, 0, 0, 0);
      denc = __builtin_amdgcn_mfma_f32_16x16x32_bf16(af, bd, denc, 0, 0, 0);
      #pragma unroll
      for (int q = 0; q < 4; q++){
        float xv = x[(size_t)(row0 + lg*4 + q)*64 + c];
        float v = xv + numc[q]/denc[q];
        y[nt][q] = v; s[q] += v; ss[q] += v*v;
      }
    }
    #pragma unroll
    for (int o = 1; o < 16; o <<= 1){
      #pragma unroll
      for (int q = 0; q < 4; q++){
        s[q] += __shfl_xor(s[q], o, 64);
        ss[q] += __shfl_xor(ss[q], o, 64);
      }
    }
    #pragma unroll
    for (int q = 0; q < 4; q++){
      float mu = s[q]*(1.f/64.f);
      float var = fmaxf(ss[q]*(1.f/64.f) - mu*mu, 0.f);
      float rs = rsqrtf(var + LN_EPS);
      #pragma unroll
      for (int nt = 0; nt < 4; nt++)
        y[nt][q] = (y[nt][q] - mu)*rs*agl[nt] + abl[nt];
    }
    // FFN + LN2 (residual y in regs)
    wsync();   // per-head Qw reads done; overwrite tile-tt with xa
    #pragma unroll
    for (int nt = 0; nt < 4; nt++){
      #pragma unroll
      for (int q = 0; q < 4; q++)
        Qw[tt*1024 + swz(lg*4 + q, lr + 16*nt)] = f2b(y[nt][q]);
    }
    wsync();
    short8v xa0 = *(const short8v*)&Qw[tt*1024 + swz(lr, lg*8)];
    short8v xa1 = *(const short8v*)&Qw[tt*1024 + swz(lr, 32 + lg*8)];
    #pragma unroll
    for (int nt = 0; nt < 4; nt++){
      floatx4 acc = zz;
      acc = __builtin_amdgcn_mfma_f32_16x16x32_bf16(xa0, f1f[nt][0], acc, 0, 0, 0);
      acc = __builtin_amdgcn_mfma_f32_16x16x32_bf16(xa1, f1f[nt][1], acc, 0, 0, 0);
      #pragma unroll
      for (int q = 0; q < 4; q++)
        Hw[swz(lg*4 + q, lr + 16*nt)] = f2b(fmaxf(acc[q] + b1l[nt], 0.f));
    }
    wsync();
    short8v h0 = *(const short8v*)&Hw[swz(lr, lg*8)];
    short8v h1 = *(const short8v*)&Hw[swz(lr, 32 + lg*8)];
    float t[4][4];
    float s2[4] = {0.f,0.f,0.f,0.f}, ss2[4] = {0.f,0.f,0.f,0.f};
    #pragma unroll
    for (int nt = 0; nt < 4; nt++){
      floatx4 acc = zz;
      acc = __builtin_amdgcn_mfma_f32_16x16x32_bf16(h0, f2f[nt][0], acc, 0, 0, 0);
      acc = __builtin_amdgcn_mfma_f32_16x16x32_bf16(h1, f2f[nt][1], acc, 0, 0, 0);
      #pragma unroll
      for (int q = 0; q < 4; q++){
        float v = acc[q] + b2l[nt] + y[nt][q];
        t[nt][q] = v; s2[q] += v; ss2[q] += v*v;
      }
    }
    #pragma unroll
    for (int o = 1; o < 16; o <<= 1){
      #pragma unroll
      for (int q = 0; q < 4; q++){
        s2[q] += __shfl_xor(s2[q], o, 64);
        ss2[q] += __shfl_xor(ss2[q], o, 64);
      }
    }
    #pragma unroll
    for (int q = 0; q < 4; q++){
      float mu = s2[q]*(1.f/64.f);
      float var = fmaxf(ss2[q]*(1.f/64.f) - mu*mu, 0.f);
      float rs = rsqrtf(var + LN_EPS);
      #pragma unroll
      for (int nt = 0; nt < 4; nt++){
        int c = lr + 16*nt;
        out[(size_t)(row0 + lg*4 + q)*64 + c] = (t[nt][q] - mu)*rs*gl[nt] + bl[nt];
      }
    }
    wsync();   // Hw reused by next tile
  }
}

// ================= host side =================
static const int DICT_SIZES[42] = {
  5120000,256,256,80000,262144,4096,4160,64,4096,64,
  8192,64,4096,64,8192,128,8192,128,8192,128,
  128,128,128,524288,8192,8192,128,8192,128,128,
  128,128,4096,64,4096,64,64,64,64,64,
  4,600000};

template<typename T>
static void run_pipeline(const float* const* N, const int* hi,
                         const int* ei_raw, const int* eflag,
                         int* cursor, int2* pk, const int* row_ptr,
                         float* qk_z, float* zr, float* kvs, float* part,
                         unsigned short* kvsb,
                         T* A, T* B, T* OA, T* OB, bool dual,
                         float* outp, hipStream_t stream){
  float* ksum = kvs + 4096;
  float* vsum = kvs + 4352;
  unsigned short* ksb = kvsb + 4096;

  // fused: scatter (needs scan done) + init_both (independent) in one dispatch
  scatter_init_kernel<T><<<NSC + NDB, 256, 0, stream>>>(ei_raw, eflag, cursor, pk,
      N[0], N[3], hi, N[6], N[7], N[8], N[9], N[10], N[11], N[12], N[13], A, B);

  if (dual){
    for (int i = 0; i < 2; i++){
      rspmm_dual<T><<<2*NRB, 256, 0, stream>>>(row_ptr, pk, qk_z, zr + i*16384, A, B, OA, OB);
      loop_dual_kernel<T><<<2*NDB, 256, 0, stream>>>(OA, A, OB, B,
          N[20] + i*64, N[16] + i*4096, N[17] + i*64, N[18] + i*4096, N[19] + i*64, N[21] + i*64, N[22] + i*64,
          N[29] + i*64, N[25] + i*4096, N[26] + i*64, N[27] + i*4096, N[28] + i*64, N[30] + i*64, N[31] + i*64);
    }
  } else {
    for (int i = 0; i < 2; i++){
      rspmm_dual<T><<<NRB, 256, 0, stream>>>(row_ptr, pk, qk_z, qk_z, A, A, OA, OA);
      loop_dual_kernel<T><<<NDB, 256, 0, stream>>>(OA, A, OA, A,
          N[20] + i*64, N[16] + i*4096, N[17] + i*64, N[18] + i*4096, N[19] + i*64, N[21] + i*64, N[22] + i*64,
          N[20] + i*64, N[16] + i*4096, N[17] + i*64, N[18] + i*4096, N[19] + i*64, N[21] + i*64, N[22] + i*64);
    }
    for (int i = 0; i < 2; i++){
      rspmm_dual<T><<<NRB, 256, 0, stream>>>(row_ptr, pk, zr + i*16384, zr + i*16384, B, B, OA, OA);
      loop_dual_kernel<T><<<NDB, 256, 0, stream>>>(OA, B, OA, B,
          N[29] + i*64, N[25] + i*4096, N[26] + i*64, N[27] + i*4096, N[28] + i*64, N[30] + i*64, N[31] + i*64,
          N[29] + i*64, N[25] + i*4096, N[26] + i*64, N[27] + i*4096, N[28] + i*64, N[30] + i*64, N[31] + i*64);
    }
  }

  // kvred + q-projection (independent block ranges) in one dispatch; qn -> OA (free)
  kvred_qproj_kernel<T><<<NKV + NTILE, 256, 0, stream>>>(A, B, N[14], N[15], part, OA);
  qkred_kernel<<<20, 256, 0, stream>>>(part, kvs, ksum, vsum, kvsb, ksb);
  attn_final_kernel<T><<<NDB, 256, 0, stream>>>(N[0], OA, B, kvsb, ksb, vsum,
      N[36], N[37], N[32], N[33], N[34], N[35], N[38], N[39], outp);
}

extern "C" void kernel_launch(void* const* d_in, const int* in_sizes, int n_in,
                              void* d_out, int out_size, void* d_ws, size_t ws_size,
                              hipStream_t stream){
  float* outp = (float*)d_out;
  const int GOUT = (out_size + 255) / 256;

  if (n_in != 42){
    fill_kernel<<<GOUT, 256, 0, stream>>>(outp, 2000.0f + (float)n_in, out_size);
    return;
  }
  auto sz_ok = [&](int s, int e)->bool{
    if (s == e) return true;
    if ((e == 4 || e == 600000) && s == 2*e) return true;
    return false;
  };
  int bad = -1;
  for (int i = 0; i < 42 && bad < 0; i++)
    if (!sz_ok(in_sizes[i], DICT_SIZES[i])) bad = i;
  if (bad >= 0){
    fill_kernel<<<GOUT, 256, 0, stream>>>(outp, 1000.0f + (float)bad, out_size);
    return;
  }

  const float* N[40];
  for (int i = 0; i < 40; i++) N[i] = (const float*)d_in[i];
  const int* hi_raw = (const int*)d_in[40];
  const int* ei_raw = (const int*)d_in[41];

  char* p = (char*)d_ws;
  auto alloc = [&](size_t bytes)->char*{ char* r = p; p += (bytes + 255) / 256 * 256; return r; };
  int* hi      = (int*)alloc(256);
  int* eflag   = (int*)alloc(256);
  int* counts  = (int*)alloc((VDIM+1)*4);
  int* row_ptr = (int*)alloc((VDIM+1)*4);
  int* cursor  = (int*)alloc((VDIM+1)*4);
  int2* pk     = (int2*)alloc((size_t)EDIM*8);
  float* qk_z  = (float*)alloc(16384u*4);
  float* zr    = (float*)alloc(32768u*4);
  float* kvs   = (float*)alloc(4608u*4);
  unsigned short* kvsb = (unsigned short*)alloc(4352u*2);
  float* part  = (float*)alloc((size_t)BDIM*NBB*1152*4);
  size_t fixed = (size_t)(p - (char*)d_ws);
  const size_t bufH = (size_t)BV*64*2;

  // setup: detect64 + zero counts + zcalc, one dispatch
  setup_kernel<<<273, 256, 0, stream>>>(ei_raw, eflag, counts,
      N[1], N[4], N[5], N[23], N[24], qk_z, zr);
  prep_count_kernel<<<(EDIM+255)/256, 256, 0, stream>>>(ei_raw, hi_raw, eflag, hi, counts);
  scan_kernel<<<1, 256, 0, stream>>>(counts, row_ptr, cursor);

  // bf16 workspace: halves intermediate traffic, makes rspmm X L2-resident.
  if (ws_size >= fixed + 4*bufH + 1024){
    bf16* A  = (bf16*)alloc(bufH);
    bf16* B  = (bf16*)alloc(bufH);
    bf16* OA = (bf16*)alloc(bufH);
    bf16* OB = (bf16*)alloc(bufH);
    run_pipeline<bf16>(N, hi, ei_raw, eflag, cursor, pk, row_ptr,
                       qk_z, zr, kvs, part, kvsb, A, B, OA, OB, true, outp, stream);
  } else {
    bf16* A  = (bf16*)alloc(bufH);
    bf16* B  = (bf16*)alloc(bufH);
    bf16* OA = (bf16*)alloc(bufH);
    run_pipeline<bf16>(N, hi, ei_raw, eflag, cursor, pk, row_ptr,
                       qk_z, zr, kvs, part, kvsb, A, B, OA, OA, false, outp, stream);
  }
}

// Round 13
// 446.321 us; speedup vs baseline: 1.1979x; 1.1599x over previous
//
#include <hip/hip_runtime.h>
#include <hip/hip_bf16.h>

#define BDIM 4
#define VDIM 20000
#define DDIM 64
#define RDIM 64
#define EDIM 200000
#define BV (BDIM*VDIM)
#define LN_EPS 1e-5f
#define NBB 125           // kvred blocks per batch
#define NTILE 1250        // BV/64 row-tiles
#define NDB 625           // dense blocks per chain (2 tiles each)
#define NRB4 (VDIM/4)     // rspmm blocks per chain (4 vertices each)
#define NSC ((EDIM+255)/256)  // scatter blocks (782)
#define NKV (BDIM*NBB)    // kvred blocks (500)

// bf16 weight buffer element offsets (all multiples of 8)
#define WB_QKW1 0         // [2][64][64]
#define WB_QKW2 8192
#define WB_VW1  16384
#define WB_VW2  24576
#define WB_IQW1 32768     // [64][64] (noise col dropped)
#define WB_IQW2 36928     // [64][64]  (36864..36928 unused pad)
#define WB_IVW1 41024     // [64][128]
#define WB_IVW2 49216
#define WB_QK   53312     // [128][64]
#define WB_FW1  61504
#define WB_FW2  65600
#define WB_TOT  69696
#define WC_TOT  69760     // + 64 rsv sums

typedef __hip_bfloat16 bf16;
typedef __attribute__((ext_vector_type(8))) short short8v;
typedef __attribute__((ext_vector_type(4))) float floatx4;

__device__ __forceinline__ float ldf(const float* p, size_t i){ return p[i]; }
__device__ __forceinline__ float ldf(const bf16* p, size_t i){ return __bfloat162float(p[i]); }
__device__ __forceinline__ void stf(float* p, size_t i, float v){ p[i] = v; }
__device__ __forceinline__ void stf(bf16* p, size_t i, float v){ p[i] = __float2bfloat16(v); }

__device__ __forceinline__ unsigned short f2b(float f){
  unsigned u = __builtin_bit_cast(unsigned, f);
  u += 0x7fffu + ((u >> 16) & 1u);
  return (unsigned short)(u >> 16);
}
__device__ __forceinline__ float b2f(unsigned short h){
  unsigned u = ((unsigned)h) << 16;
  return __builtin_bit_cast(float, u);
}
__device__ __forceinline__ float4 ldf4(const float* p, size_t i){ return *(const float4*)(p+i); }
__device__ __forceinline__ float4 ldf4(const bf16* p, size_t i){
  ushort4 u = *(const ushort4*)(p+i);
  return make_float4(b2f(u.x), b2f(u.y), b2f(u.z), b2f(u.w));
}
// LDS tile swizzle: element index for [16][64] bf16 tile, 16B-unit XOR on row
__device__ __forceinline__ int swz(int r, int c){ return r*64 + (c ^ ((r & 7) << 3)); }

__device__ __forceinline__ float dot4(float4 a, float4 b){
  return a.x*b.x + a.y*b.y + a.z*b.z + a.w*b.w;
}

// Wave-private LDS ordering: DS ops from one wave execute in order; just fence compiler.
__device__ __forceinline__ void wsync(){
  __builtin_amdgcn_wave_barrier();
  __asm__ volatile("" ::: "memory");
}

__device__ __forceinline__ ushort4 packb(float4 v){
  ushort4 t; t.x = f2b(v.x); t.y = f2b(v.y); t.z = f2b(v.z); t.w = f2b(v.w); return t;
}

// ---- diagnostic fill ----
__global__ void fill_kernel(float* __restrict__ out, float v, int n){
  int t = blockIdx.x * 256 + threadIdx.x;
  if (t < n) out[t] = v;
}

// ---- setup: blocks 0..79 zero counts, 80..271 zcalc, 272 detect, 273.. weight conv ----
__global__ void setup_kernel(const int* __restrict__ ei_raw, int* __restrict__ flag,
                             int* __restrict__ counts,
                             const float* __restrict__ z,
                             const float* __restrict__ qkzw, const float* __restrict__ qkzb,
                             const float* __restrict__ vfw,  const float* __restrict__ vfb,
                             float* __restrict__ qk_z, float* __restrict__ zr,
                             const float* __restrict__ qkw1, const float* __restrict__ qkw2,
                             const float* __restrict__ vw1l, const float* __restrict__ vw2l,
                             const float* __restrict__ iqw1, const float* __restrict__ iqw2,
                             const float* __restrict__ ivw1, const float* __restrict__ ivw2,
                             const float* __restrict__ qkpw, const float* __restrict__ fw1,
                             const float* __restrict__ fw2,
                             unsigned short* __restrict__ wb, float* __restrict__ rsvb){
  int bid = blockIdx.x, tid = threadIdx.x;
  if (bid >= 273){
    int e = (bid - 273)*256 + tid;
    if (e >= WC_TOT) return;
    if (e >= WB_TOT){
      int col = e - WB_TOT;
      const float4* r4 = (const float4*)(ivw1 + col*128 + 64);
      float rsv = 0.f;
      #pragma unroll
      for (int i = 0; i < 16; i++){ float4 t = r4[i]; rsv += t.x + t.y + t.z + t.w; }
      rsvb[col] = rsv;
      return;
    }
    float v;
    if (e < WB_QKW2)        v = qkw1[e];
    else if (e < WB_VW1)    v = qkw2[e - WB_QKW2];
    else if (e < WB_VW2)    v = vw1l[e - WB_VW1];
    else if (e < WB_IQW1)   v = vw2l[e - WB_VW2];
    else if (e < 36864){ int j = e - WB_IQW1; v = iqw1[(j>>6)*65 + (j&63)]; }
    else if (e < WB_IQW2)   v = 0.f;                      // pad
    else if (e < WB_IVW1)   v = iqw2[e - WB_IQW2];
    else if (e < WB_IVW2)   v = ivw1[e - WB_IVW1];
    else if (e < WB_QK)     v = ivw2[e - WB_IVW2];
    else if (e < WB_FW1)    v = qkpw[e - WB_QK];
    else if (e < WB_FW2)    v = fw1[e - WB_FW1];
    else                    v = fw2[e - WB_FW2];
    wb[e] = f2b(v);
    return;
  }
  if (bid == 272){
    int nz = 0;
    for (int j = 2*tid + 1; j < 1024; j += 512) nz |= (ei_raw[j] != 0);
    nz = __any(nz);
    __shared__ int r[4];
    if ((tid & 63) == 0) r[tid >> 6] = nz;
    __syncthreads();
    if (tid == 0) flag[0] = (r[0] | r[1] | r[2] | r[3]) ? 0 : 1;   // 1 => 64-bit
    return;
  }
  if (bid < 80){
    int i = bid*256 + tid;
    if (i < VDIM + 1) counts[i] = 0;
    return;
  }
  int idx = (bid - 80)*256 + tid;
  if (idx >= 49152) return;
  int which = idx >> 14;
  int r = idx & 16383;
  int b = r >> 12;
  int j = r & 4095;
  const float* wrow; float bias; float* outp;
  if (which == 0){ wrow = qkzw + (size_t)j*DDIM; bias = qkzb[j]; outp = qk_z; }
  else { int i = which - 1; wrow = vfw + (size_t)(i*4096 + j)*DDIM; bias = vfb[i*4096 + j]; outp = zr + i*16384; }
  const float4* zr4 = (const float4*)(z + (size_t)b*DDIM);
  const float4* wr4 = (const float4*)wrow;
  float acc = bias;
  #pragma unroll
  for (int i = 0; i < 16; i++) acc += dot4(zr4[i], wr4[i]);
  outp[r] = acc;
}

// ---- count directly from raw edges (is64-aware) + hi normalize ----
__global__ void prep_count_kernel(const int* __restrict__ ei_raw, const int* __restrict__ hi_raw,
                                  const int* __restrict__ flag,
                                  int* __restrict__ hi, int* __restrict__ counts){
  int is64 = flag[0];
  int e = blockIdx.x * 256 + threadIdx.x;
  if (e < EDIM){
    int dst = is64 ? ei_raw[6*e]   : ei_raw[3*e];
    int rel = is64 ? ei_raw[6*e+2] : ei_raw[3*e+1];
    int src = is64 ? ei_raw[6*e+4] : ei_raw[3*e+2];
    if ((unsigned)dst < VDIM && (unsigned)rel < RDIM && (unsigned)src < VDIM)
      atomicAdd(&counts[dst], 1);
  }
  if (e < BDIM) hi[e] = is64 ? hi_raw[2*e] : hi_raw[e];
}

// ---- scan: per-thread segments + one wave scan, 1 barrier total ----
__global__ void scan_kernel(const int* __restrict__ counts, int* __restrict__ row_ptr, int* __restrict__ cursor){
  __shared__ int wsum[4];
  int tid = threadIdx.x, lane = tid & 63, wid = tid >> 6;
  const int SEG = (VDIM + 255) / 256;        // 79
  int lo = tid * SEG;
  int hi = lo + SEG; if (hi > VDIM) hi = VDIM;
  int s = 0;
  for (int i = lo; i < hi; i++) s += counts[i];
  int x = s;
  #pragma unroll
  for (int o = 1; o < 64; o <<= 1){
    int t = __shfl_up(x, o, 64);
    if (lane >= o) x += t;
  }
  if (lane == 63) wsum[wid] = x;
  __syncthreads();
  int wo = 0;
  for (int w = 0; w < wid; w++) wo += wsum[w];
  int run = wo + x - s;                      // exclusive prefix of this thread's segment
  for (int i = lo; i < hi; i++){
    row_ptr[i] = run; cursor[i] = run; run += counts[i];
  }
  if (tid == 255) row_ptr[VDIM] = run;       // total
}

// ---- fused scatter + init_both: blocks [0,NSC) scatter, [NSC,NSC+NDB) init ----
__global__ __launch_bounds__(256) void scatter_init_kernel(
    const int* __restrict__ ei_raw, const int* __restrict__ flag,
    int* __restrict__ cursor, int2* __restrict__ pk,
    const float* __restrict__ x, const float* __restrict__ noise, const int* __restrict__ h_index,
    const unsigned short* __restrict__ wb, const float* __restrict__ rsvb,
    const float* __restrict__ iqw1f, const float* __restrict__ qb1, const float* __restrict__ qb2,
    const float* __restrict__ vb1, const float* __restrict__ vb2,
    bf16* __restrict__ A, bf16* __restrict__ B){
  if (blockIdx.x < NSC){
    int is64 = flag[0];
    int e = blockIdx.x * 256 + threadIdx.x;
    if (e < EDIM){
      int dst = is64 ? ei_raw[6*e]   : ei_raw[3*e];
      int rel = is64 ? ei_raw[6*e+2] : ei_raw[3*e+1];
      int src = is64 ? ei_raw[6*e+4] : ei_raw[3*e+2];
      if ((unsigned)dst < VDIM && (unsigned)rel < RDIM && (unsigned)src < VDIM){
        int p = atomicAdd(&cursor[dst], 1);
        pk[p] = make_int2(rel, src);
      }
    }
    return;
  }
  __shared__ unsigned short Tl[4][2048];
  __shared__ unsigned short Hl[4][1024];
  __shared__ float Nl[4][32];
  int tid = threadIdx.x, lane = tid & 63, wid = tid >> 6;
  int lr = lane & 15, lg = lane >> 4;
  unsigned short* Tw = Tl[wid];
  unsigned short* Hw = Hl[wid];
  floatx4 zz = {0.f, 0.f, 0.f, 0.f};
  int t0 = (blockIdx.x - NSC)*2;
  // stage both x tiles + noise
  #pragma unroll
  for (int tt = 0; tt < 2; tt++){
    int row0 = (t0 + tt)*64 + wid*16;
    #pragma unroll
    for (int it = 0; it < 4; it++){
      int rl = it*4 + lg;
      size_t gi = (size_t)(row0 + rl)*64 + 4*lr;
      float4 x4 = ldf4(x, gi);
      *(ushort4*)&Tw[tt*1024 + swz(rl, 4*lr)] = packb(x4);
      if (lr == 0) Nl[wid][tt*16 + rl] = noise[row0 + rl];
    }
  }
  wsync();
  short8v a0[2], a1[2];
  #pragma unroll
  for (int tt = 0; tt < 2; tt++){
    a0[tt] = *(const short8v*)&Tw[tt*1024 + swz(lr, lg*8)];
    a1[tt] = *(const short8v*)&Tw[tt*1024 + swz(lr, 32 + lg*8)];
  }
  // ---- qk branch (both tiles) ----
  {
    short8v w1f[4][2], w2f[4][2];
    float wnl[4], b1l[4], b2l[4];
    const short8v* W1 = (const short8v*)(wb + WB_IQW1);
    const short8v* W2 = (const short8v*)(wb + WB_IQW2);
    #pragma unroll
    for (int nt = 0; nt < 4; nt++){
      int col = lr + 16*nt;
      wnl[nt] = iqw1f[col*65 + 64];
      b1l[nt] = qb1[col]; b2l[nt] = qb2[col];
      #pragma unroll
      for (int ks = 0; ks < 2; ks++){
        w1f[nt][ks] = W1[col*8 + ks*4 + lg];
        w2f[nt][ks] = W2[col*8 + ks*4 + lg];
      }
    }
    #pragma unroll
    for (int tt = 0; tt < 2; tt++){
      int row0 = (t0 + tt)*64 + wid*16;
      float nzq[4];
      #pragma unroll
      for (int q = 0; q < 4; q++) nzq[q] = Nl[wid][tt*16 + lg*4 + q];
      #pragma unroll
      for (int nt = 0; nt < 4; nt++){
        floatx4 acc = zz;
        acc = __builtin_amdgcn_mfma_f32_16x16x32_bf16(a0[tt], w1f[nt][0], acc, 0, 0, 0);
        acc = __builtin_amdgcn_mfma_f32_16x16x32_bf16(a1[tt], w1f[nt][1], acc, 0, 0, 0);
        #pragma unroll
        for (int q = 0; q < 4; q++)
          Hw[swz(lg*4 + q, lr + 16*nt)] = f2b(fmaxf(acc[q] + b1l[nt] + wnl[nt]*nzq[q], 0.f));
      }
      wsync();
      short8v h0 = *(const short8v*)&Hw[swz(lr, lg*8)];
      short8v h1 = *(const short8v*)&Hw[swz(lr, 32 + lg*8)];
      #pragma unroll
      for (int nt = 0; nt < 4; nt++){
        floatx4 acc = zz;
        acc = __builtin_amdgcn_mfma_f32_16x16x32_bf16(h0, w2f[nt][0], acc, 0, 0, 0);
        acc = __builtin_amdgcn_mfma_f32_16x16x32_bf16(h1, w2f[nt][1], acc, 0, 0, 0);
        #pragma unroll
        for (int q = 0; q < 4; q++){
          int rl = lg*4 + q, c = lr + 16*nt;
          stf(A, (size_t)(row0 + rl)*64 + c, acc[q] + b2l[nt]);
        }
      }
      wsync();
    }
  }
  // ---- v branch (both tiles) ----
  {
    short8v w1f[4][2], w2f[4][2];
    float rsvl[4], b1l[4], b2l[4];
    const short8v* W1 = (const short8v*)(wb + WB_IVW1);   // row stride 128 -> 16 vec
    const short8v* W2 = (const short8v*)(wb + WB_IVW2);
    #pragma unroll
    for (int nt = 0; nt < 4; nt++){
      int col = lr + 16*nt;
      b1l[nt] = vb1[col]; b2l[nt] = vb2[col];
      rsvl[nt] = rsvb[col];
      #pragma unroll
      for (int ks = 0; ks < 2; ks++){
        w1f[nt][ks] = W1[col*16 + ks*4 + lg];
        w2f[nt][ks] = W2[col*8 + ks*4 + lg];
      }
    }
    #pragma unroll
    for (int tt = 0; tt < 2; tt++){
      int row0 = (t0 + tt)*64 + wid*16;
      int b = row0 / VDIM;
      int vb = row0 - b*VDIM;
      int hv = h_index[b];
      bool cq[4];
      #pragma unroll
      for (int q = 0; q < 4; q++) cq[q] = (vb + lg*4 + q) == hv;
      #pragma unroll
      for (int nt = 0; nt < 4; nt++){
        floatx4 acc = zz;
        acc = __builtin_amdgcn_mfma_f32_16x16x32_bf16(a0[tt], w1f[nt][0], acc, 0, 0, 0);
        acc = __builtin_amdgcn_mfma_f32_16x16x32_bf16(a1[tt], w1f[nt][1], acc, 0, 0, 0);
        #pragma unroll
        for (int q = 0; q < 4; q++)
          Hw[swz(lg*4 + q, lr + 16*nt)] = f2b(fmaxf(acc[q] + b1l[nt] + (cq[q] ? rsvl[nt] : 0.f), 0.f));
      }
      wsync();
      short8v h0 = *(const short8v*)&Hw[swz(lr, lg*8)];
      short8v h1 = *(const short8v*)&Hw[swz(lr, 32 + lg*8)];
      #pragma unroll
      for (int nt = 0; nt < 4; nt++){
        floatx4 acc = zz;
        acc = __builtin_amdgcn_mfma_f32_16x16x32_bf16(h0, w2f[nt][0], acc, 0, 0, 0);
        acc = __builtin_amdgcn_mfma_f32_16x16x32_bf16(h1, w2f[nt][1], acc, 0, 0, 0);
        #pragma unroll
        for (int q = 0; q < 4; q++){
          int rl = lg*4 + q, c = lr + 16*nt;
          stf(B, (size_t)(row0 + rl)*64 + c, acc[q] + b2l[nt]);
        }
      }
      wsync();
    }
  }
}

// ---- rspmm gather, dual-chain: blocks [0,NRB4) = chain A, [NRB4,2NRB4) = chain B ----
// 4 vertices/block, 4 edges in flight
__global__ __launch_bounds__(256) void rspmm_dual(
    const int* __restrict__ row_ptr, const int2* __restrict__ pk,
    const float* __restrict__ zA, const float* __restrict__ zB,
    const bf16* __restrict__ XA, const bf16* __restrict__ XB,
    bf16* __restrict__ outA, bf16* __restrict__ outB){
  int bid = blockIdx.x;
  bool cb = bid >= NRB4;
  int v0 = (cb ? bid - NRB4 : bid) * 4;
  const float* zrel = cb ? zB : zA;
  const bf16* X = cb ? XB : XA;
  bf16* out = cb ? outB : outA;
  int btch = threadIdx.x >> 6, d = threadIdx.x & 63;
  int rp[5];
  #pragma unroll
  for (int i = 0; i < 5; i++) rp[i] = row_ptr[v0 + i];
  const float* zb = zrel + btch*RDIM*DDIM + d;
  size_t xb = (size_t)btch*VDIM*64 + d;
  size_t ob = ((size_t)btch*VDIM + v0)*64 + d;
  #pragma unroll 1
  for (int vi = 0; vi < 4; vi++){
    int s = rp[vi], e = rp[vi+1];
    float a0 = 0.f, a1 = 0.f, a2 = 0.f, a3 = 0.f;
    int i = s;
    for (; i + 4 <= e; i += 4){
      int2 e0 = pk[i], e1 = pk[i+1], e2 = pk[i+2], e3 = pk[i+3];
      float x0 = ldf(X, xb + (size_t)e0.y*64);
      float x1 = ldf(X, xb + (size_t)e1.y*64);
      float x2 = ldf(X, xb + (size_t)e2.y*64);
      float x3 = ldf(X, xb + (size_t)e3.y*64);
      a0 += zb[(size_t)e0.x*64] * x0;
      a1 += zb[(size_t)e1.x*64] * x1;
      a2 += zb[(size_t)e2.x*64] * x2;
      a3 += zb[(size_t)e3.x*64] * x3;
    }
    for (; i < e; i++){
      int2 ed = pk[i];
      a0 += zb[(size_t)ed.x*64] * ldf(X, xb + (size_t)ed.y*64);
    }
    stf(out, ob + (size_t)vi*64, a0 + a1 + a2 + a3);
  }
}

// ================= MFMA dense kernels =================
// Per wave: 16-row x 64-col tile. A-frag: lane holds row (lane&15), k-slice (lane>>4).
// B-frag (weights): lane holds W[col=(lane&15)+16nt][k-slice]. C/D: col=lane&15,
// row=(lane>>4)*4+q (m89-verified). LDS tiles [16][64] bf16 with row-XOR swizzle.

// ---- loop body, dual-chain, 2 tiles/block: X = LN(mlp2(O + alpha*X))*ng + nb + X ----
__global__ __launch_bounds__(256) void loop_dual_kernel(
    const bf16* __restrict__ OA, bf16* __restrict__ XA,
    const bf16* __restrict__ OB, bf16* __restrict__ XB,
    const float* __restrict__ alA, const unsigned short* __restrict__ w1A, const float* __restrict__ b1A,
    const unsigned short* __restrict__ w2A, const float* __restrict__ b2A,
    const float* __restrict__ ngA, const float* __restrict__ nbA,
    const float* __restrict__ alB, const unsigned short* __restrict__ w1B, const float* __restrict__ b1B,
    const unsigned short* __restrict__ w2B, const float* __restrict__ b2B,
    const float* __restrict__ ngB, const float* __restrict__ nbB){
  __shared__ unsigned short Tl[4][2048];
  __shared__ unsigned short Xl[4][2048];
  __shared__ unsigned short Hl[4][1024];
  int bid = blockIdx.x;
  bool cb = bid >= NDB;
  int pb = cb ? bid - NDB : bid;
  const bf16* O = cb ? OB : OA;
  bf16* X = cb ? XB : XA;
  const float* alpha = cb ? alB : alA;
  const unsigned short* w1 = cb ? w1B : w1A;
  const float* b1 = cb ? b1B : b1A;
  const unsigned short* w2 = cb ? w2B : w2A;
  const float* b2 = cb ? b2B : b2A;
  const float* ng = cb ? ngB : ngA;
  const float* nb = cb ? nbB : nbA;
  int tid = threadIdx.x, lane = tid & 63, wid = tid >> 6;
  int lr = lane & 15, lg = lane >> 4;
  short8v w1f[4][2], w2f[4][2];
  const short8v* W1 = (const short8v*)w1;
  const short8v* W2 = (const short8v*)w2;
  #pragma unroll
  for (int nt = 0; nt < 4; nt++){
    int col = lr + 16*nt;
    #pragma unroll
    for (int ks = 0; ks < 2; ks++){
      w1f[nt][ks] = W1[col*8 + ks*4 + lg];
      w2f[nt][ks] = W2[col*8 + ks*4 + lg];
    }
  }
  float4 al = ((const float4*)alpha)[lr];
  float b1l[4], b2l[4], ngl[4], nbl[4];
  #pragma unroll
  for (int nt = 0; nt < 4; nt++){
    int c = lr + 16*nt;
    b1l[nt] = b1[c]; b2l[nt] = b2[c]; ngl[nt] = ng[c]; nbl[nt] = nb[c];
  }
  unsigned short* Tw = Tl[wid];
  unsigned short* Xw = Xl[wid];
  unsigned short* Hw = Hl[wid];
  floatx4 zz = {0.f, 0.f, 0.f, 0.f};
  int t0 = pb*2;
  // stage both tiles (16 loads in flight); X copied raw, T = O + alpha*X
  #pragma unroll
  for (int tt = 0; tt < 2; tt++){
    int row0 = (t0 + tt)*64 + wid*16;
    #pragma unroll
    for (int it = 0; it < 4; it++){
      int rl = it*4 + lg;
      size_t gi = (size_t)(row0 + rl)*64 + 4*lr;
      ushort4 xw = *(const ushort4*)(X + gi);
      float4 ov4 = ldf4(O, gi);
      int si = tt*1024 + swz(rl, 4*lr);
      float4 tv;
      tv.x = ov4.x + al.x*b2f(xw.x);
      tv.y = ov4.y + al.y*b2f(xw.y);
      tv.z = ov4.z + al.z*b2f(xw.z);
      tv.w = ov4.w + al.w*b2f(xw.w);
      *(ushort4*)&Tw[si] = packb(tv);
      *(ushort4*)&Xw[si] = xw;
    }
  }
  wsync();
  #pragma unroll
  for (int tt = 0; tt < 2; tt++){
    int row0 = (t0 + tt)*64 + wid*16;
    short8v a0 = *(const short8v*)&Tw[tt*1024 + swz(lr, lg*8)];
    short8v a1 = *(const short8v*)&Tw[tt*1024 + swz(lr, 32 + lg*8)];
    #pragma unroll
    for (int nt = 0; nt < 4; nt++){
      floatx4 acc = zz;
      acc = __builtin_amdgcn_mfma_f32_16x16x32_bf16(a0, w1f[nt][0], acc, 0, 0, 0);
      acc = __builtin_amdgcn_mfma_f32_16x16x32_bf16(a1, w1f[nt][1], acc, 0, 0, 0);
      #pragma unroll
      for (int q = 0; q < 4; q++)
        Hw[swz(lg*4 + q, lr + 16*nt)] = f2b(fmaxf(acc[q] + b1l[nt], 0.f));
    }
    wsync();
    short8v h0 = *(const short8v*)&Hw[swz(lr, lg*8)];
    short8v h1 = *(const short8v*)&Hw[swz(lr, 32 + lg*8)];
    float y[4][4];
    float s[4] = {0.f,0.f,0.f,0.f}, ss[4] = {0.f,0.f,0.f,0.f};
    #pragma unroll
    for (int nt = 0; nt < 4; nt++){
      floatx4 acc = zz;
      acc = __builtin_amdgcn_mfma_f32_16x16x32_bf16(h0, w2f[nt][0], acc, 0, 0, 0);
      acc = __builtin_amdgcn_mfma_f32_16x16x32_bf16(h1, w2f[nt][1], acc, 0, 0, 0);
      #pragma unroll
      for (int q = 0; q < 4; q++){
        float v = acc[q] + b2l[nt];
        y[nt][q] = v; s[q] += v; ss[q] += v*v;
      }
    }
    #pragma unroll
    for (int o = 1; o < 16; o <<= 1){
      #pragma unroll
      for (int q = 0; q < 4; q++){
        s[q] += __shfl_xor(s[q], o, 64);
        ss[q] += __shfl_xor(ss[q], o, 64);
      }
    }
    float mu[4], rs[4];
    #pragma unroll
    for (int q = 0; q < 4; q++){
      mu[q] = s[q]*(1.f/64.f);
      float var = fmaxf(ss[q]*(1.f/64.f) - mu[q]*mu[q], 0.f);
      rs[q] = rsqrtf(var + LN_EPS);
    }
    #pragma unroll
    for (int nt = 0; nt < 4; nt++){
      #pragma unroll
      for (int q = 0; q < 4; q++){
        int rl = lg*4 + q, c = lr + 16*nt;
        float xs = b2f(Xw[tt*1024 + swz(rl, c)]);
        float v = (y[nt][q] - mu[q])*rs[q]*ngl[nt] + nbl[nt] + xs;
        stf(X, (size_t)(row0 + rl)*64 + c, v);
      }
    }
    wsync();
  }
}

// ---- kvred + qproj fused dispatch: blocks [0,NKV) kvred; [NKV,NKV+NTILE) qproj ----
__global__ __launch_bounds__(256) void kvred_qproj_kernel(
    const bf16* __restrict__ Xqk, const bf16* __restrict__ Xv,
    const unsigned short* __restrict__ wb, const float* __restrict__ bias,
    float* __restrict__ partial, bf16* __restrict__ qn_out){
  __shared__ unsigned short T1[4][1024];   // Xqk stage (swz) then kn_t [64][16]
  __shared__ unsigned short T2[4][1024];   // Xv stage (swz)
  __shared__ float red[4*1536];
  int tid = threadIdx.x, lane = tid & 63, wid = tid >> 6;
  int lr = lane & 15, lg = lane >> 4;
  floatx4 zz = {0.f, 0.f, 0.f, 0.f};
  const short8v z8 = {0,0,0,0,0,0,0,0};
  const short8v* WQ = (const short8v*)(wb + WB_QK);

  if (blockIdx.x >= NKV){
    // ---- qproj: one 64-row tile of Xqk -> head-normalized q (bf16) ----
    int tile = blockIdx.x - NKV;
    unsigned short* Tw = T1[wid];
    short8v wqf[4][2];
    float bq[4];
    #pragma unroll
    for (int nt = 0; nt < 4; nt++){
      int col = lr + 16*nt;                  // q-half of fc_to_qk
      bq[nt] = bias[col];
      #pragma unroll
      for (int ks = 0; ks < 2; ks++) wqf[nt][ks] = WQ[col*8 + ks*4 + lg];
    }
    int row0 = tile*64 + wid*16;
    #pragma unroll
    for (int it = 0; it < 4; it++){
      int rl = it*4 + lg;
      size_t gi = (size_t)(row0 + rl)*64 + 4*lr;
      *(ushort4*)&Tw[swz(rl, 4*lr)] = *(const ushort4*)(Xqk + gi);
    }
    wsync();
    short8v a0 = *(const short8v*)&Tw[swz(lr, lg*8)];
    short8v a1 = *(const short8v*)&Tw[swz(lr, 32 + lg*8)];
    float qn[4][4];
    #pragma unroll
    for (int nt = 0; nt < 4; nt++){
      floatx4 acc = zz;
      acc = __builtin_amdgcn_mfma_f32_16x16x32_bf16(a0, wqf[nt][0], acc, 0, 0, 0);
      acc = __builtin_amdgcn_mfma_f32_16x16x32_bf16(a1, wqf[nt][1], acc, 0, 0, 0);
      #pragma unroll
      for (int q = 0; q < 4; q++) qn[nt][q] = acc[q] + bq[nt];
    }
    #pragma unroll
    for (int nt = 0; nt < 4; nt++){
      float n0 = qn[nt][0]*qn[nt][0], n1 = qn[nt][1]*qn[nt][1];
      float n2 = qn[nt][2]*qn[nt][2], n3 = qn[nt][3]*qn[nt][3];
      #pragma unroll
      for (int o = 1; o < 16; o <<= 1){
        n0 += __shfl_xor(n0, o, 64); n1 += __shfl_xor(n1, o, 64);
        n2 += __shfl_xor(n2, o, 64); n3 += __shfl_xor(n3, o, 64);
      }
      qn[nt][0] /= fmaxf(sqrtf(n0), 1e-12f);
      qn[nt][1] /= fmaxf(sqrtf(n1), 1e-12f);
      qn[nt][2] /= fmaxf(sqrtf(n2), 1e-12f);
      qn[nt][3] /= fmaxf(sqrtf(n3), 1e-12f);
    }
    #pragma unroll
    for (int nt = 0; nt < 4; nt++)
      #pragma unroll
      for (int q = 0; q < 4; q++)
        stf(qn_out, (size_t)(row0 + lg*4 + q)*64 + lr + 16*nt, qn[nt][q]);
    return;
  }

  // ---- kvred ----
  short8v wkf[4][2];
  float bk[4];
  #pragma unroll
  for (int nt = 0; nt < 4; nt++){
    int col = 64 + lr + 16*nt;               // k-half of fc_to_qk
    bk[nt] = bias[col];
    #pragma unroll
    for (int ks = 0; ks < 2; ks++) wkf[nt][ks] = WQ[col*8 + ks*4 + lg];
  }
  int b = blockIdx.x / NBB, blk = blockIdx.x % NBB;
  unsigned short* Tw = T1[wid];
  unsigned short* Vw = T2[wid];
  floatx4 kvacc[4] = {zz, zz, zz, zz};
  float ksp[4] = {0.f,0.f,0.f,0.f};
  float vsp[4] = {0.f,0.f,0.f,0.f};
  for (int st = blk*4 + wid; st < 1250; st += NBB*4){
    size_t gr = (size_t)b*VDIM + (size_t)st*16;
    #pragma unroll
    for (int it = 0; it < 4; it++){
      int rl = it*4 + lg;
      size_t gi = (gr + rl)*64 + 4*lr;
      ushort4 tq = *(const ushort4*)(Xqk + gi);
      ushort4 tv = *(const ushort4*)(Xv + gi);
      int si = swz(rl, 4*lr);
      *(ushort4*)&Tw[si] = tq;
      *(ushort4*)&Vw[si] = tv;
      vsp[0] += b2f(tv.x); vsp[1] += b2f(tv.y); vsp[2] += b2f(tv.z); vsp[3] += b2f(tv.w);
    }
    wsync();
    short8v a0 = *(const short8v*)&Tw[swz(lr, lg*8)];
    short8v a1 = *(const short8v*)&Tw[swz(lr, 32 + lg*8)];
    // k-projection + head norm -> kn (C-layout regs), store kn_t to T1
    float kn[4][4];
    #pragma unroll
    for (int nt = 0; nt < 4; nt++){
      floatx4 acc = zz;
      acc = __builtin_amdgcn_mfma_f32_16x16x32_bf16(a0, wkf[nt][0], acc, 0, 0, 0);
      acc = __builtin_amdgcn_mfma_f32_16x16x32_bf16(a1, wkf[nt][1], acc, 0, 0, 0);
      #pragma unroll
      for (int q = 0; q < 4; q++) kn[nt][q] = acc[q] + bk[nt];
    }
    #pragma unroll
    for (int nt = 0; nt < 4; nt++){
      float n0 = kn[nt][0]*kn[nt][0], n1 = kn[nt][1]*kn[nt][1];
      float n2 = kn[nt][2]*kn[nt][2], n3 = kn[nt][3]*kn[nt][3];
      #pragma unroll
      for (int o = 1; o < 16; o <<= 1){
        n0 += __shfl_xor(n0, o, 64); n1 += __shfl_xor(n1, o, 64);
        n2 += __shfl_xor(n2, o, 64); n3 += __shfl_xor(n3, o, 64);
      }
      kn[nt][0] /= fmaxf(sqrtf(n0), 1e-12f);
      kn[nt][1] /= fmaxf(sqrtf(n1), 1e-12f);
      kn[nt][2] /= fmaxf(sqrtf(n2), 1e-12f);
      kn[nt][3] /= fmaxf(sqrtf(n3), 1e-12f);
      ksp[nt] += kn[nt][0] + kn[nt][1] + kn[nt][2] + kn[nt][3];
    }
    wsync();   // a0/a1 consumed; safe to overwrite T1 with kn_t
    #pragma unroll
    for (int nt = 0; nt < 4; nt++){
      int c = lr + 16*nt;
      #pragma unroll
      for (int q = 0; q < 4; q++)
        Tw[c*16 + lg*4 + q] = f2b(kn[nt][q]);
    }
    wsync();
    // kv += kn^T (A) x vx (B), per head, K=16 rows zero-padded to 32
    #pragma unroll
    for (int nt = 0; nt < 4; nt++){
      short8v af = z8, bf = z8;
      if (lg < 2){
        af = *(const short8v*)&Tw[(nt*16 + lr)*16 + lg*8];
        #pragma unroll
        for (int j = 0; j < 8; j++)
          bf[j] = (short)Vw[swz(lg*8 + j, nt*16 + lr)];
      }
      kvacc[nt] = __builtin_amdgcn_mfma_f32_16x16x32_bf16(af, bf, kvacc[nt], 0, 0, 0);
    }
    wsync();   // LDS reads done before next stripe overwrites tiles
  }
  // write per-wave partials
  float* rw = red + wid*1536;
  #pragma unroll
  for (int nt = 0; nt < 4; nt++){
    #pragma unroll
    for (int q = 0; q < 4; q++)
      rw[(nt*16 + lg*4 + q)*16 + lr] = kvacc[nt][q];
    rw[1024 + lg*64 + lr + 16*nt] = ksp[nt];
  }
  #pragma unroll
  for (int m = 0; m < 4; m++)
    rw[1280 + lg*64 + 4*lr + m] = vsp[m];
  __syncthreads();
  float* P = partial + (size_t)blockIdx.x*1152;
  for (int j = tid; j < 1152; j += 256){
    float s = 0.f;
    if (j < 1024){
      #pragma unroll
      for (int wv = 0; wv < 4; wv++) s += red[wv*1536 + j];
    } else if (j < 1088){
      int c = j - 1024;
      #pragma unroll
      for (int wv = 0; wv < 4; wv++)
        #pragma unroll
        for (int gg = 0; gg < 4; gg++) s += red[wv*1536 + 1024 + gg*64 + c];
    } else {
      int c = j - 1088;
      #pragma unroll
      for (int wv = 0; wv < 4; wv++)
        #pragma unroll
        for (int gg = 0; gg < 4; gg++) s += red[wv*1536 + 1280 + gg*64 + c];
    }
    P[j] = s;
  }
}

// ---- reduce kvred partials; also emit bf16 copies for attn fragments ----
__global__ void qkred_kernel(const float* __restrict__ partial,
                             float* __restrict__ kvs, float* __restrict__ ksum, float* __restrict__ vsum,
                             unsigned short* __restrict__ kvsb, unsigned short* __restrict__ ksb){
  int b = blockIdx.x / 5, ch = blockIdx.x % 5;
  int j = ch*256 + threadIdx.x;
  if (j >= 1152) return;
  const float* P = partial + (size_t)b*NBB*1152;
  float s = 0.f;
  for (int t = 0; t < NBB; t++) s += P[(size_t)t*1152 + j];
  if (j < 1024){      kvs[b*1024 + j] = s; kvsb[b*1024 + j] = f2b(s); }
  else if (j < 1088){ ksum[b*64 + (j-1024)] = s; ksb[b*64 + (j-1024)] = f2b(s); }
  else                vsum[b*64 + (j-1088)] = s;
}

// ---- fused attention + final FFN, 2 tiles/block; qn precomputed (no q-proj) ----
__global__ __launch_bounds__(256) void attn_final_kernel(
    const float* __restrict__ x, const bf16* __restrict__ QN, const bf16* __restrict__ Xv,
    const unsigned short* __restrict__ kvsb, const unsigned short* __restrict__ ksb,
    const float* __restrict__ vsum,
    const unsigned short* __restrict__ wb,
    const float* __restrict__ ag, const float* __restrict__ ab,
    const float* __restrict__ fb1, const float* __restrict__ fb2,
    const float* __restrict__ g, const float* __restrict__ bb,
    float* __restrict__ out){
  __shared__ unsigned short Ql[4][2048];
  __shared__ unsigned short Hl[4][1024];
  int tid = threadIdx.x, lane = tid & 63, wid = tid >> 6;
  int lr = lane & 15, lg = lane >> 4;
  // FFN weights (bf16 direct)
  short8v f1f[4][2], f2f[4][2];
  float agl[4], abl[4], b1l[4], b2l[4], gl[4], bl[4];
  const short8v* W1 = (const short8v*)(wb + WB_FW1);
  const short8v* W2 = (const short8v*)(wb + WB_FW2);
  #pragma unroll
  for (int nt = 0; nt < 4; nt++){
    int col = lr + 16*nt;
    agl[nt] = ag[col]; abl[nt] = ab[col];
    b1l[nt] = fb1[col]; b2l[nt] = fb2[col]; gl[nt] = g[col]; bl[nt] = bb[col];
    #pragma unroll
    for (int ks = 0; ks < 2; ks++){
      f1f[nt][ks] = W1[col*8 + ks*4 + lg];
      f2f[nt][ks] = W2[col*8 + ks*4 + lg];
    }
  }
  unsigned short* Qw = Ql[wid];
  unsigned short* Hw = Hl[wid];
  floatx4 zz = {0.f, 0.f, 0.f, 0.f};
  const short8v z8 = {0,0,0,0,0,0,0,0};
  int t0 = blockIdx.x*2;
  // stage both qn tiles (already bf16)
  #pragma unroll
  for (int tt = 0; tt < 2; tt++){
    int row0 = (t0 + tt)*64 + wid*16;
    #pragma unroll
    for (int it = 0; it < 4; it++){
      int rl = it*4 + lg;
      size_t gi = (size_t)(row0 + rl)*64 + 4*lr;
      *(ushort4*)&Qw[tt*1024 + swz(rl, 4*lr)] = *(const ushort4*)(QN + gi);
    }
  }
  wsync();
  #pragma unroll
  for (int tt = 0; tt < 2; tt++){
    int row0 = (t0 + tt)*64 + wid*16;
    int b = row0 / VDIM;                     // wave-uniform (16 | 20000)
    // per-head attention: num/den via zero-padded 16x16x32 MFMAs; kv frags from global
    float y[4][4];
    float s[4] = {0.f,0.f,0.f,0.f}, ss[4] = {0.f,0.f,0.f,0.f};
    #pragma unroll
    for (int nt = 0; nt < 4; nt++){
      short8v af = z8, bn = z8, bd = z8;
      if (lg < 2){
        af = *(const short8v*)&Qw[tt*1024 + swz(lr, nt*16 + lg*8)];
        bd = *(const short8v*)&ksb[b*64 + nt*16 + lg*8];
        #pragma unroll
        for (int j = 0; j < 8; j++)
          bn[j] = (short)kvsb[b*1024 + (nt*16 + lg*8 + j)*16 + lr];
      }
      int c = lr + 16*nt;
      float vsb = vsum[b*64 + c];
      floatx4 numc, denc;
      #pragma unroll
      for (int q = 0; q < 4; q++){
        float vv = ldf(Xv, (size_t)(row0 + lg*4 + q)*64 + c);
        numc[q] = vsb + vv*(float)VDIM;
        denc[q] = 2.0f*(float)VDIM;
      }
      numc = __builtin_amdgcn_mfma_f32_16x16x32_bf16(af, bn, numc, 0, 0, 0);
      denc = __builtin_amdgcn_mfma_f32_16x16x32_bf16(af, bd, denc, 0, 0, 0);
      #pragma unroll
      for (int q = 0; q < 4; q++){
        float xv = x[(size_t)(row0 + lg*4 + q)*64 + c];
        float v = xv + numc[q]/denc[q];
        y[nt][q] = v; s[q] += v; ss[q] += v*v;
      }
    }
    #pragma unroll
    for (int o = 1; o < 16; o <<= 1){
      #pragma unroll
      for (int q = 0; q < 4; q++){
        s[q] += __shfl_xor(s[q], o, 64);
        ss[q] += __shfl_xor(ss[q], o, 64);
      }
    }
    #pragma unroll
    for (int q = 0; q < 4; q++){
      float mu = s[q]*(1.f/64.f);
      float var = fmaxf(ss[q]*(1.f/64.f) - mu*mu, 0.f);
      float rs = rsqrtf(var + LN_EPS);
      #pragma unroll
      for (int nt = 0; nt < 4; nt++)
        y[nt][q] = (y[nt][q] - mu)*rs*agl[nt] + abl[nt];
    }
    // FFN + LN2 (residual y in regs)
    wsync();   // per-head Qw reads done; overwrite tile-tt with xa
    #pragma unroll
    for (int nt = 0; nt < 4; nt++){
      #pragma unroll
      for (int q = 0; q < 4; q++)
        Qw[tt*1024 + swz(lg*4 + q, lr + 16*nt)] = f2b(y[nt][q]);
    }
    wsync();
    short8v xa0 = *(const short8v*)&Qw[tt*1024 + swz(lr, lg*8)];
    short8v xa1 = *(const short8v*)&Qw[tt*1024 + swz(lr, 32 + lg*8)];
    #pragma unroll
    for (int nt = 0; nt < 4; nt++){
      floatx4 acc = zz;
      acc = __builtin_amdgcn_mfma_f32_16x16x32_bf16(xa0, f1f[nt][0], acc, 0, 0, 0);
      acc = __builtin_amdgcn_mfma_f32_16x16x32_bf16(xa1, f1f[nt][1], acc, 0, 0, 0);
      #pragma unroll
      for (int q = 0; q < 4; q++)
        Hw[swz(lg*4 + q, lr + 16*nt)] = f2b(fmaxf(acc[q] + b1l[nt], 0.f));
    }
    wsync();
    short8v h0 = *(const short8v*)&Hw[swz(lr, lg*8)];
    short8v h1 = *(const short8v*)&Hw[swz(lr, 32 + lg*8)];
    float t[4][4];
    float s2[4] = {0.f,0.f,0.f,0.f}, ss2[4] = {0.f,0.f,0.f,0.f};
    #pragma unroll
    for (int nt = 0; nt < 4; nt++){
      floatx4 acc = zz;
      acc = __builtin_amdgcn_mfma_f32_16x16x32_bf16(h0, f2f[nt][0], acc, 0, 0, 0);
      acc = __builtin_amdgcn_mfma_f32_16x16x32_bf16(h1, f2f[nt][1], acc, 0, 0, 0);
      #pragma unroll
      for (int q = 0; q < 4; q++){
        float v = acc[q] + b2l[nt] + y[nt][q];
        t[nt][q] = v; s2[q] += v; ss2[q] += v*v;
      }
    }
    #pragma unroll
    for (int o = 1; o < 16; o <<= 1){
      #pragma unroll
      for (int q = 0; q < 4; q++){
        s2[q] += __shfl_xor(s2[q], o, 64);
        ss2[q] += __shfl_xor(ss2[q], o, 64);
      }
    }
    #pragma unroll
    for (int q = 0; q < 4; q++){
      float mu = s2[q]*(1.f/64.f);
      float var = fmaxf(ss2[q]*(1.f/64.f) - mu*mu, 0.f);
      float rs = rsqrtf(var + LN_EPS);
      #pragma unroll
      for (int nt = 0; nt < 4; nt++){
        int c = lr + 16*nt;
        out[(size_t)(row0 + lg*4 + q)*64 + c] = (t[nt][q] - mu)*rs*gl[nt] + bl[nt];
      }
    }
    wsync();   // Hw reused by next tile
  }
}

// ================= host side =================
static const int DICT_SIZES[42] = {
  5120000,256,256,80000,262144,4096,4160,64,4096,64,
  8192,64,4096,64,8192,128,8192,128,8192,128,
  128,128,128,524288,8192,8192,128,8192,128,128,
  128,128,4096,64,4096,64,64,64,64,64,
  4,600000};

static void run_pipeline(const float* const* N, const int* hi,
                         const int* ei_raw, const int* eflag,
                         int* cursor, int2* pk, const int* row_ptr,
                         float* qk_z, float* zr, float* kvs, float* part,
                         unsigned short* kvsb, unsigned short* wb, float* rsvb,
                         bf16* A, bf16* B, bf16* OA, bf16* OB, bool dual,
                         float* outp, hipStream_t stream){
  float* ksum = kvs + 4096;
  float* vsum = kvs + 4352;
  unsigned short* ksb = kvsb + 4096;

  // fused: scatter (needs scan done) + init_both (independent) in one dispatch
  scatter_init_kernel<<<NSC + NDB, 256, 0, stream>>>(ei_raw, eflag, cursor, pk,
      N[0], N[3], hi, wb, rsvb, N[6], N[7], N[9], N[11], N[13], A, B);

  if (dual){
    for (int i = 0; i < 2; i++){
      rspmm_dual<<<2*NRB4, 256, 0, stream>>>(row_ptr, pk, qk_z, zr + i*16384, A, B, OA, OB);
      loop_dual_kernel<<<2*NDB, 256, 0, stream>>>(OA, A, OB, B,
          N[20] + i*64, wb + WB_QKW1 + i*4096, N[17] + i*64, wb + WB_QKW2 + i*4096, N[19] + i*64, N[21] + i*64, N[22] + i*64,
          N[29] + i*64, wb + WB_VW1 + i*4096, N[26] + i*64, wb + WB_VW2 + i*4096, N[28] + i*64, N[30] + i*64, N[31] + i*64);
    }
  } else {
    for (int i = 0; i < 2; i++){
      rspmm_dual<<<NRB4, 256, 0, stream>>>(row_ptr, pk, qk_z, qk_z, A, A, OA, OA);
      loop_dual_kernel<<<NDB, 256, 0, stream>>>(OA, A, OA, A,
          N[20] + i*64, wb + WB_QKW1 + i*4096, N[17] + i*64, wb + WB_QKW2 + i*4096, N[19] + i*64, N[21] + i*64, N[22] + i*64,
          N[20] + i*64, wb + WB_QKW1 + i*4096, N[17] + i*64, wb + WB_QKW2 + i*4096, N[19] + i*64, N[21] + i*64, N[22] + i*64);
    }
    for (int i = 0; i < 2; i++){
      rspmm_dual<<<NRB4, 256, 0, stream>>>(row_ptr, pk, zr + i*16384, zr + i*16384, B, B, OA, OA);
      loop_dual_kernel<<<NDB, 256, 0, stream>>>(OA, B, OA, B,
          N[29] + i*64, wb + WB_VW1 + i*4096, N[26] + i*64, wb + WB_VW2 + i*4096, N[28] + i*64, N[30] + i*64, N[31] + i*64,
          N[29] + i*64, wb + WB_VW1 + i*4096, N[26] + i*64, wb + WB_VW2 + i*4096, N[28] + i*64, N[30] + i*64, N[31] + i*64);
    }
  }

  // kvred + q-projection (independent block ranges) in one dispatch; qn -> OA (free)
  kvred_qproj_kernel<<<NKV + NTILE, 256, 0, stream>>>(A, B, wb, N[15], part, OA);
  qkred_kernel<<<20, 256, 0, stream>>>(part, kvs, ksum, vsum, kvsb, ksb);
  attn_final_kernel<<<NDB, 256, 0, stream>>>(N[0], OA, B, kvsb, ksb, vsum,
      wb, N[36], N[37], N[33], N[35], N[38], N[39], outp);
}

extern "C" void kernel_launch(void* const* d_in, const int* in_sizes, int n_in,
                              void* d_out, int out_size, void* d_ws, size_t ws_size,
                              hipStream_t stream){
  float* outp = (float*)d_out;
  const int GOUT = (out_size + 255) / 256;

  if (n_in != 42){
    fill_kernel<<<GOUT, 256, 0, stream>>>(outp, 2000.0f + (float)n_in, out_size);
    return;
  }
  auto sz_ok = [&](int s, int e)->bool{
    if (s == e) return true;
    if ((e == 4 || e == 600000) && s == 2*e) return true;
    return false;
  };
  int bad = -1;
  for (int i = 0; i < 42 && bad < 0; i++)
    if (!sz_ok(in_sizes[i], DICT_SIZES[i])) bad = i;
  if (bad >= 0){
    fill_kernel<<<GOUT, 256, 0, stream>>>(outp, 1000.0f + (float)bad, out_size);
    return;
  }

  const float* N[40];
  for (int i = 0; i < 40; i++) N[i] = (const float*)d_in[i];
  const int* hi_raw = (const int*)d_in[40];
  const int* ei_raw = (const int*)d_in[41];

  char* p = (char*)d_ws;
  auto alloc = [&](size_t bytes)->char*{ char* r = p; p += (bytes + 255) / 256 * 256; return r; };
  int* hi      = (int*)alloc(256);
  int* eflag   = (int*)alloc(256);
  int* counts  = (int*)alloc((VDIM+1)*4);
  int* row_ptr = (int*)alloc((VDIM+1)*4);
  int* cursor  = (int*)alloc((VDIM+1)*4);
  int2* pk     = (int2*)alloc((size_t)EDIM*8);
  float* qk_z  = (float*)alloc(16384u*4);
  float* zr    = (float*)alloc(32768u*4);
  float* kvs   = (float*)alloc(4608u*4);
  unsigned short* kvsb = (unsigned short*)alloc(4352u*2);
  unsigned short* wb   = (unsigned short*)alloc((size_t)WB_TOT*2);
  float* rsvb  = (float*)alloc(64*4);
  float* part  = (float*)alloc((size_t)BDIM*NBB*1152*4);
  size_t fixed = (size_t)(p - (char*)d_ws);
  const size_t bufH = (size_t)BV*64*2;

  // setup: detect64 + zero counts + zcalc + weight bf16 conversion, one dispatch
  setup_kernel<<<273 + (WC_TOT+255)/256, 256, 0, stream>>>(ei_raw, eflag, counts,
      N[1], N[4], N[5], N[23], N[24], qk_z, zr,
      N[16], N[18], N[25], N[27], N[6], N[8], N[10], N[12], N[14], N[32], N[34],
      wb, rsvb);
  prep_count_kernel<<<(EDIM+255)/256, 256, 0, stream>>>(ei_raw, hi_raw, eflag, hi, counts);
  scan_kernel<<<1, 256, 0, stream>>>(counts, row_ptr, cursor);

  // bf16 workspace: halves intermediate traffic, makes rspmm X L2-resident.
  if (ws_size >= fixed + 4*bufH + 1024){
    bf16* A  = (bf16*)alloc(bufH);
    bf16* B  = (bf16*)alloc(bufH);
    bf16* OA = (bf16*)alloc(bufH);
    bf16* OB = (bf16*)alloc(bufH);
    run_pipeline(N, hi, ei_raw, eflag, cursor, pk, row_ptr,
                 qk_z, zr, kvs, part, kvsb, wb, rsvb, A, B, OA, OB, true, outp, stream);
  } else {
    bf16* A  = (bf16*)alloc(bufH);
    bf16* B  = (bf16*)alloc(bufH);
    bf16* OA = (bf16*)alloc(bufH);
    run_pipeline(N, hi, ei_raw, eflag, cursor, pk, row_ptr,
                 qk_z, zr, kvs, part, kvsb, wb, rsvb, A, B, OA, OA, false, outp, stream);
  }
}

// Round 15
// 446.280 us; speedup vs baseline: 1.1980x; 1.0001x over previous
//
#include <hip/hip_runtime.h>
#include <hip/hip_bf16.h>

#define BDIM 4
#define VDIM 20000
#define DDIM 64
#define RDIM 64
#define EDIM 200000
#define BV (BDIM*VDIM)
#define LN_EPS 1e-5f
#define NBB 125           // kvred blocks per batch
#define NTILE 1250        // BV/64 row-tiles
#define NDB 625           // dense blocks per chain (2 tiles each)
#define NRB4 (VDIM/4)     // rspmm blocks per chain (4 vertices each)
#define NSC ((EDIM+255)/256)  // scatter blocks (782)
#define NKV (BDIM*NBB)    // kvred blocks (500)

// bf16 weight buffer element offsets (all multiples of 8)
#define WB_QKW1 0         // [2][64][64]
#define WB_QKW2 8192
#define WB_VW1  16384
#define WB_VW2  24576
#define WB_IQW1 32768     // [64][64] (noise col dropped)
#define WB_IQW2 36928     // [64][64]  (36864..36928 unused pad)
#define WB_IVW1 41024     // [64][128]
#define WB_IVW2 49216
#define WB_QK   53312     // [128][64]
#define WB_FW1  61504
#define WB_FW2  65600
#define WB_TOT  69696
#define WC_TOT  69760     // + 64 rsv sums

typedef __hip_bfloat16 bf16;
typedef __attribute__((ext_vector_type(8))) short short8v;
typedef __attribute__((ext_vector_type(4))) float floatx4;

__device__ __forceinline__ float ldf(const float* p, size_t i){ return p[i]; }
__device__ __forceinline__ float ldf(const bf16* p, size_t i){ return __bfloat162float(p[i]); }
__device__ __forceinline__ void stf(float* p, size_t i, float v){ p[i] = v; }
__device__ __forceinline__ void stf(bf16* p, size_t i, float v){ p[i] = __float2bfloat16(v); }

__device__ __forceinline__ unsigned short f2b(float f){
  unsigned u = __builtin_bit_cast(unsigned, f);
  u += 0x7fffu + ((u >> 16) & 1u);
  return (unsigned short)(u >> 16);
}
__device__ __forceinline__ float b2f(unsigned short h){
  unsigned u = ((unsigned)h) << 16;
  return __builtin_bit_cast(float, u);
}
__device__ __forceinline__ float4 ldf4(const float* p, size_t i){ return *(const float4*)(p+i); }
__device__ __forceinline__ float4 ldf4(const bf16* p, size_t i){
  ushort4 u = *(const ushort4*)(p+i);
  return make_float4(b2f(u.x), b2f(u.y), b2f(u.z), b2f(u.w));
}
// LDS tile swizzle: element index for [16][64] bf16 tile, 16B-unit XOR on row
__device__ __forceinline__ int swz(int r, int c){ return r*64 + (c ^ ((r & 7) << 3)); }

__device__ __forceinline__ float dot4(float4 a, float4 b){
  return a.x*b.x + a.y*b.y + a.z*b.z + a.w*b.w;
}

// Wave-private LDS ordering: DS ops from one wave execute in order; just fence compiler.
__device__ __forceinline__ void wsync(){
  __builtin_amdgcn_wave_barrier();
  __asm__ volatile("" ::: "memory");
}

__device__ __forceinline__ ushort4 packb(float4 v){
  ushort4 t; t.x = f2b(v.x); t.y = f2b(v.y); t.z = f2b(v.z); t.w = f2b(v.w); return t;
}

// ---- diagnostic fill ----
__global__ void fill_kernel(float* __restrict__ out, float v, int n){
  int t = blockIdx.x * 256 + threadIdx.x;
  if (t < n) out[t] = v;
}

// ---- setup: blocks 0..79 zero counts, 80..271 zcalc, 272 detect, 273.. weight conv ----
__global__ void setup_kernel(const int* __restrict__ ei_raw, int* __restrict__ flag,
                             int* __restrict__ counts,
                             const float* __restrict__ z,
                             const float* __restrict__ qkzw, const float* __restrict__ qkzb,
                             const float* __restrict__ vfw,  const float* __restrict__ vfb,
                             float* __restrict__ qk_z, float* __restrict__ zr,
                             const float* __restrict__ qkw1, const float* __restrict__ qkw2,
                             const float* __restrict__ vw1l, const float* __restrict__ vw2l,
                             const float* __restrict__ iqw1, const float* __restrict__ iqw2,
                             const float* __restrict__ ivw1, const float* __restrict__ ivw2,
                             const float* __restrict__ qkpw, const float* __restrict__ fw1,
                             const float* __restrict__ fw2,
                             unsigned short* __restrict__ wb, float* __restrict__ rsvb){
  int bid = blockIdx.x, tid = threadIdx.x;
  if (bid >= 273){
    int e = (bid - 273)*256 + tid;
    if (e >= WC_TOT) return;
    if (e >= WB_TOT){
      int col = e - WB_TOT;
      const float4* r4 = (const float4*)(ivw1 + col*128 + 64);
      float rsv = 0.f;
      #pragma unroll
      for (int i = 0; i < 16; i++){ float4 t = r4[i]; rsv += t.x + t.y + t.z + t.w; }
      rsvb[col] = rsv;
      return;
    }
    float v;
    if (e < WB_QKW2)        v = qkw1[e];
    else if (e < WB_VW1)    v = qkw2[e - WB_QKW2];
    else if (e < WB_VW2)    v = vw1l[e - WB_VW1];
    else if (e < WB_IQW1)   v = vw2l[e - WB_VW2];
    else if (e < 36864){ int j = e - WB_IQW1; v = iqw1[(j>>6)*65 + (j&63)]; }
    else if (e < WB_IQW2)   v = 0.f;                      // pad
    else if (e < WB_IVW1)   v = iqw2[e - WB_IQW2];
    else if (e < WB_IVW2)   v = ivw1[e - WB_IVW1];
    else if (e < WB_QK)     v = ivw2[e - WB_IVW2];
    else if (e < WB_FW1)    v = qkpw[e - WB_QK];
    else if (e < WB_FW2)    v = fw1[e - WB_FW1];
    else                    v = fw2[e - WB_FW2];
    wb[e] = f2b(v);
    return;
  }
  if (bid == 272){
    int nz = 0;
    for (int j = 2*tid + 1; j < 1024; j += 512) nz |= (ei_raw[j] != 0);
    nz = __any(nz);
    __shared__ int r[4];
    if ((tid & 63) == 0) r[tid >> 6] = nz;
    __syncthreads();
    if (tid == 0) flag[0] = (r[0] | r[1] | r[2] | r[3]) ? 0 : 1;   // 1 => 64-bit
    return;
  }
  if (bid < 80){
    int i = bid*256 + tid;
    if (i < VDIM + 1) counts[i] = 0;
    return;
  }
  int idx = (bid - 80)*256 + tid;
  if (idx >= 49152) return;
  int which = idx >> 14;
  int r = idx & 16383;
  int b = r >> 12;
  int j = r & 4095;
  const float* wrow; float bias; float* outp;
  if (which == 0){ wrow = qkzw + (size_t)j*DDIM; bias = qkzb[j]; outp = qk_z; }
  else { int i = which - 1; wrow = vfw + (size_t)(i*4096 + j)*DDIM; bias = vfb[i*4096 + j]; outp = zr + i*16384; }
  const float4* zr4 = (const float4*)(z + (size_t)b*DDIM);
  const float4* wr4 = (const float4*)wrow;
  float acc = bias;
  #pragma unroll
  for (int i = 0; i < 16; i++) acc += dot4(zr4[i], wr4[i]);
  outp[r] = acc;
}

// ---- count directly from raw edges (is64-aware) + hi normalize ----
__global__ void prep_count_kernel(const int* __restrict__ ei_raw, const int* __restrict__ hi_raw,
                                  const int* __restrict__ flag,
                                  int* __restrict__ hi, int* __restrict__ counts){
  int is64 = flag[0];
  int e = blockIdx.x * 256 + threadIdx.x;
  if (e < EDIM){
    int dst = is64 ? ei_raw[6*e]   : ei_raw[3*e];
    int rel = is64 ? ei_raw[6*e+2] : ei_raw[3*e+1];
    int src = is64 ? ei_raw[6*e+4] : ei_raw[3*e+2];
    if ((unsigned)dst < VDIM && (unsigned)rel < RDIM && (unsigned)src < VDIM)
      atomicAdd(&counts[dst], 1);
  }
  if (e < BDIM) hi[e] = is64 ? hi_raw[2*e] : hi_raw[e];
}

// ---- scan: per-thread segments + one wave scan, 1 barrier total ----
__global__ void scan_kernel(const int* __restrict__ counts, int* __restrict__ row_ptr, int* __restrict__ cursor){
  __shared__ int wsum[4];
  int tid = threadIdx.x, lane = tid & 63, wid = tid >> 6;
  const int SEG = (VDIM + 255) / 256;        // 79
  int lo = tid * SEG;
  int hi = lo + SEG; if (hi > VDIM) hi = VDIM;
  int s = 0;
  for (int i = lo; i < hi; i++) s += counts[i];
  int x = s;
  #pragma unroll
  for (int o = 1; o < 64; o <<= 1){
    int t = __shfl_up(x, o, 64);
    if (lane >= o) x += t;
  }
  if (lane == 63) wsum[wid] = x;
  __syncthreads();
  int wo = 0;
  for (int w = 0; w < wid; w++) wo += wsum[w];
  int run = wo + x - s;                      // exclusive prefix of this thread's segment
  for (int i = lo; i < hi; i++){
    row_ptr[i] = run; cursor[i] = run; run += counts[i];
  }
  if (tid == 255) row_ptr[VDIM] = run;       // total
}

// ---- fused scatter + init_both: blocks [0,NSC) scatter, [NSC,NSC+NDB) init ----
__global__ __launch_bounds__(256) void scatter_init_kernel(
    const int* __restrict__ ei_raw, const int* __restrict__ flag,
    int* __restrict__ cursor, int2* __restrict__ pk,
    const float* __restrict__ x, const float* __restrict__ noise, const int* __restrict__ h_index,
    const unsigned short* __restrict__ wb, const float* __restrict__ rsvb,
    const float* __restrict__ iqw1f, const float* __restrict__ qb1, const float* __restrict__ qb2,
    const float* __restrict__ vb1, const float* __restrict__ vb2,
    bf16* __restrict__ A, bf16* __restrict__ B){
  if (blockIdx.x < NSC){
    int is64 = flag[0];
    int e = blockIdx.x * 256 + threadIdx.x;
    if (e < EDIM){
      int dst = is64 ? ei_raw[6*e]   : ei_raw[3*e];
      int rel = is64 ? ei_raw[6*e+2] : ei_raw[3*e+1];
      int src = is64 ? ei_raw[6*e+4] : ei_raw[3*e+2];
      if ((unsigned)dst < VDIM && (unsigned)rel < RDIM && (unsigned)src < VDIM){
        int p = atomicAdd(&cursor[dst], 1);
        pk[p] = make_int2(rel, src);
      }
    }
    return;
  }
  __shared__ unsigned short Tl[4][2048];
  __shared__ unsigned short Hl[4][1024];
  __shared__ float Nl[4][32];
  int tid = threadIdx.x, lane = tid & 63, wid = tid >> 6;
  int lr = lane & 15, lg = lane >> 4;
  unsigned short* Tw = Tl[wid];
  unsigned short* Hw = Hl[wid];
  floatx4 zz = {0.f, 0.f, 0.f, 0.f};
  int t0 = (blockIdx.x - NSC)*2;
  // stage both x tiles + noise
  #pragma unroll
  for (int tt = 0; tt < 2; tt++){
    int row0 = (t0 + tt)*64 + wid*16;
    #pragma unroll
    for (int it = 0; it < 4; it++){
      int rl = it*4 + lg;
      size_t gi = (size_t)(row0 + rl)*64 + 4*lr;
      float4 x4 = ldf4(x, gi);
      *(ushort4*)&Tw[tt*1024 + swz(rl, 4*lr)] = packb(x4);
      if (lr == 0) Nl[wid][tt*16 + rl] = noise[row0 + rl];
    }
  }
  wsync();
  short8v a0[2], a1[2];
  #pragma unroll
  for (int tt = 0; tt < 2; tt++){
    a0[tt] = *(const short8v*)&Tw[tt*1024 + swz(lr, lg*8)];
    a1[tt] = *(const short8v*)&Tw[tt*1024 + swz(lr, 32 + lg*8)];
  }
  // ---- qk branch (both tiles) ----
  {
    short8v w1f[4][2], w2f[4][2];
    float wnl[4], b1l[4], b2l[4];
    const short8v* W1 = (const short8v*)(wb + WB_IQW1);
    const short8v* W2 = (const short8v*)(wb + WB_IQW2);
    #pragma unroll
    for (int nt = 0; nt < 4; nt++){
      int col = lr + 16*nt;
      wnl[nt] = iqw1f[col*65 + 64];
      b1l[nt] = qb1[col]; b2l[nt] = qb2[col];
      #pragma unroll
      for (int ks = 0; ks < 2; ks++){
        w1f[nt][ks] = W1[col*8 + ks*4 + lg];
        w2f[nt][ks] = W2[col*8 + ks*4 + lg];
      }
    }
    #pragma unroll
    for (int tt = 0; tt < 2; tt++){
      int row0 = (t0 + tt)*64 + wid*16;
      float nzq[4];
      #pragma unroll
      for (int q = 0; q < 4; q++) nzq[q] = Nl[wid][tt*16 + lg*4 + q];
      #pragma unroll
      for (int nt = 0; nt < 4; nt++){
        floatx4 acc = zz;
        acc = __builtin_amdgcn_mfma_f32_16x16x32_bf16(a0[tt], w1f[nt][0], acc, 0, 0, 0);
        acc = __builtin_amdgcn_mfma_f32_16x16x32_bf16(a1[tt], w1f[nt][1], acc, 0, 0, 0);
        #pragma unroll
        for (int q = 0; q < 4; q++)
          Hw[swz(lg*4 + q, lr + 16*nt)] = f2b(fmaxf(acc[q] + b1l[nt] + wnl[nt]*nzq[q], 0.f));
      }
      wsync();
      short8v h0 = *(const short8v*)&Hw[swz(lr, lg*8)];
      short8v h1 = *(const short8v*)&Hw[swz(lr, 32 + lg*8)];
      #pragma unroll
      for (int nt = 0; nt < 4; nt++){
        floatx4 acc = zz;
        acc = __builtin_amdgcn_mfma_f32_16x16x32_bf16(h0, w2f[nt][0], acc, 0, 0, 0);
        acc = __builtin_amdgcn_mfma_f32_16x16x32_bf16(h1, w2f[nt][1], acc, 0, 0, 0);
        #pragma unroll
        for (int q = 0; q < 4; q++){
          int rl = lg*4 + q, c = lr + 16*nt;
          stf(A, (size_t)(row0 + rl)*64 + c, acc[q] + b2l[nt]);
        }
      }
      wsync();
    }
  }
  // ---- v branch (both tiles) ----
  {
    short8v w1f[4][2], w2f[4][2];
    float rsvl[4], b1l[4], b2l[4];
    const short8v* W1 = (const short8v*)(wb + WB_IVW1);   // row stride 128 -> 16 vec
    const short8v* W2 = (const short8v*)(wb + WB_IVW2);
    #pragma unroll
    for (int nt = 0; nt < 4; nt++){
      int col = lr + 16*nt;
      b1l[nt] = vb1[col]; b2l[nt] = vb2[col];
      rsvl[nt] = rsvb[col];
      #pragma unroll
      for (int ks = 0; ks < 2; ks++){
        w1f[nt][ks] = W1[col*16 + ks*4 + lg];
        w2f[nt][ks] = W2[col*8 + ks*4 + lg];
      }
    }
    #pragma unroll
    for (int tt = 0; tt < 2; tt++){
      int row0 = (t0 + tt)*64 + wid*16;
      int b = row0 / VDIM;
      int vb = row0 - b*VDIM;
      int hv = h_index[b];
      bool cq[4];
      #pragma unroll
      for (int q = 0; q < 4; q++) cq[q] = (vb + lg*4 + q) == hv;
      #pragma unroll
      for (int nt = 0; nt < 4; nt++){
        floatx4 acc = zz;
        acc = __builtin_amdgcn_mfma_f32_16x16x32_bf16(a0[tt], w1f[nt][0], acc, 0, 0, 0);
        acc = __builtin_amdgcn_mfma_f32_16x16x32_bf16(a1[tt], w1f[nt][1], acc, 0, 0, 0);
        #pragma unroll
        for (int q = 0; q < 4; q++)
          Hw[swz(lg*4 + q, lr + 16*nt)] = f2b(fmaxf(acc[q] + b1l[nt] + (cq[q] ? rsvl[nt] : 0.f), 0.f));
      }
      wsync();
      short8v h0 = *(const short8v*)&Hw[swz(lr, lg*8)];
      short8v h1 = *(const short8v*)&Hw[swz(lr, 32 + lg*8)];
      #pragma unroll
      for (int nt = 0; nt < 4; nt++){
        floatx4 acc = zz;
        acc = __builtin_amdgcn_mfma_f32_16x16x32_bf16(h0, w2f[nt][0], acc, 0, 0, 0);
        acc = __builtin_amdgcn_mfma_f32_16x16x32_bf16(h1, w2f[nt][1], acc, 0, 0, 0);
        #pragma unroll
        for (int q = 0; q < 4; q++){
          int rl = lg*4 + q, c = lr + 16*nt;
          stf(B, (size_t)(row0 + rl)*64 + c, acc[q] + b2l[nt]);
        }
      }
      wsync();
    }
  }
}

// ---- rspmm gather, dual-chain: blocks [0,NRB4) = chain A, [NRB4,2NRB4) = chain B ----
// 4 vertices/block, 4 edges in flight
__global__ __launch_bounds__(256) void rspmm_dual(
    const int* __restrict__ row_ptr, const int2* __restrict__ pk,
    const float* __restrict__ zA, const float* __restrict__ zB,
    const bf16* __restrict__ XA, const bf16* __restrict__ XB,
    bf16* __restrict__ outA, bf16* __restrict__ outB){
  int bid = blockIdx.x;
  bool cb = bid >= NRB4;
  int v0 = (cb ? bid - NRB4 : bid) * 4;
  const float* zrel = cb ? zB : zA;
  const bf16* X = cb ? XB : XA;
  bf16* out = cb ? outB : outA;
  int btch = threadIdx.x >> 6, d = threadIdx.x & 63;
  int rp[5];
  #pragma unroll
  for (int i = 0; i < 5; i++) rp[i] = row_ptr[v0 + i];
  const float* zb = zrel + btch*RDIM*DDIM + d;
  size_t xb = (size_t)btch*VDIM*64 + d;
  size_t ob = ((size_t)btch*VDIM + v0)*64 + d;
  #pragma unroll 1
  for (int vi = 0; vi < 4; vi++){
    int s = rp[vi], e = rp[vi+1];
    float a0 = 0.f, a1 = 0.f, a2 = 0.f, a3 = 0.f;
    int i = s;
    for (; i + 4 <= e; i += 4){
      int2 e0 = pk[i], e1 = pk[i+1], e2 = pk[i+2], e3 = pk[i+3];
      float x0 = ldf(X, xb + (size_t)e0.y*64);
      float x1 = ldf(X, xb + (size_t)e1.y*64);
      float x2 = ldf(X, xb + (size_t)e2.y*64);
      float x3 = ldf(X, xb + (size_t)e3.y*64);
      a0 += zb[(size_t)e0.x*64] * x0;
      a1 += zb[(size_t)e1.x*64] * x1;
      a2 += zb[(size_t)e2.x*64] * x2;
      a3 += zb[(size_t)e3.x*64] * x3;
    }
    for (; i < e; i++){
      int2 ed = pk[i];
      a0 += zb[(size_t)ed.x*64] * ldf(X, xb + (size_t)ed.y*64);
    }
    stf(out, ob + (size_t)vi*64, a0 + a1 + a2 + a3);
  }
}

// ================= MFMA dense kernels =================
// Per wave: 16-row x 64-col tile. A-frag: lane holds row (lane&15), k-slice (lane>>4).
// B-frag (weights): lane holds W[col=(lane&15)+16nt][k-slice]. C/D: col=lane&15,
// row=(lane>>4)*4+q (m89-verified). LDS tiles [16][64] bf16 with row-XOR swizzle.

// ---- loop body, dual-chain, 2 tiles/block: X = LN(mlp2(O + alpha*X))*ng + nb + X ----
__global__ __launch_bounds__(256) void loop_dual_kernel(
    const bf16* __restrict__ OA, bf16* __restrict__ XA,
    const bf16* __restrict__ OB, bf16* __restrict__ XB,
    const float* __restrict__ alA, const unsigned short* __restrict__ w1A, const float* __restrict__ b1A,
    const unsigned short* __restrict__ w2A, const float* __restrict__ b2A,
    const float* __restrict__ ngA, const float* __restrict__ nbA,
    const float* __restrict__ alB, const unsigned short* __restrict__ w1B, const float* __restrict__ b1B,
    const unsigned short* __restrict__ w2B, const float* __restrict__ b2B,
    const float* __restrict__ ngB, const float* __restrict__ nbB){
  __shared__ unsigned short Tl[4][2048];
  __shared__ unsigned short Xl[4][2048];
  __shared__ unsigned short Hl[4][1024];
  int bid = blockIdx.x;
  bool cb = bid >= NDB;
  int pb = cb ? bid - NDB : bid;
  const bf16* O = cb ? OB : OA;
  bf16* X = cb ? XB : XA;
  const float* alpha = cb ? alB : alA;
  const unsigned short* w1 = cb ? w1B : w1A;
  const float* b1 = cb ? b1B : b1A;
  const unsigned short* w2 = cb ? w2B : w2A;
  const float* b2 = cb ? b2B : b2A;
  const float* ng = cb ? ngB : ngA;
  const float* nb = cb ? nbB : nbA;
  int tid = threadIdx.x, lane = tid & 63, wid = tid >> 6;
  int lr = lane & 15, lg = lane >> 4;
  short8v w1f[4][2], w2f[4][2];
  const short8v* W1 = (const short8v*)w1;
  const short8v* W2 = (const short8v*)w2;
  #pragma unroll
  for (int nt = 0; nt < 4; nt++){
    int col = lr + 16*nt;
    #pragma unroll
    for (int ks = 0; ks < 2; ks++){
      w1f[nt][ks] = W1[col*8 + ks*4 + lg];
      w2f[nt][ks] = W2[col*8 + ks*4 + lg];
    }
  }
  float4 al = ((const float4*)alpha)[lr];
  float b1l[4], b2l[4], ngl[4], nbl[4];
  #pragma unroll
  for (int nt = 0; nt < 4; nt++){
    int c = lr + 16*nt;
    b1l[nt] = b1[c]; b2l[nt] = b2[c]; ngl[nt] = ng[c]; nbl[nt] = nb[c];
  }
  unsigned short* Tw = Tl[wid];
  unsigned short* Xw = Xl[wid];
  unsigned short* Hw = Hl[wid];
  floatx4 zz = {0.f, 0.f, 0.f, 0.f};
  int t0 = pb*2;
  // stage both tiles (16 loads in flight); X copied raw, T = O + alpha*X
  #pragma unroll
  for (int tt = 0; tt < 2; tt++){
    int row0 = (t0 + tt)*64 + wid*16;
    #pragma unroll
    for (int it = 0; it < 4; it++){
      int rl = it*4 + lg;
      size_t gi = (size_t)(row0 + rl)*64 + 4*lr;
      ushort4 xw = *(const ushort4*)(X + gi);
      float4 ov4 = ldf4(O, gi);
      int si = tt*1024 + swz(rl, 4*lr);
      float4 tv;
      tv.x = ov4.x + al.x*b2f(xw.x);
      tv.y = ov4.y + al.y*b2f(xw.y);
      tv.z = ov4.z + al.z*b2f(xw.z);
      tv.w = ov4.w + al.w*b2f(xw.w);
      *(ushort4*)&Tw[si] = packb(tv);
      *(ushort4*)&Xw[si] = xw;
    }
  }
  wsync();
  #pragma unroll
  for (int tt = 0; tt < 2; tt++){
    int row0 = (t0 + tt)*64 + wid*16;
    short8v a0 = *(const short8v*)&Tw[tt*1024 + swz(lr, lg*8)];
    short8v a1 = *(const short8v*)&Tw[tt*1024 + swz(lr, 32 + lg*8)];
    #pragma unroll
    for (int nt = 0; nt < 4; nt++){
      floatx4 acc = zz;
      acc = __builtin_amdgcn_mfma_f32_16x16x32_bf16(a0, w1f[nt][0], acc, 0, 0, 0);
      acc = __builtin_amdgcn_mfma_f32_16x16x32_bf16(a1, w1f[nt][1], acc, 0, 0, 0);
      #pragma unroll
      for (int q = 0; q < 4; q++)
        Hw[swz(lg*4 + q, lr + 16*nt)] = f2b(fmaxf(acc[q] + b1l[nt], 0.f));
    }
    wsync();
    short8v h0 = *(const short8v*)&Hw[swz(lr, lg*8)];
    short8v h1 = *(const short8v*)&Hw[swz(lr, 32 + lg*8)];
    float y[4][4];
    float s[4] = {0.f,0.f,0.f,0.f}, ss[4] = {0.f,0.f,0.f,0.f};
    #pragma unroll
    for (int nt = 0; nt < 4; nt++){
      floatx4 acc = zz;
      acc = __builtin_amdgcn_mfma_f32_16x16x32_bf16(h0, w2f[nt][0], acc, 0, 0, 0);
      acc = __builtin_amdgcn_mfma_f32_16x16x32_bf16(h1, w2f[nt][1], acc, 0, 0, 0);
      #pragma unroll
      for (int q = 0; q < 4; q++){
        float v = acc[q] + b2l[nt];
        y[nt][q] = v; s[q] += v; ss[q] += v*v;
      }
    }
    #pragma unroll
    for (int o = 1; o < 16; o <<= 1){
      #pragma unroll
      for (int q = 0; q < 4; q++){
        s[q] += __shfl_xor(s[q], o, 64);
        ss[q] += __shfl_xor(ss[q], o, 64);
      }
    }
    float mu[4], rs[4];
    #pragma unroll
    for (int q = 0; q < 4; q++){
      mu[q] = s[q]*(1.f/64.f);
      float var = fmaxf(ss[q]*(1.f/64.f) - mu[q]*mu[q], 0.f);
      rs[q] = rsqrtf(var + LN_EPS);
    }
    #pragma unroll
    for (int nt = 0; nt < 4; nt++){
      #pragma unroll
      for (int q = 0; q < 4; q++){
        int rl = lg*4 + q, c = lr + 16*nt;
        float xs = b2f(Xw[tt*1024 + swz(rl, c)]);
        float v = (y[nt][q] - mu[q])*rs[q]*ngl[nt] + nbl[nt] + xs;
        stf(X, (size_t)(row0 + rl)*64 + c, v);
      }
    }
    wsync();
  }
}

// ---- kvred + qproj fused dispatch: blocks [0,NKV) kvred; [NKV,NKV+NTILE) qproj ----
__global__ __launch_bounds__(256) void kvred_qproj_kernel(
    const bf16* __restrict__ Xqk, const bf16* __restrict__ Xv,
    const unsigned short* __restrict__ wb, const float* __restrict__ bias,
    float* __restrict__ partial, bf16* __restrict__ qn_out){
  __shared__ unsigned short T1[4][1024];   // Xqk stage (swz) then kn_t [64][16]
  __shared__ unsigned short T2[4][1024];   // Xv stage (swz)
  __shared__ float red[4*1536];
  int tid = threadIdx.x, lane = tid & 63, wid = tid >> 6;
  int lr = lane & 15, lg = lane >> 4;
  floatx4 zz = {0.f, 0.f, 0.f, 0.f};
  const short8v z8 = {0,0,0,0,0,0,0,0};
  const short8v* WQ = (const short8v*)(wb + WB_QK);

  if (blockIdx.x >= NKV){
    // ---- qproj: one 64-row tile of Xqk -> head-normalized q (bf16) ----
    int tile = blockIdx.x - NKV;
    unsigned short* Tw = T1[wid];
    short8v wqf[4][2];
    float bq[4];
    #pragma unroll
    for (int nt = 0; nt < 4; nt++){
      int col = lr + 16*nt;                  // q-half of fc_to_qk
      bq[nt] = bias[col];
      #pragma unroll
      for (int ks = 0; ks < 2; ks++) wqf[nt][ks] = WQ[col*8 + ks*4 + lg];
    }
    int row0 = tile*64 + wid*16;
    #pragma unroll
    for (int it = 0; it < 4; it++){
      int rl = it*4 + lg;
      size_t gi = (size_t)(row0 + rl)*64 + 4*lr;
      *(ushort4*)&Tw[swz(rl, 4*lr)] = *(const ushort4*)(Xqk + gi);
    }
    wsync();
    short8v a0 = *(const short8v*)&Tw[swz(lr, lg*8)];
    short8v a1 = *(const short8v*)&Tw[swz(lr, 32 + lg*8)];
    float qn[4][4];
    #pragma unroll
    for (int nt = 0; nt < 4; nt++){
      floatx4 acc = zz;
      acc = __builtin_amdgcn_mfma_f32_16x16x32_bf16(a0, wqf[nt][0], acc, 0, 0, 0);
      acc = __builtin_amdgcn_mfma_f32_16x16x32_bf16(a1, wqf[nt][1], acc, 0, 0, 0);
      #pragma unroll
      for (int q = 0; q < 4; q++) qn[nt][q] = acc[q] + bq[nt];
    }
    #pragma unroll
    for (int nt = 0; nt < 4; nt++){
      float n0 = qn[nt][0]*qn[nt][0], n1 = qn[nt][1]*qn[nt][1];
      float n2 = qn[nt][2]*qn[nt][2], n3 = qn[nt][3]*qn[nt][3];
      #pragma unroll
      for (int o = 1; o < 16; o <<= 1){
        n0 += __shfl_xor(n0, o, 64); n1 += __shfl_xor(n1, o, 64);
        n2 += __shfl_xor(n2, o, 64); n3 += __shfl_xor(n3, o, 64);
      }
      qn[nt][0] /= fmaxf(sqrtf(n0), 1e-12f);
      qn[nt][1] /= fmaxf(sqrtf(n1), 1e-12f);
      qn[nt][2] /= fmaxf(sqrtf(n2), 1e-12f);
      qn[nt][3] /= fmaxf(sqrtf(n3), 1e-12f);
    }
    #pragma unroll
    for (int nt = 0; nt < 4; nt++)
      #pragma unroll
      for (int q = 0; q < 4; q++)
        stf(qn_out, (size_t)(row0 + lg*4 + q)*64 + lr + 16*nt, qn[nt][q]);
    return;
  }

  // ---- kvred ----
  short8v wkf[4][2];
  float bk[4];
  #pragma unroll
  for (int nt = 0; nt < 4; nt++){
    int col = 64 + lr + 16*nt;               // k-half of fc_to_qk
    bk[nt] = bias[col];
    #pragma unroll
    for (int ks = 0; ks < 2; ks++) wkf[nt][ks] = WQ[col*8 + ks*4 + lg];
  }
  int b = blockIdx.x / NBB, blk = blockIdx.x % NBB;
  unsigned short* Tw = T1[wid];
  unsigned short* Vw = T2[wid];
  floatx4 kvacc[4] = {zz, zz, zz, zz};
  float ksp[4] = {0.f,0.f,0.f,0.f};
  float vsp[4] = {0.f,0.f,0.f,0.f};
  for (int st = blk*4 + wid; st < 1250; st += NBB*4){
    size_t gr = (size_t)b*VDIM + (size_t)st*16;
    #pragma unroll
    for (int it = 0; it < 4; it++){
      int rl = it*4 + lg;
      size_t gi = (gr + rl)*64 + 4*lr;
      ushort4 tq = *(const ushort4*)(Xqk + gi);
      ushort4 tv = *(const ushort4*)(Xv + gi);
      int si = swz(rl, 4*lr);
      *(ushort4*)&Tw[si] = tq;
      *(ushort4*)&Vw[si] = tv;
      vsp[0] += b2f(tv.x); vsp[1] += b2f(tv.y); vsp[2] += b2f(tv.z); vsp[3] += b2f(tv.w);
    }
    wsync();
    short8v a0 = *(const short8v*)&Tw[swz(lr, lg*8)];
    short8v a1 = *(const short8v*)&Tw[swz(lr, 32 + lg*8)];
    // k-projection + head norm -> kn (C-layout regs), store kn_t to T1
    float kn[4][4];
    #pragma unroll
    for (int nt = 0; nt < 4; nt++){
      floatx4 acc = zz;
      acc = __builtin_amdgcn_mfma_f32_16x16x32_bf16(a0, wkf[nt][0], acc, 0, 0, 0);
      acc = __builtin_amdgcn_mfma_f32_16x16x32_bf16(a1, wkf[nt][1], acc, 0, 0, 0);
      #pragma unroll
      for (int q = 0; q < 4; q++) kn[nt][q] = acc[q] + bk[nt];
    }
    #pragma unroll
    for (int nt = 0; nt < 4; nt++){
      float n0 = kn[nt][0]*kn[nt][0], n1 = kn[nt][1]*kn[nt][1];
      float n2 = kn[nt][2]*kn[nt][2], n3 = kn[nt][3]*kn[nt][3];
      #pragma unroll
      for (int o = 1; o < 16; o <<= 1){
        n0 += __shfl_xor(n0, o, 64); n1 += __shfl_xor(n1, o, 64);
        n2 += __shfl_xor(n2, o, 64); n3 += __shfl_xor(n3, o, 64);
      }
      kn[nt][0] /= fmaxf(sqrtf(n0), 1e-12f);
      kn[nt][1] /= fmaxf(sqrtf(n1), 1e-12f);
      kn[nt][2] /= fmaxf(sqrtf(n2), 1e-12f);
      kn[nt][3] /= fmaxf(sqrtf(n3), 1e-12f);
      ksp[nt] += kn[nt][0] + kn[nt][1] + kn[nt][2] + kn[nt][3];
    }
    wsync();   // a0/a1 consumed; safe to overwrite T1 with kn_t
    #pragma unroll
    for (int nt = 0; nt < 4; nt++){
      int c = lr + 16*nt;
      #pragma unroll
      for (int q = 0; q < 4; q++)
        Tw[c*16 + lg*4 + q] = f2b(kn[nt][q]);
    }
    wsync();
    // kv += kn^T (A) x vx (B), per head, K=16 rows zero-padded to 32
    #pragma unroll
    for (int nt = 0; nt < 4; nt++){
      short8v af = z8, bf = z8;
      if (lg < 2){
        af = *(const short8v*)&Tw[(nt*16 + lr)*16 + lg*8];
        #pragma unroll
        for (int j = 0; j < 8; j++)
          bf[j] = (short)Vw[swz(lg*8 + j, nt*16 + lr)];
      }
      kvacc[nt] = __builtin_amdgcn_mfma_f32_16x16x32_bf16(af, bf, kvacc[nt], 0, 0, 0);
    }
    wsync();   // LDS reads done before next stripe overwrites tiles
  }
  // write per-wave partials
  float* rw = red + wid*1536;
  #pragma unroll
  for (int nt = 0; nt < 4; nt++){
    #pragma unroll
    for (int q = 0; q < 4; q++)
      rw[(nt*16 + lg*4 + q)*16 + lr] = kvacc[nt][q];
    rw[1024 + lg*64 + lr + 16*nt] = ksp[nt];
  }
  #pragma unroll
  for (int m = 0; m < 4; m++)
    rw[1280 + lg*64 + 4*lr + m] = vsp[m];
  __syncthreads();
  float* P = partial + (size_t)blockIdx.x*1152;
  for (int j = tid; j < 1152; j += 256){
    float s = 0.f;
    if (j < 1024){
      #pragma unroll
      for (int wv = 0; wv < 4; wv++) s += red[wv*1536 + j];
    } else if (j < 1088){
      int c = j - 1024;
      #pragma unroll
      for (int wv = 0; wv < 4; wv++)
        #pragma unroll
        for (int gg = 0; gg < 4; gg++) s += red[wv*1536 + 1024 + gg*64 + c];
    } else {
      int c = j - 1088;
      #pragma unroll
      for (int wv = 0; wv < 4; wv++)
        #pragma unroll
        for (int gg = 0; gg < 4; gg++) s += red[wv*1536 + 1280 + gg*64 + c];
    }
    P[j] = s;
  }
}

// ---- reduce kvred partials; also emit bf16 copies for attn fragments ----
__global__ void qkred_kernel(const float* __restrict__ partial,
                             float* __restrict__ kvs, float* __restrict__ ksum, float* __restrict__ vsum,
                             unsigned short* __restrict__ kvsb, unsigned short* __restrict__ ksb){
  int b = blockIdx.x / 5, ch = blockIdx.x % 5;
  int j = ch*256 + threadIdx.x;
  if (j >= 1152) return;
  const float* P = partial + (size_t)b*NBB*1152;
  float s = 0.f;
  for (int t = 0; t < NBB; t++) s += P[(size_t)t*1152 + j];
  if (j < 1024){      kvs[b*1024 + j] = s; kvsb[b*1024 + j] = f2b(s); }
  else if (j < 1088){ ksum[b*64 + (j-1024)] = s; ksb[b*64 + (j-1024)] = f2b(s); }
  else                vsum[b*64 + (j-1088)] = s;
}

// ---- fused attention + final FFN, 2 tiles/block; qn precomputed (no q-proj) ----
__global__ __launch_bounds__(256) void attn_final_kernel(
    const float* __restrict__ x, const bf16* __restrict__ QN, const bf16* __restrict__ Xv,
    const unsigned short* __restrict__ kvsb, const unsigned short* __restrict__ ksb,
    const float* __restrict__ vsum,
    const unsigned short* __restrict__ wb,
    const float* __restrict__ ag, const float* __restrict__ ab,
    const float* __restrict__ fb1, const float* __restrict__ fb2,
    const float* __restrict__ g, const float* __restrict__ bb,
    float* __restrict__ out){
  __shared__ unsigned short Ql[4][2048];
  __shared__ unsigned short Hl[4][1024];
  int tid = threadIdx.x, lane = tid & 63, wid = tid >> 6;
  int lr = lane & 15, lg = lane >> 4;
  // FFN weights (bf16 direct)
  short8v f1f[4][2], f2f[4][2];
  float agl[4], abl[4], b1l[4], b2l[4], gl[4], bl[4];
  const short8v* W1 = (const short8v*)(wb + WB_FW1);
  const short8v* W2 = (const short8v*)(wb + WB_FW2);
  #pragma unroll
  for (int nt = 0; nt < 4; nt++){
    int col = lr + 16*nt;
    agl[nt] = ag[col]; abl[nt] = ab[col];
    b1l[nt] = fb1[col]; b2l[nt] = fb2[col]; gl[nt] = g[col]; bl[nt] = bb[col];
    #pragma unroll
    for (int ks = 0; ks < 2; ks++){
      f1f[nt][ks] = W1[col*8 + ks*4 + lg];
      f2f[nt][ks] = W2[col*8 + ks*4 + lg];
    }
  }
  unsigned short* Qw = Ql[wid];
  unsigned short* Hw = Hl[wid];
  floatx4 zz = {0.f, 0.f, 0.f, 0.f};
  const short8v z8 = {0,0,0,0,0,0,0,0};
  int t0 = blockIdx.x*2;
  // stage both qn tiles (already bf16)
  #pragma unroll
  for (int tt = 0; tt < 2; tt++){
    int row0 = (t0 + tt)*64 + wid*16;
    #pragma unroll
    for (int it = 0; it < 4; it++){
      int rl = it*4 + lg;
      size_t gi = (size_t)(row0 + rl)*64 + 4*lr;
      *(ushort4*)&Qw[tt*1024 + swz(rl, 4*lr)] = *(const ushort4*)(QN + gi);
    }
  }
  wsync();
  #pragma unroll
  for (int tt = 0; tt < 2; tt++){
    int row0 = (t0 + tt)*64 + wid*16;
    int b = row0 / VDIM;                     // wave-uniform (16 | 20000)
    // per-head attention: num/den via zero-padded 16x16x32 MFMAs; kv frags from global
    float y[4][4];
    float s[4] = {0.f,0.f,0.f,0.f}, ss[4] = {0.f,0.f,0.f,0.f};
    #pragma unroll
    for (int nt = 0; nt < 4; nt++){
      short8v af = z8, bn = z8, bd = z8;
      if (lg < 2){
        af = *(const short8v*)&Qw[tt*1024 + swz(lr, nt*16 + lg*8)];
        bd = *(const short8v*)&ksb[b*64 + nt*16 + lg*8];
        #pragma unroll
        for (int j = 0; j < 8; j++)
          bn[j] = (short)kvsb[b*1024 + (nt*16 + lg*8 + j)*16 + lr];
      }
      int c = lr + 16*nt;
      float vsb = vsum[b*64 + c];
      floatx4 numc, denc;
      #pragma unroll
      for (int q = 0; q < 4; q++){
        float vv = ldf(Xv, (size_t)(row0 + lg*4 + q)*64 + c);
        numc[q] = vsb + vv*(float)VDIM;
        denc[q] = 2.0f*(float)VDIM;
      }
      numc = __builtin_amdgcn_mfma_f32_16x16x32_bf16(af, bn, numc, 0, 0, 0);
      denc = __builtin_amdgcn_mfma_f32_16x16x32_bf16(af, bd, denc, 0, 0, 0);
      #pragma unroll
      for (int q = 0; q < 4; q++){
        float xv = x[(size_t)(row0 + lg*4 + q)*64 + c];
        float v = xv + numc[q]/denc[q];
        y[nt][q] = v; s[q] += v; ss[q] += v*v;
      }
    }
    #pragma unroll
    for (int o = 1; o < 16; o <<= 1){
      #pragma unroll
      for (int q = 0; q < 4; q++){
        s[q] += __shfl_xor(s[q], o, 64);
        ss[q] += __shfl_xor(ss[q], o, 64);
      }
    }
    #pragma unroll
    for (int q = 0; q < 4; q++){
      float mu = s[q]*(1.f/64.f);
      float var = fmaxf(ss[q]*(1.f/64.f) - mu*mu, 0.f);
      float rs = rsqrtf(var + LN_EPS);
      #pragma unroll
      for (int nt = 0; nt < 4; nt++)
        y[nt][q] = (y[nt][q] - mu)*rs*agl[nt] + abl[nt];
    }
    // FFN + LN2 (residual y in regs)
    wsync();   // per-head Qw reads done; overwrite tile-tt with xa
    #pragma unroll
    for (int nt = 0; nt < 4; nt++){
      #pragma unroll
      for (int q = 0; q < 4; q++)
        Qw[tt*1024 + swz(lg*4 + q, lr + 16*nt)] = f2b(y[nt][q]);
    }
    wsync();
    short8v xa0 = *(const short8v*)&Qw[tt*1024 + swz(lr, lg*8)];
    short8v xa1 = *(const short8v*)&Qw[tt*1024 + swz(lr, 32 + lg*8)];
    #pragma unroll
    for (int nt = 0; nt < 4; nt++){
      floatx4 acc = zz;
      acc = __builtin_amdgcn_mfma_f32_16x16x32_bf16(xa0, f1f[nt][0], acc, 0, 0, 0);
      acc = __builtin_amdgcn_mfma_f32_16x16x32_bf16(xa1, f1f[nt][1], acc, 0, 0, 0);
      #pragma unroll
      for (int q = 0; q < 4; q++)
        Hw[swz(lg*4 + q, lr + 16*nt)] = f2b(fmaxf(acc[q] + b1l[nt], 0.f));
    }
    wsync();
    short8v h0 = *(const short8v*)&Hw[swz(lr, lg*8)];
    short8v h1 = *(const short8v*)&Hw[swz(lr, 32 + lg*8)];
    float t[4][4];
    float s2[4] = {0.f,0.f,0.f,0.f}, ss2[4] = {0.f,0.f,0.f,0.f};
    #pragma unroll
    for (int nt = 0; nt < 4; nt++){
      floatx4 acc = zz;
      acc = __builtin_amdgcn_mfma_f32_16x16x32_bf16(h0, f2f[nt][0], acc, 0, 0, 0);
      acc = __builtin_amdgcn_mfma_f32_16x16x32_bf16(h1, f2f[nt][1], acc, 0, 0, 0);
      #pragma unroll
      for (int q = 0; q < 4; q++){
        float v = acc[q] + b2l[nt] + y[nt][q];
        t[nt][q] = v; s2[q] += v; ss2[q] += v*v;
      }
    }
    #pragma unroll
    for (int o = 1; o < 16; o <<= 1){
      #pragma unroll
      for (int q = 0; q < 4; q++){
        s2[q] += __shfl_xor(s2[q], o, 64);
        ss2[q] += __shfl_xor(ss2[q], o, 64);
      }
    }
    #pragma unroll
    for (int q = 0; q < 4; q++){
      float mu = s2[q]*(1.f/64.f);
      float var = fmaxf(ss2[q]*(1.f/64.f) - mu*mu, 0.f);
      float rs = rsqrtf(var + LN_EPS);
      #pragma unroll
      for (int nt = 0; nt < 4; nt++){
        int c = lr + 16*nt;
        out[(size_t)(row0 + lg*4 + q)*64 + c] = (t[nt][q] - mu)*rs*gl[nt] + bl[nt];
      }
    }
    wsync();   // Hw reused by next tile
  }
}

// ================= host side =================
static const int DICT_SIZES[42] = {
  5120000,256,256,80000,262144,4096,4160,64,4096,64,
  8192,64,4096,64,8192,128,8192,128,8192,128,
  128,128,128,524288,8192,8192,128,8192,128,128,
  128,128,4096,64,4096,64,64,64,64,64,
  4,600000};

static void run_pipeline(const float* const* N, const int* hi,
                         const int* ei_raw, const int* eflag,
                         int* cursor, int2* pk, const int* row_ptr,
                         float* qk_z, float* zr, float* kvs, float* part,
                         unsigned short* kvsb, unsigned short* wb, float* rsvb,
                         bf16* A, bf16* B, bf16* OA, bf16* OB, bool dual,
                         float* outp, hipStream_t stream){
  float* ksum = kvs + 4096;
  float* vsum = kvs + 4352;
  unsigned short* ksb = kvsb + 4096;

  // fused: scatter (needs scan done) + init_both (independent) in one dispatch
  scatter_init_kernel<<<NSC + NDB, 256, 0, stream>>>(ei_raw, eflag, cursor, pk,
      N[0], N[3], hi, wb, rsvb, N[6], N[7], N[9], N[11], N[13], A, B);

  if (dual){
    for (int i = 0; i < 2; i++){
      rspmm_dual<<<2*NRB4, 256, 0, stream>>>(row_ptr, pk, qk_z, zr + i*16384, A, B, OA, OB);
      loop_dual_kernel<<<2*NDB, 256, 0, stream>>>(OA, A, OB, B,
          N[20] + i*64, wb + WB_QKW1 + i*4096, N[17] + i*64, wb + WB_QKW2 + i*4096, N[19] + i*64, N[21] + i*64, N[22] + i*64,
          N[29] + i*64, wb + WB_VW1 + i*4096, N[26] + i*64, wb + WB_VW2 + i*4096, N[28] + i*64, N[30] + i*64, N[31] + i*64);
    }
  } else {
    for (int i = 0; i < 2; i++){
      rspmm_dual<<<NRB4, 256, 0, stream>>>(row_ptr, pk, qk_z, qk_z, A, A, OA, OA);
      loop_dual_kernel<<<NDB, 256, 0, stream>>>(OA, A, OA, A,
          N[20] + i*64, wb + WB_QKW1 + i*4096, N[17] + i*64, wb + WB_QKW2 + i*4096, N[19] + i*64, N[21] + i*64, N[22] + i*64,
          N[20] + i*64, wb + WB_QKW1 + i*4096, N[17] + i*64, wb + WB_QKW2 + i*4096, N[19] + i*64, N[21] + i*64, N[22] + i*64);
    }
    for (int i = 0; i < 2; i++){
      rspmm_dual<<<NRB4, 256, 0, stream>>>(row_ptr, pk, zr + i*16384, zr + i*16384, B, B, OA, OA);
      loop_dual_kernel<<<NDB, 256, 0, stream>>>(OA, B, OA, B,
          N[29] + i*64, wb + WB_VW1 + i*4096, N[26] + i*64, wb + WB_VW2 + i*4096, N[28] + i*64, N[30] + i*64, N[31] + i*64,
          N[29] + i*64, wb + WB_VW1 + i*4096, N[26] + i*64, wb + WB_VW2 + i*4096, N[28] + i*64, N[30] + i*64, N[31] + i*64);
    }
  }

  // kvred + q-projection (independent block ranges) in one dispatch; qn -> OA (free)
  kvred_qproj_kernel<<<NKV + NTILE, 256, 0, stream>>>(A, B, wb, N[15], part, OA);
  qkred_kernel<<<20, 256, 0, stream>>>(part, kvs, ksum, vsum, kvsb, ksb);
  attn_final_kernel<<<NDB, 256, 0, stream>>>(N[0], OA, B, kvsb, ksb, vsum,
      wb, N[36], N[37], N[33], N[35], N[38], N[39], outp);
}

extern "C" void kernel_launch(void* const* d_in, const int* in_sizes, int n_in,
                              void* d_out, int out_size, void* d_ws, size_t ws_size,
                              hipStream_t stream){
  float* outp = (float*)d_out;
  const int GOUT = (out_size + 255) / 256;

  if (n_in != 42){
    fill_kernel<<<GOUT, 256, 0, stream>>>(outp, 2000.0f + (float)n_in, out_size);
    return;
  }
  auto sz_ok = [&](int s, int e)->bool{
    if (s == e) return true;
    if ((e == 4 || e == 600000) && s == 2*e) return true;
    return false;
  };
  int bad = -1;
  for (int i = 0; i < 42 && bad < 0; i++)
    if (!sz_ok(in_sizes[i], DICT_SIZES[i])) bad = i;
  if (bad >= 0){
    fill_kernel<<<GOUT, 256, 0, stream>>>(outp, 1000.0f + (float)bad, out_size);
    return;
  }

  const float* N[40];
  for (int i = 0; i < 40; i++) N[i] = (const float*)d_in[i];
  const int* hi_raw = (const int*)d_in[40];
  const int* ei_raw = (const int*)d_in[41];

  char* p = (char*)d_ws;
  auto alloc = [&](size_t bytes)->char*{ char* r = p; p += (bytes + 255) / 256 * 256; return r; };
  int* hi      = (int*)alloc(256);
  int* eflag   = (int*)alloc(256);
  int* counts  = (int*)alloc((VDIM+1)*4);
  int* row_ptr = (int*)alloc((VDIM+1)*4);
  int* cursor  = (int*)alloc((VDIM+1)*4);
  int2* pk     = (int2*)alloc((size_t)EDIM*8);
  float* qk_z  = (float*)alloc(16384u*4);
  float* zr    = (float*)alloc(32768u*4);
  float* kvs   = (float*)alloc(4608u*4);
  unsigned short* kvsb = (unsigned short*)alloc(4352u*2);
  unsigned short* wb   = (unsigned short*)alloc((size_t)WB_TOT*2);
  float* rsvb  = (float*)alloc(64*4);
  float* part  = (float*)alloc((size_t)BDIM*NBB*1152*4);
  size_t fixed = (size_t)(p - (char*)d_ws);
  const size_t bufH = (size_t)BV*64*2;

  // setup: detect64 + zero counts + zcalc + weight bf16 conversion, one dispatch
  setup_kernel<<<273 + (WC_TOT+255)/256, 256, 0, stream>>>(ei_raw, eflag, counts,
      N[1], N[4], N[5], N[23], N[24], qk_z, zr,
      N[16], N[18], N[25], N[27], N[6], N[8], N[10], N[12], N[14], N[32], N[34],
      wb, rsvb);
  prep_count_kernel<<<(EDIM+255)/256, 256, 0, stream>>>(ei_raw, hi_raw, eflag, hi, counts);
  scan_kernel<<<1, 256, 0, stream>>>(counts, row_ptr, cursor);

  // bf16 workspace: halves intermediate traffic, makes rspmm X L2-resident.
  if (ws_size >= fixed + 4*bufH + 1024){
    bf16* A  = (bf16*)alloc(bufH);
    bf16* B  = (bf16*)alloc(bufH);
    bf16* OA = (bf16*)alloc(bufH);
    bf16* OB = (bf16*)alloc(bufH);
    run_pipeline(N, hi, ei_raw, eflag, cursor, pk, row_ptr,
                 qk_z, zr, kvs, part, kvsb, wb, rsvb, A, B, OA, OB, true, outp, stream);
  } else {
    bf16* A  = (bf16*)alloc(bufH);
    bf16* B  = (bf16*)alloc(bufH);
    bf16* OA = (bf16*)alloc(bufH);
    run_pipeline(N, hi, ei_raw, eflag, cursor, pk, row_ptr,
                 qk_z, zr, kvs, part, kvsb, wb, rsvb, A, B, OA, OA, false, outp, stream);
  }
}

// Round 16
// 444.040 us; speedup vs baseline: 1.2040x; 1.0050x over previous
//
#include <hip/hip_runtime.h>
#include <hip/hip_bf16.h>

#define BDIM 4
#define VDIM 20000
#define DDIM 64
#define RDIM 64
#define EDIM 200000
#define BV (BDIM*VDIM)
#define LN_EPS 1e-5f
#define NBB 125           // kvred blocks per batch
#define NTILE 1250        // BV/64 row-tiles
#define NDB 625           // dense blocks per chain (2 tiles each)
#define NRB4 (VDIM/4)     // rspmm blocks per chain (4 vertices each)
#define NSC ((EDIM+255)/256)  // scatter blocks (782)
#define NKV (BDIM*NBB)    // kvred blocks (500)

// bf16 weight buffer element offsets (all multiples of 8)
#define WB_QKW1 0         // [2][64][64]
#define WB_QKW2 8192
#define WB_VW1  16384
#define WB_VW2  24576
#define WB_IQW1 32768     // [64][64] (noise col dropped)
#define WB_IQW2 36928     // [64][64]  (36864..36928 unused pad)
#define WB_IVW1 41024     // [64][128]
#define WB_IVW2 49216
#define WB_QK   53312     // [128][64]
#define WB_FW1  61504
#define WB_FW2  65600
#define WB_TOT  69696
#define WC_TOT  69760     // + 64 rsv sums

typedef __hip_bfloat16 bf16;
typedef __attribute__((ext_vector_type(8))) short short8v;
typedef __attribute__((ext_vector_type(4))) float floatx4;

__device__ __forceinline__ float ldf(const float* p, size_t i){ return p[i]; }
__device__ __forceinline__ float ldf(const bf16* p, size_t i){ return __bfloat162float(p[i]); }
__device__ __forceinline__ void stf(float* p, size_t i, float v){ p[i] = v; }
__device__ __forceinline__ void stf(bf16* p, size_t i, float v){ p[i] = __float2bfloat16(v); }

__device__ __forceinline__ unsigned short f2b(float f){
  unsigned u = __builtin_bit_cast(unsigned, f);
  u += 0x7fffu + ((u >> 16) & 1u);
  return (unsigned short)(u >> 16);
}
__device__ __forceinline__ float b2f(unsigned short h){
  unsigned u = ((unsigned)h) << 16;
  return __builtin_bit_cast(float, u);
}
__device__ __forceinline__ float4 ldf4(const float* p, size_t i){ return *(const float4*)(p+i); }
__device__ __forceinline__ float4 ldf4(const bf16* p, size_t i){
  ushort4 u = *(const ushort4*)(p+i);
  return make_float4(b2f(u.x), b2f(u.y), b2f(u.z), b2f(u.w));
}
// LDS tile swizzle: element index for [16][64] bf16 tile, 16B-unit XOR on row
__device__ __forceinline__ int swz(int r, int c){ return r*64 + (c ^ ((r & 7) << 3)); }

__device__ __forceinline__ float dot4(float4 a, float4 b){
  return a.x*b.x + a.y*b.y + a.z*b.z + a.w*b.w;
}

// Wave-private LDS ordering: DS ops from one wave execute in order; just fence compiler.
__device__ __forceinline__ void wsync(){
  __builtin_amdgcn_wave_barrier();
  __asm__ volatile("" ::: "memory");
}

__device__ __forceinline__ ushort4 packb(float4 v){
  ushort4 t; t.x = f2b(v.x); t.y = f2b(v.y); t.z = f2b(v.z); t.w = f2b(v.w); return t;
}

// ---- diagnostic fill ----
__global__ void fill_kernel(float* __restrict__ out, float v, int n){
  int t = blockIdx.x * 256 + threadIdx.x;
  if (t < n) out[t] = v;
}

// ---- setup: blocks 0..79 zero counts, 80..271 zcalc, 272 detect, 273.. weight conv ----
__global__ void setup_kernel(const int* __restrict__ ei_raw, int* __restrict__ flag,
                             int* __restrict__ counts,
                             const float* __restrict__ z,
                             const float* __restrict__ qkzw, const float* __restrict__ qkzb,
                             const float* __restrict__ vfw,  const float* __restrict__ vfb,
                             float* __restrict__ qk_z, float* __restrict__ zr,
                             const float* __restrict__ qkw1, const float* __restrict__ qkw2,
                             const float* __restrict__ vw1l, const float* __restrict__ vw2l,
                             const float* __restrict__ iqw1, const float* __restrict__ iqw2,
                             const float* __restrict__ ivw1, const float* __restrict__ ivw2,
                             const float* __restrict__ qkpw, const float* __restrict__ fw1,
                             const float* __restrict__ fw2,
                             unsigned short* __restrict__ wb, float* __restrict__ rsvb){
  int bid = blockIdx.x, tid = threadIdx.x;
  if (bid >= 273){
    int e = (bid - 273)*256 + tid;
    if (e >= WC_TOT) return;
    if (e >= WB_TOT){
      int col = e - WB_TOT;
      const float4* r4 = (const float4*)(ivw1 + col*128 + 64);
      float rsv = 0.f;
      #pragma unroll
      for (int i = 0; i < 16; i++){ float4 t = r4[i]; rsv += t.x + t.y + t.z + t.w; }
      rsvb[col] = rsv;
      return;
    }
    float v;
    if (e < WB_QKW2)        v = qkw1[e];
    else if (e < WB_VW1)    v = qkw2[e - WB_QKW2];
    else if (e < WB_VW2)    v = vw1l[e - WB_VW1];
    else if (e < WB_IQW1)   v = vw2l[e - WB_VW2];
    else if (e < 36864){ int j = e - WB_IQW1; v = iqw1[(j>>6)*65 + (j&63)]; }
    else if (e < WB_IQW2)   v = 0.f;                      // pad
    else if (e < WB_IVW1)   v = iqw2[e - WB_IQW2];
    else if (e < WB_IVW2)   v = ivw1[e - WB_IVW1];
    else if (e < WB_QK)     v = ivw2[e - WB_IVW2];
    else if (e < WB_FW1)    v = qkpw[e - WB_QK];
    else if (e < WB_FW2)    v = fw1[e - WB_FW1];
    else                    v = fw2[e - WB_FW2];
    wb[e] = f2b(v);
    return;
  }
  if (bid == 272){
    int nz = 0;
    for (int j = 2*tid + 1; j < 1024; j += 512) nz |= (ei_raw[j] != 0);
    nz = __any(nz);
    __shared__ int r[4];
    if ((tid & 63) == 0) r[tid >> 6] = nz;
    __syncthreads();
    if (tid == 0) flag[0] = (r[0] | r[1] | r[2] | r[3]) ? 0 : 1;   // 1 => 64-bit
    return;
  }
  if (bid < 80){
    int i = bid*256 + tid;
    if (i < VDIM + 1) counts[i] = 0;
    return;
  }
  int idx = (bid - 80)*256 + tid;
  if (idx >= 49152) return;
  int which = idx >> 14;
  int r = idx & 16383;
  int b = r >> 12;
  int j = r & 4095;
  const float* wrow; float bias; float* outp;
  if (which == 0){ wrow = qkzw + (size_t)j*DDIM; bias = qkzb[j]; outp = qk_z; }
  else { int i = which - 1; wrow = vfw + (size_t)(i*4096 + j)*DDIM; bias = vfb[i*4096 + j]; outp = zr + i*16384; }
  const float4* zr4 = (const float4*)(z + (size_t)b*DDIM);
  const float4* wr4 = (const float4*)wrow;
  float acc = bias;
  #pragma unroll
  for (int i = 0; i < 16; i++) acc += dot4(zr4[i], wr4[i]);
  outp[r] = acc;
}

// ---- count directly from raw edges (is64-aware) + hi normalize ----
__global__ void prep_count_kernel(const int* __restrict__ ei_raw, const int* __restrict__ hi_raw,
                                  const int* __restrict__ flag,
                                  int* __restrict__ hi, int* __restrict__ counts){
  int is64 = flag[0];
  int e = blockIdx.x * 256 + threadIdx.x;
  if (e < EDIM){
    int dst = is64 ? ei_raw[6*e]   : ei_raw[3*e];
    int rel = is64 ? ei_raw[6*e+2] : ei_raw[3*e+1];
    int src = is64 ? ei_raw[6*e+4] : ei_raw[3*e+2];
    if ((unsigned)dst < VDIM && (unsigned)rel < RDIM && (unsigned)src < VDIM)
      atomicAdd(&counts[dst], 1);
  }
  if (e < BDIM) hi[e] = is64 ? hi_raw[2*e] : hi_raw[e];
}

// ---- scan: per-thread segments + one wave scan, 1 barrier total ----
__global__ void scan_kernel(const int* __restrict__ counts, int* __restrict__ row_ptr, int* __restrict__ cursor){
  __shared__ int wsum[4];
  int tid = threadIdx.x, lane = tid & 63, wid = tid >> 6;
  const int SEG = (VDIM + 255) / 256;        // 79
  int lo = tid * SEG;
  int hi = lo + SEG; if (hi > VDIM) hi = VDIM;
  int s = 0;
  for (int i = lo; i < hi; i++) s += counts[i];
  int x = s;
  #pragma unroll
  for (int o = 1; o < 64; o <<= 1){
    int t = __shfl_up(x, o, 64);
    if (lane >= o) x += t;
  }
  if (lane == 63) wsum[wid] = x;
  __syncthreads();
  int wo = 0;
  for (int w = 0; w < wid; w++) wo += wsum[w];
  int run = wo + x - s;                      // exclusive prefix of this thread's segment
  for (int i = lo; i < hi; i++){
    row_ptr[i] = run; cursor[i] = run; run += counts[i];
  }
  if (tid == 255) row_ptr[VDIM] = run;       // total
}

// ---- fused scatter + init_both: blocks [0,NSC) scatter, [NSC,NSC+NDB) init ----
__global__ __launch_bounds__(256) void scatter_init_kernel(
    const int* __restrict__ ei_raw, const int* __restrict__ flag,
    int* __restrict__ cursor, int2* __restrict__ pk,
    const float* __restrict__ x, const float* __restrict__ noise, const int* __restrict__ h_index,
    const unsigned short* __restrict__ wb, const float* __restrict__ rsvb,
    const float* __restrict__ iqw1f, const float* __restrict__ qb1, const float* __restrict__ qb2,
    const float* __restrict__ vb1, const float* __restrict__ vb2,
    bf16* __restrict__ A, bf16* __restrict__ B){
  if (blockIdx.x < NSC){
    int is64 = flag[0];
    int e = blockIdx.x * 256 + threadIdx.x;
    if (e < EDIM){
      int dst = is64 ? ei_raw[6*e]   : ei_raw[3*e];
      int rel = is64 ? ei_raw[6*e+2] : ei_raw[3*e+1];
      int src = is64 ? ei_raw[6*e+4] : ei_raw[3*e+2];
      if ((unsigned)dst < VDIM && (unsigned)rel < RDIM && (unsigned)src < VDIM){
        int p = atomicAdd(&cursor[dst], 1);
        pk[p] = make_int2(rel, src);
      }
    }
    return;
  }
  __shared__ unsigned short Tl[4][2048];
  __shared__ unsigned short Hl[4][1024];
  __shared__ float Nl[4][32];
  int tid = threadIdx.x, lane = tid & 63, wid = tid >> 6;
  int lr = lane & 15, lg = lane >> 4;
  unsigned short* Tw = Tl[wid];
  unsigned short* Hw = Hl[wid];
  floatx4 zz = {0.f, 0.f, 0.f, 0.f};
  int t0 = (blockIdx.x - NSC)*2;
  // stage both x tiles + noise
  #pragma unroll
  for (int tt = 0; tt < 2; tt++){
    int row0 = (t0 + tt)*64 + wid*16;
    #pragma unroll
    for (int it = 0; it < 4; it++){
      int rl = it*4 + lg;
      size_t gi = (size_t)(row0 + rl)*64 + 4*lr;
      float4 x4 = ldf4(x, gi);
      *(ushort4*)&Tw[tt*1024 + swz(rl, 4*lr)] = packb(x4);
      if (lr == 0) Nl[wid][tt*16 + rl] = noise[row0 + rl];
    }
  }
  wsync();
  short8v a0[2], a1[2];
  #pragma unroll
  for (int tt = 0; tt < 2; tt++){
    a0[tt] = *(const short8v*)&Tw[tt*1024 + swz(lr, lg*8)];
    a1[tt] = *(const short8v*)&Tw[tt*1024 + swz(lr, 32 + lg*8)];
  }
  // ---- qk branch (both tiles) ----
  {
    short8v w1f[4][2], w2f[4][2];
    float wnl[4], b1l[4], b2l[4];
    const short8v* W1 = (const short8v*)(wb + WB_IQW1);
    const short8v* W2 = (const short8v*)(wb + WB_IQW2);
    #pragma unroll
    for (int nt = 0; nt < 4; nt++){
      int col = lr + 16*nt;
      wnl[nt] = iqw1f[col*65 + 64];
      b1l[nt] = qb1[col]; b2l[nt] = qb2[col];
      #pragma unroll
      for (int ks = 0; ks < 2; ks++){
        w1f[nt][ks] = W1[col*8 + ks*4 + lg];
        w2f[nt][ks] = W2[col*8 + ks*4 + lg];
      }
    }
    #pragma unroll
    for (int tt = 0; tt < 2; tt++){
      int row0 = (t0 + tt)*64 + wid*16;
      float nzq[4];
      #pragma unroll
      for (int q = 0; q < 4; q++) nzq[q] = Nl[wid][tt*16 + lg*4 + q];
      #pragma unroll
      for (int nt = 0; nt < 4; nt++){
        floatx4 acc = zz;
        acc = __builtin_amdgcn_mfma_f32_16x16x32_bf16(a0[tt], w1f[nt][0], acc, 0, 0, 0);
        acc = __builtin_amdgcn_mfma_f32_16x16x32_bf16(a1[tt], w1f[nt][1], acc, 0, 0, 0);
        #pragma unroll
        for (int q = 0; q < 4; q++)
          Hw[swz(lg*4 + q, lr + 16*nt)] = f2b(fmaxf(acc[q] + b1l[nt] + wnl[nt]*nzq[q], 0.f));
      }
      wsync();
      short8v h0 = *(const short8v*)&Hw[swz(lr, lg*8)];
      short8v h1 = *(const short8v*)&Hw[swz(lr, 32 + lg*8)];
      #pragma unroll
      for (int nt = 0; nt < 4; nt++){
        floatx4 acc = zz;
        acc = __builtin_amdgcn_mfma_f32_16x16x32_bf16(h0, w2f[nt][0], acc, 0, 0, 0);
        acc = __builtin_amdgcn_mfma_f32_16x16x32_bf16(h1, w2f[nt][1], acc, 0, 0, 0);
        #pragma unroll
        for (int q = 0; q < 4; q++){
          int rl = lg*4 + q, c = lr + 16*nt;
          stf(A, (size_t)(row0 + rl)*64 + c, acc[q] + b2l[nt]);
        }
      }
      wsync();
    }
  }
  // ---- v branch (both tiles) ----
  {
    short8v w1f[4][2], w2f[4][2];
    float rsvl[4], b1l[4], b2l[4];
    const short8v* W1 = (const short8v*)(wb + WB_IVW1);   // row stride 128 -> 16 vec
    const short8v* W2 = (const short8v*)(wb + WB_IVW2);
    #pragma unroll
    for (int nt = 0; nt < 4; nt++){
      int col = lr + 16*nt;
      b1l[nt] = vb1[col]; b2l[nt] = vb2[col];
      rsvl[nt] = rsvb[col];
      #pragma unroll
      for (int ks = 0; ks < 2; ks++){
        w1f[nt][ks] = W1[col*16 + ks*4 + lg];
        w2f[nt][ks] = W2[col*8 + ks*4 + lg];
      }
    }
    #pragma unroll
    for (int tt = 0; tt < 2; tt++){
      int row0 = (t0 + tt)*64 + wid*16;
      int b = row0 / VDIM;
      int vb = row0 - b*VDIM;
      int hv = h_index[b];
      bool cq[4];
      #pragma unroll
      for (int q = 0; q < 4; q++) cq[q] = (vb + lg*4 + q) == hv;
      #pragma unroll
      for (int nt = 0; nt < 4; nt++){
        floatx4 acc = zz;
        acc = __builtin_amdgcn_mfma_f32_16x16x32_bf16(a0[tt], w1f[nt][0], acc, 0, 0, 0);
        acc = __builtin_amdgcn_mfma_f32_16x16x32_bf16(a1[tt], w1f[nt][1], acc, 0, 0, 0);
        #pragma unroll
        for (int q = 0; q < 4; q++)
          Hw[swz(lg*4 + q, lr + 16*nt)] = f2b(fmaxf(acc[q] + b1l[nt] + (cq[q] ? rsvl[nt] : 0.f), 0.f));
      }
      wsync();
      short8v h0 = *(const short8v*)&Hw[swz(lr, lg*8)];
      short8v h1 = *(const short8v*)&Hw[swz(lr, 32 + lg*8)];
      #pragma unroll
      for (int nt = 0; nt < 4; nt++){
        floatx4 acc = zz;
        acc = __builtin_amdgcn_mfma_f32_16x16x32_bf16(h0, w2f[nt][0], acc, 0, 0, 0);
        acc = __builtin_amdgcn_mfma_f32_16x16x32_bf16(h1, w2f[nt][1], acc, 0, 0, 0);
        #pragma unroll
        for (int q = 0; q < 4; q++){
          int rl = lg*4 + q, c = lr + 16*nt;
          stf(B, (size_t)(row0 + rl)*64 + c, acc[q] + b2l[nt]);
        }
      }
      wsync();
    }
  }
}

// ---- rspmm gather, dual-chain: blocks [0,NRB4) = chain A, [NRB4,2NRB4) = chain B ----
// 4 vertices/block, 8 edges in flight (math bit-identical to 4-edge version:
// two sequential 4-groups into the same accumulators, loads hoisted)
__global__ __launch_bounds__(256) void rspmm_dual(
    const int* __restrict__ row_ptr, const int2* __restrict__ pk,
    const float* __restrict__ zA, const float* __restrict__ zB,
    const bf16* __restrict__ XA, const bf16* __restrict__ XB,
    bf16* __restrict__ outA, bf16* __restrict__ outB){
  int bid = blockIdx.x;
  bool cb = bid >= NRB4;
  int v0 = (cb ? bid - NRB4 : bid) * 4;
  const float* zrel = cb ? zB : zA;
  const bf16* X = cb ? XB : XA;
  bf16* out = cb ? outB : outA;
  int btch = threadIdx.x >> 6, d = threadIdx.x & 63;
  int rp[5];
  #pragma unroll
  for (int i = 0; i < 5; i++) rp[i] = row_ptr[v0 + i];
  const float* zb = zrel + btch*RDIM*DDIM + d;
  size_t xb = (size_t)btch*VDIM*64 + d;
  size_t ob = ((size_t)btch*VDIM + v0)*64 + d;
  #pragma unroll 1
  for (int vi = 0; vi < 4; vi++){
    int s = rp[vi], e = rp[vi+1];
    float a0 = 0.f, a1 = 0.f, a2 = 0.f, a3 = 0.f;
    int i = s;
    for (; i + 8 <= e; i += 8){
      int2 e0 = pk[i],   e1 = pk[i+1], e2 = pk[i+2], e3 = pk[i+3];
      int2 e4 = pk[i+4], e5 = pk[i+5], e6 = pk[i+6], e7 = pk[i+7];
      float x0 = ldf(X, xb + (size_t)e0.y*64);
      float x1 = ldf(X, xb + (size_t)e1.y*64);
      float x2 = ldf(X, xb + (size_t)e2.y*64);
      float x3 = ldf(X, xb + (size_t)e3.y*64);
      float x4 = ldf(X, xb + (size_t)e4.y*64);
      float x5 = ldf(X, xb + (size_t)e5.y*64);
      float x6 = ldf(X, xb + (size_t)e6.y*64);
      float x7 = ldf(X, xb + (size_t)e7.y*64);
      float z0 = zb[(size_t)e0.x*64], z1 = zb[(size_t)e1.x*64];
      float z2 = zb[(size_t)e2.x*64], z3 = zb[(size_t)e3.x*64];
      float z4 = zb[(size_t)e4.x*64], z5 = zb[(size_t)e5.x*64];
      float z6 = zb[(size_t)e6.x*64], z7 = zb[(size_t)e7.x*64];
      a0 += z0*x0; a1 += z1*x1; a2 += z2*x2; a3 += z3*x3;
      a0 += z4*x4; a1 += z5*x5; a2 += z6*x6; a3 += z7*x7;
    }
    for (; i + 4 <= e; i += 4){
      int2 e0 = pk[i], e1 = pk[i+1], e2 = pk[i+2], e3 = pk[i+3];
      float x0 = ldf(X, xb + (size_t)e0.y*64);
      float x1 = ldf(X, xb + (size_t)e1.y*64);
      float x2 = ldf(X, xb + (size_t)e2.y*64);
      float x3 = ldf(X, xb + (size_t)e3.y*64);
      a0 += zb[(size_t)e0.x*64] * x0;
      a1 += zb[(size_t)e1.x*64] * x1;
      a2 += zb[(size_t)e2.x*64] * x2;
      a3 += zb[(size_t)e3.x*64] * x3;
    }
    for (; i < e; i++){
      int2 ed = pk[i];
      a0 += zb[(size_t)ed.x*64] * ldf(X, xb + (size_t)ed.y*64);
    }
    stf(out, ob + (size_t)vi*64, a0 + a1 + a2 + a3);
  }
}

// ================= MFMA dense kernels =================
// Per wave: 16-row x 64-col tile. A-frag: lane holds row (lane&15), k-slice (lane>>4).
// B-frag (weights): lane holds W[col=(lane&15)+16nt][k-slice]. C/D: col=lane&15,
// row=(lane>>4)*4+q (m89-verified). LDS tiles [16][64] bf16 with row-XOR swizzle.

// ---- loop body, dual-chain, 2 tiles/block: X = LN(mlp2(O + alpha*X))*ng + nb + X ----
__global__ __launch_bounds__(256) void loop_dual_kernel(
    const bf16* __restrict__ OA, bf16* __restrict__ XA,
    const bf16* __restrict__ OB, bf16* __restrict__ XB,
    const float* __restrict__ alA, const unsigned short* __restrict__ w1A, const float* __restrict__ b1A,
    const unsigned short* __restrict__ w2A, const float* __restrict__ b2A,
    const float* __restrict__ ngA, const float* __restrict__ nbA,
    const float* __restrict__ alB, const unsigned short* __restrict__ w1B, const float* __restrict__ b1B,
    const unsigned short* __restrict__ w2B, const float* __restrict__ b2B,
    const float* __restrict__ ngB, const float* __restrict__ nbB){
  __shared__ unsigned short Tl[4][2048];
  __shared__ unsigned short Xl[4][2048];
  __shared__ unsigned short Hl[4][1024];
  int bid = blockIdx.x;
  bool cb = bid >= NDB;
  int pb = cb ? bid - NDB : bid;
  const bf16* O = cb ? OB : OA;
  bf16* X = cb ? XB : XA;
  const float* alpha = cb ? alB : alA;
  const unsigned short* w1 = cb ? w1B : w1A;
  const float* b1 = cb ? b1B : b1A;
  const unsigned short* w2 = cb ? w2B : w2A;
  const float* b2 = cb ? b2B : b2A;
  const float* ng = cb ? ngB : ngA;
  const float* nb = cb ? nbB : nbA;
  int tid = threadIdx.x, lane = tid & 63, wid = tid >> 6;
  int lr = lane & 15, lg = lane >> 4;
  short8v w1f[4][2], w2f[4][2];
  const short8v* W1 = (const short8v*)w1;
  const short8v* W2 = (const short8v*)w2;
  #pragma unroll
  for (int nt = 0; nt < 4; nt++){
    int col = lr + 16*nt;
    #pragma unroll
    for (int ks = 0; ks < 2; ks++){
      w1f[nt][ks] = W1[col*8 + ks*4 + lg];
      w2f[nt][ks] = W2[col*8 + ks*4 + lg];
    }
  }
  float4 al = ((const float4*)alpha)[lr];
  float b1l[4], b2l[4], ngl[4], nbl[4];
  #pragma unroll
  for (int nt = 0; nt < 4; nt++){
    int c = lr + 16*nt;
    b1l[nt] = b1[c]; b2l[nt] = b2[c]; ngl[nt] = ng[c]; nbl[nt] = nb[c];
  }
  unsigned short* Tw = Tl[wid];
  unsigned short* Xw = Xl[wid];
  unsigned short* Hw = Hl[wid];
  floatx4 zz = {0.f, 0.f, 0.f, 0.f};
  int t0 = pb*2;
  // stage both tiles (16 loads in flight); X copied raw, T = O + alpha*X
  #pragma unroll
  for (int tt = 0; tt < 2; tt++){
    int row0 = (t0 + tt)*64 + wid*16;
    #pragma unroll
    for (int it = 0; it < 4; it++){
      int rl = it*4 + lg;
      size_t gi = (size_t)(row0 + rl)*64 + 4*lr;
      ushort4 xw = *(const ushort4*)(X + gi);
      float4 ov4 = ldf4(O, gi);
      int si = tt*1024 + swz(rl, 4*lr);
      float4 tv;
      tv.x = ov4.x + al.x*b2f(xw.x);
      tv.y = ov4.y + al.y*b2f(xw.y);
      tv.z = ov4.z + al.z*b2f(xw.z);
      tv.w = ov4.w + al.w*b2f(xw.w);
      *(ushort4*)&Tw[si] = packb(tv);
      *(ushort4*)&Xw[si] = xw;
    }
  }
  wsync();
  #pragma unroll
  for (int tt = 0; tt < 2; tt++){
    int row0 = (t0 + tt)*64 + wid*16;
    short8v a0 = *(const short8v*)&Tw[tt*1024 + swz(lr, lg*8)];
    short8v a1 = *(const short8v*)&Tw[tt*1024 + swz(lr, 32 + lg*8)];
    #pragma unroll
    for (int nt = 0; nt < 4; nt++){
      floatx4 acc = zz;
      acc = __builtin_amdgcn_mfma_f32_16x16x32_bf16(a0, w1f[nt][0], acc, 0, 0, 0);
      acc = __builtin_amdgcn_mfma_f32_16x16x32_bf16(a1, w1f[nt][1], acc, 0, 0, 0);
      #pragma unroll
      for (int q = 0; q < 4; q++)
        Hw[swz(lg*4 + q, lr + 16*nt)] = f2b(fmaxf(acc[q] + b1l[nt], 0.f));
    }
    wsync();
    short8v h0 = *(const short8v*)&Hw[swz(lr, lg*8)];
    short8v h1 = *(const short8v*)&Hw[swz(lr, 32 + lg*8)];
    float y[4][4];
    float s[4] = {0.f,0.f,0.f,0.f}, ss[4] = {0.f,0.f,0.f,0.f};
    #pragma unroll
    for (int nt = 0; nt < 4; nt++){
      floatx4 acc = zz;
      acc = __builtin_amdgcn_mfma_f32_16x16x32_bf16(h0, w2f[nt][0], acc, 0, 0, 0);
      acc = __builtin_amdgcn_mfma_f32_16x16x32_bf16(h1, w2f[nt][1], acc, 0, 0, 0);
      #pragma unroll
      for (int q = 0; q < 4; q++){
        float v = acc[q] + b2l[nt];
        y[nt][q] = v; s[q] += v; ss[q] += v*v;
      }
    }
    #pragma unroll
    for (int o = 1; o < 16; o <<= 1){
      #pragma unroll
      for (int q = 0; q < 4; q++){
        s[q] += __shfl_xor(s[q], o, 64);
        ss[q] += __shfl_xor(ss[q], o, 64);
      }
    }
    float mu[4], rs[4];
    #pragma unroll
    for (int q = 0; q < 4; q++){
      mu[q] = s[q]*(1.f/64.f);
      float var = fmaxf(ss[q]*(1.f/64.f) - mu[q]*mu[q], 0.f);
      rs[q] = rsqrtf(var + LN_EPS);
    }
    #pragma unroll
    for (int nt = 0; nt < 4; nt++){
      #pragma unroll
      for (int q = 0; q < 4; q++){
        int rl = lg*4 + q, c = lr + 16*nt;
        float xs = b2f(Xw[tt*1024 + swz(rl, c)]);
        float v = (y[nt][q] - mu[q])*rs[q]*ngl[nt] + nbl[nt] + xs;
        stf(X, (size_t)(row0 + rl)*64 + c, v);
      }
    }
    wsync();
  }
}

// ---- kvred + qproj fused dispatch: blocks [0,NKV) kvred; [NKV,NKV+NTILE) qproj ----
__global__ __launch_bounds__(256) void kvred_qproj_kernel(
    const bf16* __restrict__ Xqk, const bf16* __restrict__ Xv,
    const unsigned short* __restrict__ wb, const float* __restrict__ bias,
    float* __restrict__ partial, bf16* __restrict__ qn_out){
  __shared__ unsigned short T1[4][1024];   // Xqk stage (swz) then kn_t [64][16]
  __shared__ unsigned short T2[4][1024];   // Xv stage (swz)
  __shared__ float red[4*1536];
  int tid = threadIdx.x, lane = tid & 63, wid = tid >> 6;
  int lr = lane & 15, lg = lane >> 4;
  floatx4 zz = {0.f, 0.f, 0.f, 0.f};
  const short8v z8 = {0,0,0,0,0,0,0,0};
  const short8v* WQ = (const short8v*)(wb + WB_QK);

  if (blockIdx.x >= NKV){
    // ---- qproj: one 64-row tile of Xqk -> head-normalized q (bf16) ----
    int tile = blockIdx.x - NKV;
    unsigned short* Tw = T1[wid];
    short8v wqf[4][2];
    float bq[4];
    #pragma unroll
    for (int nt = 0; nt < 4; nt++){
      int col = lr + 16*nt;                  // q-half of fc_to_qk
      bq[nt] = bias[col];
      #pragma unroll
      for (int ks = 0; ks < 2; ks++) wqf[nt][ks] = WQ[col*8 + ks*4 + lg];
    }
    int row0 = tile*64 + wid*16;
    #pragma unroll
    for (int it = 0; it < 4; it++){
      int rl = it*4 + lg;
      size_t gi = (size_t)(row0 + rl)*64 + 4*lr;
      *(ushort4*)&Tw[swz(rl, 4*lr)] = *(const ushort4*)(Xqk + gi);
    }
    wsync();
    short8v a0 = *(const short8v*)&Tw[swz(lr, lg*8)];
    short8v a1 = *(const short8v*)&Tw[swz(lr, 32 + lg*8)];
    float qn[4][4];
    #pragma unroll
    for (int nt = 0; nt < 4; nt++){
      floatx4 acc = zz;
      acc = __builtin_amdgcn_mfma_f32_16x16x32_bf16(a0, wqf[nt][0], acc, 0, 0, 0);
      acc = __builtin_amdgcn_mfma_f32_16x16x32_bf16(a1, wqf[nt][1], acc, 0, 0, 0);
      #pragma unroll
      for (int q = 0; q < 4; q++) qn[nt][q] = acc[q] + bq[nt];
    }
    #pragma unroll
    for (int nt = 0; nt < 4; nt++){
      float n0 = qn[nt][0]*qn[nt][0], n1 = qn[nt][1]*qn[nt][1];
      float n2 = qn[nt][2]*qn[nt][2], n3 = qn[nt][3]*qn[nt][3];
      #pragma unroll
      for (int o = 1; o < 16; o <<= 1){
        n0 += __shfl_xor(n0, o, 64); n1 += __shfl_xor(n1, o, 64);
        n2 += __shfl_xor(n2, o, 64); n3 += __shfl_xor(n3, o, 64);
      }
      qn[nt][0] /= fmaxf(sqrtf(n0), 1e-12f);
      qn[nt][1] /= fmaxf(sqrtf(n1), 1e-12f);
      qn[nt][2] /= fmaxf(sqrtf(n2), 1e-12f);
      qn[nt][3] /= fmaxf(sqrtf(n3), 1e-12f);
    }
    #pragma unroll
    for (int nt = 0; nt < 4; nt++)
      #pragma unroll
      for (int q = 0; q < 4; q++)
        stf(qn_out, (size_t)(row0 + lg*4 + q)*64 + lr + 16*nt, qn[nt][q]);
    return;
  }

  // ---- kvred ----
  short8v wkf[4][2];
  float bk[4];
  #pragma unroll
  for (int nt = 0; nt < 4; nt++){
    int col = 64 + lr + 16*nt;               // k-half of fc_to_qk
    bk[nt] = bias[col];
    #pragma unroll
    for (int ks = 0; ks < 2; ks++) wkf[nt][ks] = WQ[col*8 + ks*4 + lg];
  }
  int b = blockIdx.x / NBB, blk = blockIdx.x % NBB;
  unsigned short* Tw = T1[wid];
  unsigned short* Vw = T2[wid];
  floatx4 kvacc[4] = {zz, zz, zz, zz};
  float ksp[4] = {0.f,0.f,0.f,0.f};
  float vsp[4] = {0.f,0.f,0.f,0.f};
  for (int st = blk*4 + wid; st < 1250; st += NBB*4){
    size_t gr = (size_t)b*VDIM + (size_t)st*16;
    #pragma unroll
    for (int it = 0; it < 4; it++){
      int rl = it*4 + lg;
      size_t gi = (gr + rl)*64 + 4*lr;
      ushort4 tq = *(const ushort4*)(Xqk + gi);
      ushort4 tv = *(const ushort4*)(Xv + gi);
      int si = swz(rl, 4*lr);
      *(ushort4*)&Tw[si] = tq;
      *(ushort4*)&Vw[si] = tv;
      vsp[0] += b2f(tv.x); vsp[1] += b2f(tv.y); vsp[2] += b2f(tv.z); vsp[3] += b2f(tv.w);
    }
    wsync();
    short8v a0 = *(const short8v*)&Tw[swz(lr, lg*8)];
    short8v a1 = *(const short8v*)&Tw[swz(lr, 32 + lg*8)];
    // k-projection + head norm -> kn (C-layout regs), store kn_t to T1
    float kn[4][4];
    #pragma unroll
    for (int nt = 0; nt < 4; nt++){
      floatx4 acc = zz;
      acc = __builtin_amdgcn_mfma_f32_16x16x32_bf16(a0, wkf[nt][0], acc, 0, 0, 0);
      acc = __builtin_amdgcn_mfma_f32_16x16x32_bf16(a1, wkf[nt][1], acc, 0, 0, 0);
      #pragma unroll
      for (int q = 0; q < 4; q++) kn[nt][q] = acc[q] + bk[nt];
    }
    #pragma unroll
    for (int nt = 0; nt < 4; nt++){
      float n0 = kn[nt][0]*kn[nt][0], n1 = kn[nt][1]*kn[nt][1];
      float n2 = kn[nt][2]*kn[nt][2], n3 = kn[nt][3]*kn[nt][3];
      #pragma unroll
      for (int o = 1; o < 16; o <<= 1){
        n0 += __shfl_xor(n0, o, 64); n1 += __shfl_xor(n1, o, 64);
        n2 += __shfl_xor(n2, o, 64); n3 += __shfl_xor(n3, o, 64);
      }
      kn[nt][0] /= fmaxf(sqrtf(n0), 1e-12f);
      kn[nt][1] /= fmaxf(sqrtf(n1), 1e-12f);
      kn[nt][2] /= fmaxf(sqrtf(n2), 1e-12f);
      kn[nt][3] /= fmaxf(sqrtf(n3), 1e-12f);
      ksp[nt] += kn[nt][0] + kn[nt][1] + kn[nt][2] + kn[nt][3];
    }
    wsync();   // a0/a1 consumed; safe to overwrite T1 with kn_t
    #pragma unroll
    for (int nt = 0; nt < 4; nt++){
      int c = lr + 16*nt;
      #pragma unroll
      for (int q = 0; q < 4; q++)
        Tw[c*16 + lg*4 + q] = f2b(kn[nt][q]);
    }
    wsync();
    // kv += kn^T (A) x vx (B), per head, K=16 rows zero-padded to 32
    #pragma unroll
    for (int nt = 0; nt < 4; nt++){
      short8v af = z8, bf = z8;
      if (lg < 2){
        af = *(const short8v*)&Tw[(nt*16 + lr)*16 + lg*8];
        #pragma unroll
        for (int j = 0; j < 8; j++)
          bf[j] = (short)Vw[swz(lg*8 + j, nt*16 + lr)];
      }
      kvacc[nt] = __builtin_amdgcn_mfma_f32_16x16x32_bf16(af, bf, kvacc[nt], 0, 0, 0);
    }
    wsync();   // LDS reads done before next stripe overwrites tiles
  }
  // write per-wave partials
  float* rw = red + wid*1536;
  #pragma unroll
  for (int nt = 0; nt < 4; nt++){
    #pragma unroll
    for (int q = 0; q < 4; q++)
      rw[(nt*16 + lg*4 + q)*16 + lr] = kvacc[nt][q];
    rw[1024 + lg*64 + lr + 16*nt] = ksp[nt];
  }
  #pragma unroll
  for (int m = 0; m < 4; m++)
    rw[1280 + lg*64 + 4*lr + m] = vsp[m];
  __syncthreads();
  float* P = partial + (size_t)blockIdx.x*1152;
  for (int j = tid; j < 1152; j += 256){
    float s = 0.f;
    if (j < 1024){
      #pragma unroll
      for (int wv = 0; wv < 4; wv++) s += red[wv*1536 + j];
    } else if (j < 1088){
      int c = j - 1024;
      #pragma unroll
      for (int wv = 0; wv < 4; wv++)
        #pragma unroll
        for (int gg = 0; gg < 4; gg++) s += red[wv*1536 + 1024 + gg*64 + c];
    } else {
      int c = j - 1088;
      #pragma unroll
      for (int wv = 0; wv < 4; wv++)
        #pragma unroll
        for (int gg = 0; gg < 4; gg++) s += red[wv*1536 + 1280 + gg*64 + c];
    }
    P[j] = s;
  }
}

// ---- reduce kvred partials; also emit bf16 copies for attn fragments ----
__global__ void qkred_kernel(const float* __restrict__ partial,
                             float* __restrict__ kvs, float* __restrict__ ksum, float* __restrict__ vsum,
                             unsigned short* __restrict__ kvsb, unsigned short* __restrict__ ksb){
  int b = blockIdx.x / 5, ch = blockIdx.x % 5;
  int j = ch*256 + threadIdx.x;
  if (j >= 1152) return;
  const float* P = partial + (size_t)b*NBB*1152;
  float s = 0.f;
  for (int t = 0; t < NBB; t++) s += P[(size_t)t*1152 + j];
  if (j < 1024){      kvs[b*1024 + j] = s; kvsb[b*1024 + j] = f2b(s); }
  else if (j < 1088){ ksum[b*64 + (j-1024)] = s; ksb[b*64 + (j-1024)] = f2b(s); }
  else                vsum[b*64 + (j-1088)] = s;
}

// ---- fused attention + final FFN, 2 tiles/block; qn precomputed (no q-proj) ----
__global__ __launch_bounds__(256) void attn_final_kernel(
    const float* __restrict__ x, const bf16* __restrict__ QN, const bf16* __restrict__ Xv,
    const unsigned short* __restrict__ kvsb, const unsigned short* __restrict__ ksb,
    const float* __restrict__ vsum,
    const unsigned short* __restrict__ wb,
    const float* __restrict__ ag, const float* __restrict__ ab,
    const float* __restrict__ fb1, const float* __restrict__ fb2,
    const float* __restrict__ g, const float* __restrict__ bb,
    float* __restrict__ out){
  __shared__ unsigned short Ql[4][2048];
  __shared__ unsigned short Hl[4][1024];
  int tid = threadIdx.x, lane = tid & 63, wid = tid >> 6;
  int lr = lane & 15, lg = lane >> 4;
  // FFN weights (bf16 direct)
  short8v f1f[4][2], f2f[4][2];
  float agl[4], abl[4], b1l[4], b2l[4], gl[4], bl[4];
  const short8v* W1 = (const short8v*)(wb + WB_FW1);
  const short8v* W2 = (const short8v*)(wb + WB_FW2);
  #pragma unroll
  for (int nt = 0; nt < 4; nt++){
    int col = lr + 16*nt;
    agl[nt] = ag[col]; abl[nt] = ab[col];
    b1l[nt] = fb1[col]; b2l[nt] = fb2[col]; gl[nt] = g[col]; bl[nt] = bb[col];
    #pragma unroll
    for (int ks = 0; ks < 2; ks++){
      f1f[nt][ks] = W1[col*8 + ks*4 + lg];
      f2f[nt][ks] = W2[col*8 + ks*4 + lg];
    }
  }
  unsigned short* Qw = Ql[wid];
  unsigned short* Hw = Hl[wid];
  floatx4 zz = {0.f, 0.f, 0.f, 0.f};
  const short8v z8 = {0,0,0,0,0,0,0,0};
  int t0 = blockIdx.x*2;
  // stage both qn tiles (already bf16)
  #pragma unroll
  for (int tt = 0; tt < 2; tt++){
    int row0 = (t0 + tt)*64 + wid*16;
    #pragma unroll
    for (int it = 0; it < 4; it++){
      int rl = it*4 + lg;
      size_t gi = (size_t)(row0 + rl)*64 + 4*lr;
      *(ushort4*)&Qw[tt*1024 + swz(rl, 4*lr)] = *(const ushort4*)(QN + gi);
    }
  }
  wsync();
  #pragma unroll
  for (int tt = 0; tt < 2; tt++){
    int row0 = (t0 + tt)*64 + wid*16;
    int b = row0 / VDIM;                     // wave-uniform (16 | 20000)
    // per-head attention: num/den via zero-padded 16x16x32 MFMAs; kv frags from global
    float y[4][4];
    float s[4] = {0.f,0.f,0.f,0.f}, ss[4] = {0.f,0.f,0.f,0.f};
    #pragma unroll
    for (int nt = 0; nt < 4; nt++){
      short8v af = z8, bn = z8, bd = z8;
      if (lg < 2){
        af = *(const short8v*)&Qw[tt*1024 + swz(lr, nt*16 + lg*8)];
        bd = *(const short8v*)&ksb[b*64 + nt*16 + lg*8];
        #pragma unroll
        for (int j = 0; j < 8; j++)
          bn[j] = (short)kvsb[b*1024 + (nt*16 + lg*8 + j)*16 + lr];
      }
      int c = lr + 16*nt;
      float vsb = vsum[b*64 + c];
      floatx4 numc, denc;
      #pragma unroll
      for (int q = 0; q < 4; q++){
        float vv = ldf(Xv, (size_t)(row0 + lg*4 + q)*64 + c);
        numc[q] = vsb + vv*(float)VDIM;
        denc[q] = 2.0f*(float)VDIM;
      }
      numc = __builtin_amdgcn_mfma_f32_16x16x32_bf16(af, bn, numc, 0, 0, 0);
      denc = __builtin_amdgcn_mfma_f32_16x16x32_bf16(af, bd, denc, 0, 0, 0);
      #pragma unroll
      for (int q = 0; q < 4; q++){
        float xv = x[(size_t)(row0 + lg*4 + q)*64 + c];
        float v = xv + numc[q]/denc[q];
        y[nt][q] = v; s[q] += v; ss[q] += v*v;
      }
    }
    #pragma unroll
    for (int o = 1; o < 16; o <<= 1){
      #pragma unroll
      for (int q = 0; q < 4; q++){
        s[q] += __shfl_xor(s[q], o, 64);
        ss[q] += __shfl_xor(ss[q], o, 64);
      }
    }
    #pragma unroll
    for (int q = 0; q < 4; q++){
      float mu = s[q]*(1.f/64.f);
      float var = fmaxf(ss[q]*(1.f/64.f) - mu*mu, 0.f);
      float rs = rsqrtf(var + LN_EPS);
      #pragma unroll
      for (int nt = 0; nt < 4; nt++)
        y[nt][q] = (y[nt][q] - mu)*rs*agl[nt] + abl[nt];
    }
    // FFN + LN2 (residual y in regs)
    wsync();   // per-head Qw reads done; overwrite tile-tt with xa
    #pragma unroll
    for (int nt = 0; nt < 4; nt++){
      #pragma unroll
      for (int q = 0; q < 4; q++)
        Qw[tt*1024 + swz(lg*4 + q, lr + 16*nt)] = f2b(y[nt][q]);
    }
    wsync();
    short8v xa0 = *(const short8v*)&Qw[tt*1024 + swz(lr, lg*8)];
    short8v xa1 = *(const short8v*)&Qw[tt*1024 + swz(lr, 32 + lg*8)];
    #pragma unroll
    for (int nt = 0; nt < 4; nt++){
      floatx4 acc = zz;
      acc = __builtin_amdgcn_mfma_f32_16x16x32_bf16(xa0, f1f[nt][0], acc, 0, 0, 0);
      acc = __builtin_amdgcn_mfma_f32_16x16x32_bf16(xa1, f1f[nt][1], acc, 0, 0, 0);
      #pragma unroll
      for (int q = 0; q < 4; q++)
        Hw[swz(lg*4 + q, lr + 16*nt)] = f2b(fmaxf(acc[q] + b1l[nt], 0.f));
    }
    wsync();
    short8v h0 = *(const short8v*)&Hw[swz(lr, lg*8)];
    short8v h1 = *(const short8v*)&Hw[swz(lr, 32 + lg*8)];
    float t[4][4];
    float s2[4] = {0.f,0.f,0.f,0.f}, ss2[4] = {0.f,0.f,0.f,0.f};
    #pragma unroll
    for (int nt = 0; nt < 4; nt++){
      floatx4 acc = zz;
      acc = __builtin_amdgcn_mfma_f32_16x16x32_bf16(h0, f2f[nt][0], acc, 0, 0, 0);
      acc = __builtin_amdgcn_mfma_f32_16x16x32_bf16(h1, f2f[nt][1], acc, 0, 0, 0);
      #pragma unroll
      for (int q = 0; q < 4; q++){
        float v = acc[q] + b2l[nt] + y[nt][q];
        t[nt][q] = v; s2[q] += v; ss2[q] += v*v;
      }
    }
    #pragma unroll
    for (int o = 1; o < 16; o <<= 1){
      #pragma unroll
      for (int q = 0; q < 4; q++){
        s2[q] += __shfl_xor(s2[q], o, 64);
        ss2[q] += __shfl_xor(ss2[q], o, 64);
      }
    }
    #pragma unroll
    for (int q = 0; q < 4; q++){
      float mu = s2[q]*(1.f/64.f);
      float var = fmaxf(ss2[q]*(1.f/64.f) - mu*mu, 0.f);
      float rs = rsqrtf(var + LN_EPS);
      #pragma unroll
      for (int nt = 0; nt < 4; nt++){
        int c = lr + 16*nt;
        out[(size_t)(row0 + lg*4 + q)*64 + c] = (t[nt][q] - mu)*rs*gl[nt] + bl[nt];
      }
    }
    wsync();   // Hw reused by next tile
  }
}

// ================= host side =================
static const int DICT_SIZES[42] = {
  5120000,256,256,80000,262144,4096,4160,64,4096,64,
  8192,64,4096,64,8192,128,8192,128,8192,128,
  128,128,128,524288,8192,8192,128,8192,128,128,
  128,128,4096,64,4096,64,64,64,64,64,
  4,600000};

static void run_pipeline(const float* const* N, const int* hi,
                         const int* ei_raw, const int* eflag,
                         int* cursor, int2* pk, const int* row_ptr,
                         float* qk_z, float* zr, float* kvs, float* part,
                         unsigned short* kvsb, unsigned short* wb, float* rsvb,
                         bf16* A, bf16* B, bf16* OA, bf16* OB, bool dual,
                         float* outp, hipStream_t stream){
  float* ksum = kvs + 4096;
  float* vsum = kvs + 4352;
  unsigned short* ksb = kvsb + 4096;

  // fused: scatter (needs scan done) + init_both (independent) in one dispatch
  scatter_init_kernel<<<NSC + NDB, 256, 0, stream>>>(ei_raw, eflag, cursor, pk,
      N[0], N[3], hi, wb, rsvb, N[6], N[7], N[9], N[11], N[13], A, B);

  if (dual){
    for (int i = 0; i < 2; i++){
      rspmm_dual<<<2*NRB4, 256, 0, stream>>>(row_ptr, pk, qk_z, zr + i*16384, A, B, OA, OB);
      loop_dual_kernel<<<2*NDB, 256, 0, stream>>>(OA, A, OB, B,
          N[20] + i*64, wb + WB_QKW1 + i*4096, N[17] + i*64, wb + WB_QKW2 + i*4096, N[19] + i*64, N[21] + i*64, N[22] + i*64,
          N[29] + i*64, wb + WB_VW1 + i*4096, N[26] + i*64, wb + WB_VW2 + i*4096, N[28] + i*64, N[30] + i*64, N[31] + i*64);
    }
  } else {
    for (int i = 0; i < 2; i++){
      rspmm_dual<<<NRB4, 256, 0, stream>>>(row_ptr, pk, qk_z, qk_z, A, A, OA, OA);
      loop_dual_kernel<<<NDB, 256, 0, stream>>>(OA, A, OA, A,
          N[20] + i*64, wb + WB_QKW1 + i*4096, N[17] + i*64, wb + WB_QKW2 + i*4096, N[19] + i*64, N[21] + i*64, N[22] + i*64,
          N[20] + i*64, wb + WB_QKW1 + i*4096, N[17] + i*64, wb + WB_QKW2 + i*4096, N[19] + i*64, N[21] + i*64, N[22] + i*64);
    }
    for (int i = 0; i < 2; i++){
      rspmm_dual<<<NRB4, 256, 0, stream>>>(row_ptr, pk, zr + i*16384, zr + i*16384, B, B, OA, OA);
      loop_dual_kernel<<<NDB, 256, 0, stream>>>(OA, B, OA, B,
          N[29] + i*64, wb + WB_VW1 + i*4096, N[26] + i*64, wb + WB_VW2 + i*4096, N[28] + i*64, N[30] + i*64, N[31] + i*64,
          N[29] + i*64, wb + WB_VW1 + i*4096, N[26] + i*64, wb + WB_VW2 + i*4096, N[28] + i*64, N[30] + i*64, N[31] + i*64);
    }
  }

  // kvred + q-projection (independent block ranges) in one dispatch; qn -> OA (free)
  kvred_qproj_kernel<<<NKV + NTILE, 256, 0, stream>>>(A, B, wb, N[15], part, OA);
  qkred_kernel<<<20, 256, 0, stream>>>(part, kvs, ksum, vsum, kvsb, ksb);
  attn_final_kernel<<<NDB, 256, 0, stream>>>(N[0], OA, B, kvsb, ksb, vsum,
      wb, N[36], N[37], N[33], N[35], N[38], N[39], outp);
}

extern "C" void kernel_launch(void* const* d_in, const int* in_sizes, int n_in,
                              void* d_out, int out_size, void* d_ws, size_t ws_size,
                              hipStream_t stream){
  float* outp = (float*)d_out;
  const int GOUT = (out_size + 255) / 256;

  if (n_in != 42){
    fill_kernel<<<GOUT, 256, 0, stream>>>(outp, 2000.0f + (float)n_in, out_size);
    return;
  }
  auto sz_ok = [&](int s, int e)->bool{
    if (s == e) return true;
    if ((e == 4 || e == 600000) && s == 2*e) return true;
    return false;
  };
  int bad = -1;
  for (int i = 0; i < 42 && bad < 0; i++)
    if (!sz_ok(in_sizes[i], DICT_SIZES[i])) bad = i;
  if (bad >= 0){
    fill_kernel<<<GOUT, 256, 0, stream>>>(outp, 1000.0f + (float)bad, out_size);
    return;
  }

  const float* N[40];
  for (int i = 0; i < 40; i++) N[i] = (const float*)d_in[i];
  const int* hi_raw = (const int*)d_in[40];
  const int* ei_raw = (const int*)d_in[41];

  char* p = (char*)d_ws;
  auto alloc = [&](size_t bytes)->char*{ char* r = p; p += (bytes + 255) / 256 * 256; return r; };
  int* hi      = (int*)alloc(256);
  int* eflag   = (int*)alloc(256);
  int* counts  = (int*)alloc((VDIM+1)*4);
  int* row_ptr = (int*)alloc((VDIM+1)*4);
  int* cursor  = (int*)alloc((VDIM+1)*4);
  int2* pk     = (int2*)alloc((size_t)EDIM*8);
  float* qk_z  = (float*)alloc(16384u*4);
  float* zr    = (float*)alloc(32768u*4);
  float* kvs   = (float*)alloc(4608u*4);
  unsigned short* kvsb = (unsigned short*)alloc(4352u*2);
  unsigned short* wb   = (unsigned short*)alloc((size_t)WB_TOT*2);
  float* rsvb  = (float*)alloc(64*4);
  float* part  = (float*)alloc((size_t)BDIM*NBB*1152*4);
  size_t fixed = (size_t)(p - (char*)d_ws);
  const size_t bufH = (size_t)BV*64*2;

  // setup: detect64 + zero counts + zcalc + weight bf16 conversion, one dispatch
  setup_kernel<<<273 + (WC_TOT+255)/256, 256, 0, stream>>>(ei_raw, eflag, counts,
      N[1], N[4], N[5], N[23], N[24], qk_z, zr,
      N[16], N[18], N[25], N[27], N[6], N[8], N[10], N[12], N[14], N[32], N[34],
      wb, rsvb);
  prep_count_kernel<<<(EDIM+255)/256, 256, 0, stream>>>(ei_raw, hi_raw, eflag, hi, counts);
  scan_kernel<<<1, 256, 0, stream>>>(counts, row_ptr, cursor);

  // bf16 workspace: halves intermediate traffic, makes rspmm X L2-resident.
  if (ws_size >= fixed + 4*bufH + 1024){
    bf16* A  = (bf16*)alloc(bufH);
    bf16* B  = (bf16*)alloc(bufH);
    bf16* OA = (bf16*)alloc(bufH);
    bf16* OB = (bf16*)alloc(bufH);
    run_pipeline(N, hi, ei_raw, eflag, cursor, pk, row_ptr,
                 qk_z, zr, kvs, part, kvsb, wb, rsvb, A, B, OA, OB, true, outp, stream);
  } else {
    bf16* A  = (bf16*)alloc(bufH);
    bf16* B  = (bf16*)alloc(bufH);
    bf16* OA = (bf16*)alloc(bufH);
    run_pipeline(N, hi, ei_raw, eflag, cursor, pk, row_ptr,
                 qk_z, zr, kvs, part, kvsb, wb, rsvb, A, B, OA, OA, false, outp, stream);
  }
}

// Round 17
// 437.542 us; speedup vs baseline: 1.2219x; 1.0149x over previous
//
#include <hip/hip_runtime.h>
#include <hip/hip_bf16.h>

#define BDIM 4
#define VDIM 20000
#define DDIM 64
#define RDIM 64
#define EDIM 200000
#define BV (BDIM*VDIM)
#define LN_EPS 1e-5f
#define NBB 125           // kvred blocks per batch
#define NTILE 1250        // BV/64 row-tiles
#define NDB 625           // dense blocks per chain (2 tiles each)
#define NRB2 (VDIM/2)     // rspmm blocks per chain (2 vertices each)
#define NSC ((EDIM+255)/256)  // scatter blocks (782)
#define NKV (BDIM*NBB)    // kvred blocks (500)

// bf16 weight buffer element offsets (all multiples of 8)
#define WB_QKW1 0         // [2][64][64]
#define WB_QKW2 8192
#define WB_VW1  16384
#define WB_VW2  24576
#define WB_IQW1 32768     // [64][64] (noise col dropped)
#define WB_IQW2 36928     // [64][64]  (36864..36928 unused pad)
#define WB_IVW1 41024     // [64][128]
#define WB_IVW2 49216
#define WB_QK   53312     // [128][64]
#define WB_FW1  61504
#define WB_FW2  65600
#define WB_TOT  69696
#define WC_TOT  69760     // + 64 rsv sums

typedef __hip_bfloat16 bf16;
typedef __attribute__((ext_vector_type(8))) short short8v;
typedef __attribute__((ext_vector_type(4))) float floatx4;

__device__ __forceinline__ float ldf(const float* p, size_t i){ return p[i]; }
__device__ __forceinline__ float ldf(const bf16* p, size_t i){ return __bfloat162float(p[i]); }
__device__ __forceinline__ void stf(float* p, size_t i, float v){ p[i] = v; }
__device__ __forceinline__ void stf(bf16* p, size_t i, float v){ p[i] = __float2bfloat16(v); }

__device__ __forceinline__ unsigned short f2b(float f){
  unsigned u = __builtin_bit_cast(unsigned, f);
  u += 0x7fffu + ((u >> 16) & 1u);
  return (unsigned short)(u >> 16);
}
__device__ __forceinline__ float b2f(unsigned short h){
  unsigned u = ((unsigned)h) << 16;
  return __builtin_bit_cast(float, u);
}
__device__ __forceinline__ float4 ldf4(const float* p, size_t i){ return *(const float4*)(p+i); }
__device__ __forceinline__ float4 ldf4(const bf16* p, size_t i){
  ushort4 u = *(const ushort4*)(p+i);
  return make_float4(b2f(u.x), b2f(u.y), b2f(u.z), b2f(u.w));
}
// LDS tile swizzle: element index for [16][64] bf16 tile, 16B-unit XOR on row
__device__ __forceinline__ int swz(int r, int c){ return r*64 + (c ^ ((r & 7) << 3)); }

__device__ __forceinline__ float dot4(float4 a, float4 b){
  return a.x*b.x + a.y*b.y + a.z*b.z + a.w*b.w;
}

// Wave-private LDS ordering: DS ops from one wave execute in order; just fence compiler.
__device__ __forceinline__ void wsync(){
  __builtin_amdgcn_wave_barrier();
  __asm__ volatile("" ::: "memory");
}

__device__ __forceinline__ ushort4 packb(float4 v){
  ushort4 t; t.x = f2b(v.x); t.y = f2b(v.y); t.z = f2b(v.z); t.w = f2b(v.w); return t;
}

// ---- diagnostic fill ----
__global__ void fill_kernel(float* __restrict__ out, float v, int n){
  int t = blockIdx.x * 256 + threadIdx.x;
  if (t < n) out[t] = v;
}

// ---- setup: blocks 0..79 zero counts, 80..271 zcalc, 272 detect, 273.. weight conv ----
__global__ void setup_kernel(const int* __restrict__ ei_raw, int* __restrict__ flag,
                             int* __restrict__ counts,
                             const float* __restrict__ z,
                             const float* __restrict__ qkzw, const float* __restrict__ qkzb,
                             const float* __restrict__ vfw,  const float* __restrict__ vfb,
                             float* __restrict__ qk_z, float* __restrict__ zr,
                             const float* __restrict__ qkw1, const float* __restrict__ qkw2,
                             const float* __restrict__ vw1l, const float* __restrict__ vw2l,
                             const float* __restrict__ iqw1, const float* __restrict__ iqw2,
                             const float* __restrict__ ivw1, const float* __restrict__ ivw2,
                             const float* __restrict__ qkpw, const float* __restrict__ fw1,
                             const float* __restrict__ fw2,
                             unsigned short* __restrict__ wb, float* __restrict__ rsvb){
  int bid = blockIdx.x, tid = threadIdx.x;
  if (bid >= 273){
    int e = (bid - 273)*256 + tid;
    if (e >= WC_TOT) return;
    if (e >= WB_TOT){
      int col = e - WB_TOT;
      const float4* r4 = (const float4*)(ivw1 + col*128 + 64);
      float rsv = 0.f;
      #pragma unroll
      for (int i = 0; i < 16; i++){ float4 t = r4[i]; rsv += t.x + t.y + t.z + t.w; }
      rsvb[col] = rsv;
      return;
    }
    float v;
    if (e < WB_QKW2)        v = qkw1[e];
    else if (e < WB_VW1)    v = qkw2[e - WB_QKW2];
    else if (e < WB_VW2)    v = vw1l[e - WB_VW1];
    else if (e < WB_IQW1)   v = vw2l[e - WB_VW2];
    else if (e < 36864){ int j = e - WB_IQW1; v = iqw1[(j>>6)*65 + (j&63)]; }
    else if (e < WB_IQW2)   v = 0.f;                      // pad
    else if (e < WB_IVW1)   v = iqw2[e - WB_IQW2];
    else if (e < WB_IVW2)   v = ivw1[e - WB_IVW1];
    else if (e < WB_QK)     v = ivw2[e - WB_IVW2];
    else if (e < WB_FW1)    v = qkpw[e - WB_QK];
    else if (e < WB_FW2)    v = fw1[e - WB_FW1];
    else                    v = fw2[e - WB_FW2];
    wb[e] = f2b(v);
    return;
  }
  if (bid == 272){
    int nz = 0;
    for (int j = 2*tid + 1; j < 1024; j += 512) nz |= (ei_raw[j] != 0);
    nz = __any(nz);
    __shared__ int r[4];
    if ((tid & 63) == 0) r[tid >> 6] = nz;
    __syncthreads();
    if (tid == 0) flag[0] = (r[0] | r[1] | r[2] | r[3]) ? 0 : 1;   // 1 => 64-bit
    return;
  }
  if (bid < 80){
    int i = bid*256 + tid;
    if (i < VDIM + 1) counts[i] = 0;
    return;
  }
  int idx = (bid - 80)*256 + tid;
  if (idx >= 49152) return;
  int which = idx >> 14;
  int r = idx & 16383;
  int b = r >> 12;
  int j = r & 4095;
  const float* wrow; float bias; float* outp;
  if (which == 0){ wrow = qkzw + (size_t)j*DDIM; bias = qkzb[j]; outp = qk_z; }
  else { int i = which - 1; wrow = vfw + (size_t)(i*4096 + j)*DDIM; bias = vfb[i*4096 + j]; outp = zr + i*16384; }
  const float4* zr4 = (const float4*)(z + (size_t)b*DDIM);
  const float4* wr4 = (const float4*)wrow;
  float acc = bias;
  #pragma unroll
  for (int i = 0; i < 16; i++) acc += dot4(zr4[i], wr4[i]);
  outp[r] = acc;
}

// ---- count directly from raw edges (is64-aware) + hi normalize ----
__global__ void prep_count_kernel(const int* __restrict__ ei_raw, const int* __restrict__ hi_raw,
                                  const int* __restrict__ flag,
                                  int* __restrict__ hi, int* __restrict__ counts){
  int is64 = flag[0];
  int e = blockIdx.x * 256 + threadIdx.x;
  if (e < EDIM){
    int dst = is64 ? ei_raw[6*e]   : ei_raw[3*e];
    int rel = is64 ? ei_raw[6*e+2] : ei_raw[3*e+1];
    int src = is64 ? ei_raw[6*e+4] : ei_raw[3*e+2];
    if ((unsigned)dst < VDIM && (unsigned)rel < RDIM && (unsigned)src < VDIM)
      atomicAdd(&counts[dst], 1);
  }
  if (e < BDIM) hi[e] = is64 ? hi_raw[2*e] : hi_raw[e];
}

// ---- scan: per-thread segments + one wave scan, 1 barrier total ----
__global__ void scan_kernel(const int* __restrict__ counts, int* __restrict__ row_ptr, int* __restrict__ cursor){
  __shared__ int wsum[4];
  int tid = threadIdx.x, lane = tid & 63, wid = tid >> 6;
  const int SEG = (VDIM + 255) / 256;        // 79
  int lo = tid * SEG;
  int hi = lo + SEG; if (hi > VDIM) hi = VDIM;
  int s = 0;
  for (int i = lo; i < hi; i++) s += counts[i];
  int x = s;
  #pragma unroll
  for (int o = 1; o < 64; o <<= 1){
    int t = __shfl_up(x, o, 64);
    if (lane >= o) x += t;
  }
  if (lane == 63) wsum[wid] = x;
  __syncthreads();
  int wo = 0;
  for (int w = 0; w < wid; w++) wo += wsum[w];
  int run = wo + x - s;                      // exclusive prefix of this thread's segment
  for (int i = lo; i < hi; i++){
    row_ptr[i] = run; cursor[i] = run; run += counts[i];
  }
  if (tid == 255) row_ptr[VDIM] = run;       // total
}

// ---- fused scatter + init_both: blocks [0,NSC) scatter, [NSC,NSC+NDB) init ----
__global__ __launch_bounds__(256) void scatter_init_kernel(
    const int* __restrict__ ei_raw, const int* __restrict__ flag,
    int* __restrict__ cursor, int2* __restrict__ pk,
    const float* __restrict__ x, const float* __restrict__ noise, const int* __restrict__ h_index,
    const unsigned short* __restrict__ wb, const float* __restrict__ rsvb,
    const float* __restrict__ iqw1f, const float* __restrict__ qb1, const float* __restrict__ qb2,
    const float* __restrict__ vb1, const float* __restrict__ vb2,
    bf16* __restrict__ A, bf16* __restrict__ B){
  if (blockIdx.x < NSC){
    int is64 = flag[0];
    int e = blockIdx.x * 256 + threadIdx.x;
    if (e < EDIM){
      int dst = is64 ? ei_raw[6*e]   : ei_raw[3*e];
      int rel = is64 ? ei_raw[6*e+2] : ei_raw[3*e+1];
      int src = is64 ? ei_raw[6*e+4] : ei_raw[3*e+2];
      if ((unsigned)dst < VDIM && (unsigned)rel < RDIM && (unsigned)src < VDIM){
        int p = atomicAdd(&cursor[dst], 1);
        pk[p] = make_int2(rel, src);
      }
    }
    return;
  }
  __shared__ unsigned short Tl[4][2048];
  __shared__ unsigned short Hl[4][1024];
  __shared__ float Nl[4][32];
  int tid = threadIdx.x, lane = tid & 63, wid = tid >> 6;
  int lr = lane & 15, lg = lane >> 4;
  unsigned short* Tw = Tl[wid];
  unsigned short* Hw = Hl[wid];
  floatx4 zz = {0.f, 0.f, 0.f, 0.f};
  int t0 = (blockIdx.x - NSC)*2;
  // stage both x tiles + noise
  #pragma unroll
  for (int tt = 0; tt < 2; tt++){
    int row0 = (t0 + tt)*64 + wid*16;
    #pragma unroll
    for (int it = 0; it < 4; it++){
      int rl = it*4 + lg;
      size_t gi = (size_t)(row0 + rl)*64 + 4*lr;
      float4 x4 = ldf4(x, gi);
      *(ushort4*)&Tw[tt*1024 + swz(rl, 4*lr)] = packb(x4);
      if (lr == 0) Nl[wid][tt*16 + rl] = noise[row0 + rl];
    }
  }
  wsync();
  short8v a0[2], a1[2];
  #pragma unroll
  for (int tt = 0; tt < 2; tt++){
    a0[tt] = *(const short8v*)&Tw[tt*1024 + swz(lr, lg*8)];
    a1[tt] = *(const short8v*)&Tw[tt*1024 + swz(lr, 32 + lg*8)];
  }
  // ---- qk branch (both tiles) ----
  {
    short8v w1f[4][2], w2f[4][2];
    float wnl[4], b1l[4], b2l[4];
    const short8v* W1 = (const short8v*)(wb + WB_IQW1);
    const short8v* W2 = (const short8v*)(wb + WB_IQW2);
    #pragma unroll
    for (int nt = 0; nt < 4; nt++){
      int col = lr + 16*nt;
      wnl[nt] = iqw1f[col*65 + 64];
      b1l[nt] = qb1[col]; b2l[nt] = qb2[col];
      #pragma unroll
      for (int ks = 0; ks < 2; ks++){
        w1f[nt][ks] = W1[col*8 + ks*4 + lg];
        w2f[nt][ks] = W2[col*8 + ks*4 + lg];
      }
    }
    #pragma unroll
    for (int tt = 0; tt < 2; tt++){
      int row0 = (t0 + tt)*64 + wid*16;
      float nzq[4];
      #pragma unroll
      for (int q = 0; q < 4; q++) nzq[q] = Nl[wid][tt*16 + lg*4 + q];
      #pragma unroll
      for (int nt = 0; nt < 4; nt++){
        floatx4 acc = zz;
        acc = __builtin_amdgcn_mfma_f32_16x16x32_bf16(a0[tt], w1f[nt][0], acc, 0, 0, 0);
        acc = __builtin_amdgcn_mfma_f32_16x16x32_bf16(a1[tt], w1f[nt][1], acc, 0, 0, 0);
        #pragma unroll
        for (int q = 0; q < 4; q++)
          Hw[swz(lg*4 + q, lr + 16*nt)] = f2b(fmaxf(acc[q] + b1l[nt] + wnl[nt]*nzq[q], 0.f));
      }
      wsync();
      short8v h0 = *(const short8v*)&Hw[swz(lr, lg*8)];
      short8v h1 = *(const short8v*)&Hw[swz(lr, 32 + lg*8)];
      #pragma unroll
      for (int nt = 0; nt < 4; nt++){
        floatx4 acc = zz;
        acc = __builtin_amdgcn_mfma_f32_16x16x32_bf16(h0, w2f[nt][0], acc, 0, 0, 0);
        acc = __builtin_amdgcn_mfma_f32_16x16x32_bf16(h1, w2f[nt][1], acc, 0, 0, 0);
        #pragma unroll
        for (int q = 0; q < 4; q++){
          int rl = lg*4 + q, c = lr + 16*nt;
          stf(A, (size_t)(row0 + rl)*64 + c, acc[q] + b2l[nt]);
        }
      }
      wsync();
    }
  }
  // ---- v branch (both tiles) ----
  {
    short8v w1f[4][2], w2f[4][2];
    float rsvl[4], b1l[4], b2l[4];
    const short8v* W1 = (const short8v*)(wb + WB_IVW1);   // row stride 128 -> 16 vec
    const short8v* W2 = (const short8v*)(wb + WB_IVW2);
    #pragma unroll
    for (int nt = 0; nt < 4; nt++){
      int col = lr + 16*nt;
      b1l[nt] = vb1[col]; b2l[nt] = vb2[col];
      rsvl[nt] = rsvb[col];
      #pragma unroll
      for (int ks = 0; ks < 2; ks++){
        w1f[nt][ks] = W1[col*16 + ks*4 + lg];
        w2f[nt][ks] = W2[col*8 + ks*4 + lg];
      }
    }
    #pragma unroll
    for (int tt = 0; tt < 2; tt++){
      int row0 = (t0 + tt)*64 + wid*16;
      int b = row0 / VDIM;
      int vb = row0 - b*VDIM;
      int hv = h_index[b];
      bool cq[4];
      #pragma unroll
      for (int q = 0; q < 4; q++) cq[q] = (vb + lg*4 + q) == hv;
      #pragma unroll
      for (int nt = 0; nt < 4; nt++){
        floatx4 acc = zz;
        acc = __builtin_amdgcn_mfma_f32_16x16x32_bf16(a0[tt], w1f[nt][0], acc, 0, 0, 0);
        acc = __builtin_amdgcn_mfma_f32_16x16x32_bf16(a1[tt], w1f[nt][1], acc, 0, 0, 0);
        #pragma unroll
        for (int q = 0; q < 4; q++)
          Hw[swz(lg*4 + q, lr + 16*nt)] = f2b(fmaxf(acc[q] + b1l[nt] + (cq[q] ? rsvl[nt] : 0.f), 0.f));
      }
      wsync();
      short8v h0 = *(const short8v*)&Hw[swz(lr, lg*8)];
      short8v h1 = *(const short8v*)&Hw[swz(lr, 32 + lg*8)];
      #pragma unroll
      for (int nt = 0; nt < 4; nt++){
        floatx4 acc = zz;
        acc = __builtin_amdgcn_mfma_f32_16x16x32_bf16(h0, w2f[nt][0], acc, 0, 0, 0);
        acc = __builtin_amdgcn_mfma_f32_16x16x32_bf16(h1, w2f[nt][1], acc, 0, 0, 0);
        #pragma unroll
        for (int q = 0; q < 4; q++){
          int rl = lg*4 + q, c = lr + 16*nt;
          stf(B, (size_t)(row0 + rl)*64 + c, acc[q] + b2l[nt]);
        }
      }
      wsync();
    }
  }
}

// ---- rspmm gather, dual-chain: blocks [0,NRB2) = chain A, [NRB2,2NRB2) = chain B ----
// 2 vertices/block (shorter serial chain, more blocks); per-vertex edge accumulation
// order identical to prior version (8-group, 4-group, scalar tail) => bit-identical.
__global__ __launch_bounds__(256) void rspmm_dual(
    const int* __restrict__ row_ptr, const int2* __restrict__ pk,
    const float* __restrict__ zA, const float* __restrict__ zB,
    const bf16* __restrict__ XA, const bf16* __restrict__ XB,
    bf16* __restrict__ outA, bf16* __restrict__ outB){
  int bid = blockIdx.x;
  bool cb = bid >= NRB2;
  int v0 = (cb ? bid - NRB2 : bid) * 2;
  const float* zrel = cb ? zB : zA;
  const bf16* X = cb ? XB : XA;
  bf16* out = cb ? outB : outA;
  int btch = threadIdx.x >> 6, d = threadIdx.x & 63;
  int rp[3];
  #pragma unroll
  for (int i = 0; i < 3; i++) rp[i] = row_ptr[v0 + i];
  const float* zb = zrel + btch*RDIM*DDIM + d;
  size_t xb = (size_t)btch*VDIM*64 + d;
  size_t ob = ((size_t)btch*VDIM + v0)*64 + d;
  #pragma unroll 1
  for (int vi = 0; vi < 2; vi++){
    int s = rp[vi], e = rp[vi+1];
    float a0 = 0.f, a1 = 0.f, a2 = 0.f, a3 = 0.f;
    int i = s;
    for (; i + 8 <= e; i += 8){
      int2 e0 = pk[i],   e1 = pk[i+1], e2 = pk[i+2], e3 = pk[i+3];
      int2 e4 = pk[i+4], e5 = pk[i+5], e6 = pk[i+6], e7 = pk[i+7];
      float x0 = ldf(X, xb + (size_t)e0.y*64);
      float x1 = ldf(X, xb + (size_t)e1.y*64);
      float x2 = ldf(X, xb + (size_t)e2.y*64);
      float x3 = ldf(X, xb + (size_t)e3.y*64);
      float x4 = ldf(X, xb + (size_t)e4.y*64);
      float x5 = ldf(X, xb + (size_t)e5.y*64);
      float x6 = ldf(X, xb + (size_t)e6.y*64);
      float x7 = ldf(X, xb + (size_t)e7.y*64);
      float z0 = zb[(size_t)e0.x*64], z1 = zb[(size_t)e1.x*64];
      float z2 = zb[(size_t)e2.x*64], z3 = zb[(size_t)e3.x*64];
      float z4 = zb[(size_t)e4.x*64], z5 = zb[(size_t)e5.x*64];
      float z6 = zb[(size_t)e6.x*64], z7 = zb[(size_t)e7.x*64];
      a0 += z0*x0; a1 += z1*x1; a2 += z2*x2; a3 += z3*x3;
      a0 += z4*x4; a1 += z5*x5; a2 += z6*x6; a3 += z7*x7;
    }
    for (; i + 4 <= e; i += 4){
      int2 e0 = pk[i], e1 = pk[i+1], e2 = pk[i+2], e3 = pk[i+3];
      float x0 = ldf(X, xb + (size_t)e0.y*64);
      float x1 = ldf(X, xb + (size_t)e1.y*64);
      float x2 = ldf(X, xb + (size_t)e2.y*64);
      float x3 = ldf(X, xb + (size_t)e3.y*64);
      a0 += zb[(size_t)e0.x*64] * x0;
      a1 += zb[(size_t)e1.x*64] * x1;
      a2 += zb[(size_t)e2.x*64] * x2;
      a3 += zb[(size_t)e3.x*64] * x3;
    }
    for (; i < e; i++){
      int2 ed = pk[i];
      a0 += zb[(size_t)ed.x*64] * ldf(X, xb + (size_t)ed.y*64);
    }
    stf(out, ob + (size_t)vi*64, a0 + a1 + a2 + a3);
  }
}

// ================= MFMA dense kernels =================
// Per wave: 16-row x 64-col tile. A-frag: lane holds row (lane&15), k-slice (lane>>4).
// B-frag (weights): lane holds W[col=(lane&15)+16nt][k-slice]. C/D: col=lane&15,
// row=(lane>>4)*4+q (m89-verified). LDS tiles [16][64] bf16 with row-XOR swizzle.

// ---- loop body, dual-chain, 2 tiles/block: X = LN(mlp2(O + alpha*X))*ng + nb + X ----
__global__ __launch_bounds__(256) void loop_dual_kernel(
    const bf16* __restrict__ OA, bf16* __restrict__ XA,
    const bf16* __restrict__ OB, bf16* __restrict__ XB,
    const float* __restrict__ alA, const unsigned short* __restrict__ w1A, const float* __restrict__ b1A,
    const unsigned short* __restrict__ w2A, const float* __restrict__ b2A,
    const float* __restrict__ ngA, const float* __restrict__ nbA,
    const float* __restrict__ alB, const unsigned short* __restrict__ w1B, const float* __restrict__ b1B,
    const unsigned short* __restrict__ w2B, const float* __restrict__ b2B,
    const float* __restrict__ ngB, const float* __restrict__ nbB){
  __shared__ unsigned short Tl[4][2048];
  __shared__ unsigned short Xl[4][2048];
  __shared__ unsigned short Hl[4][1024];
  int bid = blockIdx.x;
  bool cb = bid >= NDB;
  int pb = cb ? bid - NDB : bid;
  const bf16* O = cb ? OB : OA;
  bf16* X = cb ? XB : XA;
  const float* alpha = cb ? alB : alA;
  const unsigned short* w1 = cb ? w1B : w1A;
  const float* b1 = cb ? b1B : b1A;
  const unsigned short* w2 = cb ? w2B : w2A;
  const float* b2 = cb ? b2B : b2A;
  const float* ng = cb ? ngB : ngA;
  const float* nb = cb ? nbB : nbA;
  int tid = threadIdx.x, lane = tid & 63, wid = tid >> 6;
  int lr = lane & 15, lg = lane >> 4;
  short8v w1f[4][2], w2f[4][2];
  const short8v* W1 = (const short8v*)w1;
  const short8v* W2 = (const short8v*)w2;
  #pragma unroll
  for (int nt = 0; nt < 4; nt++){
    int col = lr + 16*nt;
    #pragma unroll
    for (int ks = 0; ks < 2; ks++){
      w1f[nt][ks] = W1[col*8 + ks*4 + lg];
      w2f[nt][ks] = W2[col*8 + ks*4 + lg];
    }
  }
  float4 al = ((const float4*)alpha)[lr];
  float b1l[4], b2l[4], ngl[4], nbl[4];
  #pragma unroll
  for (int nt = 0; nt < 4; nt++){
    int c = lr + 16*nt;
    b1l[nt] = b1[c]; b2l[nt] = b2[c]; ngl[nt] = ng[c]; nbl[nt] = nb[c];
  }
  unsigned short* Tw = Tl[wid];
  unsigned short* Xw = Xl[wid];
  unsigned short* Hw = Hl[wid];
  floatx4 zz = {0.f, 0.f, 0.f, 0.f};
  int t0 = pb*2;
  // stage both tiles (16 loads in flight); X copied raw, T = O + alpha*X
  #pragma unroll
  for (int tt = 0; tt < 2; tt++){
    int row0 = (t0 + tt)*64 + wid*16;
    #pragma unroll
    for (int it = 0; it < 4; it++){
      int rl = it*4 + lg;
      size_t gi = (size_t)(row0 + rl)*64 + 4*lr;
      ushort4 xw = *(const ushort4*)(X + gi);
      float4 ov4 = ldf4(O, gi);
      int si = tt*1024 + swz(rl, 4*lr);
      float4 tv;
      tv.x = ov4.x + al.x*b2f(xw.x);
      tv.y = ov4.y + al.y*b2f(xw.y);
      tv.z = ov4.z + al.z*b2f(xw.z);
      tv.w = ov4.w + al.w*b2f(xw.w);
      *(ushort4*)&Tw[si] = packb(tv);
      *(ushort4*)&Xw[si] = xw;
    }
  }
  wsync();
  #pragma unroll
  for (int tt = 0; tt < 2; tt++){
    int row0 = (t0 + tt)*64 + wid*16;
    short8v a0 = *(const short8v*)&Tw[tt*1024 + swz(lr, lg*8)];
    short8v a1 = *(const short8v*)&Tw[tt*1024 + swz(lr, 32 + lg*8)];
    #pragma unroll
    for (int nt = 0; nt < 4; nt++){
      floatx4 acc = zz;
      acc = __builtin_amdgcn_mfma_f32_16x16x32_bf16(a0, w1f[nt][0], acc, 0, 0, 0);
      acc = __builtin_amdgcn_mfma_f32_16x16x32_bf16(a1, w1f[nt][1], acc, 0, 0, 0);
      #pragma unroll
      for (int q = 0; q < 4; q++)
        Hw[swz(lg*4 + q, lr + 16*nt)] = f2b(fmaxf(acc[q] + b1l[nt], 0.f));
    }
    wsync();
    short8v h0 = *(const short8v*)&Hw[swz(lr, lg*8)];
    short8v h1 = *(const short8v*)&Hw[swz(lr, 32 + lg*8)];
    float y[4][4];
    float s[4] = {0.f,0.f,0.f,0.f}, ss[4] = {0.f,0.f,0.f,0.f};
    #pragma unroll
    for (int nt = 0; nt < 4; nt++){
      floatx4 acc = zz;
      acc = __builtin_amdgcn_mfma_f32_16x16x32_bf16(h0, w2f[nt][0], acc, 0, 0, 0);
      acc = __builtin_amdgcn_mfma_f32_16x16x32_bf16(h1, w2f[nt][1], acc, 0, 0, 0);
      #pragma unroll
      for (int q = 0; q < 4; q++){
        float v = acc[q] + b2l[nt];
        y[nt][q] = v; s[q] += v; ss[q] += v*v;
      }
    }
    #pragma unroll
    for (int o = 1; o < 16; o <<= 1){
      #pragma unroll
      for (int q = 0; q < 4; q++){
        s[q] += __shfl_xor(s[q], o, 64);
        ss[q] += __shfl_xor(ss[q], o, 64);
      }
    }
    float mu[4], rs[4];
    #pragma unroll
    for (int q = 0; q < 4; q++){
      mu[q] = s[q]*(1.f/64.f);
      float var = fmaxf(ss[q]*(1.f/64.f) - mu[q]*mu[q], 0.f);
      rs[q] = rsqrtf(var + LN_EPS);
    }
    #pragma unroll
    for (int nt = 0; nt < 4; nt++){
      #pragma unroll
      for (int q = 0; q < 4; q++){
        int rl = lg*4 + q, c = lr + 16*nt;
        float xs = b2f(Xw[tt*1024 + swz(rl, c)]);
        float v = (y[nt][q] - mu[q])*rs[q]*ngl[nt] + nbl[nt] + xs;
        stf(X, (size_t)(row0 + rl)*64 + c, v);
      }
    }
    wsync();
  }
}

// ---- kvred + qproj fused dispatch: blocks [0,NKV) kvred; [NKV,NKV+NTILE) qproj ----
__global__ __launch_bounds__(256) void kvred_qproj_kernel(
    const bf16* __restrict__ Xqk, const bf16* __restrict__ Xv,
    const unsigned short* __restrict__ wb, const float* __restrict__ bias,
    float* __restrict__ partial, bf16* __restrict__ qn_out){
  __shared__ unsigned short T1[4][1024];   // Xqk stage (swz) then kn_t [64][16]
  __shared__ unsigned short T2[4][1024];   // Xv stage (swz)
  __shared__ float red[4*1536];
  int tid = threadIdx.x, lane = tid & 63, wid = tid >> 6;
  int lr = lane & 15, lg = lane >> 4;
  floatx4 zz = {0.f, 0.f, 0.f, 0.f};
  const short8v z8 = {0,0,0,0,0,0,0,0};
  const short8v* WQ = (const short8v*)(wb + WB_QK);

  if (blockIdx.x >= NKV){
    // ---- qproj: one 64-row tile of Xqk -> head-normalized q (bf16) ----
    int tile = blockIdx.x - NKV;
    unsigned short* Tw = T1[wid];
    short8v wqf[4][2];
    float bq[4];
    #pragma unroll
    for (int nt = 0; nt < 4; nt++){
      int col = lr + 16*nt;                  // q-half of fc_to_qk
      bq[nt] = bias[col];
      #pragma unroll
      for (int ks = 0; ks < 2; ks++) wqf[nt][ks] = WQ[col*8 + ks*4 + lg];
    }
    int row0 = tile*64 + wid*16;
    #pragma unroll
    for (int it = 0; it < 4; it++){
      int rl = it*4 + lg;
      size_t gi = (size_t)(row0 + rl)*64 + 4*lr;
      *(ushort4*)&Tw[swz(rl, 4*lr)] = *(const ushort4*)(Xqk + gi);
    }
    wsync();
    short8v a0 = *(const short8v*)&Tw[swz(lr, lg*8)];
    short8v a1 = *(const short8v*)&Tw[swz(lr, 32 + lg*8)];
    float qn[4][4];
    #pragma unroll
    for (int nt = 0; nt < 4; nt++){
      floatx4 acc = zz;
      acc = __builtin_amdgcn_mfma_f32_16x16x32_bf16(a0, wqf[nt][0], acc, 0, 0, 0);
      acc = __builtin_amdgcn_mfma_f32_16x16x32_bf16(a1, wqf[nt][1], acc, 0, 0, 0);
      #pragma unroll
      for (int q = 0; q < 4; q++) qn[nt][q] = acc[q] + bq[nt];
    }
    #pragma unroll
    for (int nt = 0; nt < 4; nt++){
      float n0 = qn[nt][0]*qn[nt][0], n1 = qn[nt][1]*qn[nt][1];
      float n2 = qn[nt][2]*qn[nt][2], n3 = qn[nt][3]*qn[nt][3];
      #pragma unroll
      for (int o = 1; o < 16; o <<= 1){
        n0 += __shfl_xor(n0, o, 64); n1 += __shfl_xor(n1, o, 64);
        n2 += __shfl_xor(n2, o, 64); n3 += __shfl_xor(n3, o, 64);
      }
      qn[nt][0] /= fmaxf(sqrtf(n0), 1e-12f);
      qn[nt][1] /= fmaxf(sqrtf(n1), 1e-12f);
      qn[nt][2] /= fmaxf(sqrtf(n2), 1e-12f);
      qn[nt][3] /= fmaxf(sqrtf(n3), 1e-12f);
    }
    #pragma unroll
    for (int nt = 0; nt < 4; nt++)
      #pragma unroll
      for (int q = 0; q < 4; q++)
        stf(qn_out, (size_t)(row0 + lg*4 + q)*64 + lr + 16*nt, qn[nt][q]);
    return;
  }

  // ---- kvred ----
  short8v wkf[4][2];
  float bk[4];
  #pragma unroll
  for (int nt = 0; nt < 4; nt++){
    int col = 64 + lr + 16*nt;               // k-half of fc_to_qk
    bk[nt] = bias[col];
    #pragma unroll
    for (int ks = 0; ks < 2; ks++) wkf[nt][ks] = WQ[col*8 + ks*4 + lg];
  }
  int b = blockIdx.x / NBB, blk = blockIdx.x % NBB;
  unsigned short* Tw = T1[wid];
  unsigned short* Vw = T2[wid];
  floatx4 kvacc[4] = {zz, zz, zz, zz};
  float ksp[4] = {0.f,0.f,0.f,0.f};
  float vsp[4] = {0.f,0.f,0.f,0.f};
  for (int st = blk*4 + wid; st < 1250; st += NBB*4){
    size_t gr = (size_t)b*VDIM + (size_t)st*16;
    #pragma unroll
    for (int it = 0; it < 4; it++){
      int rl = it*4 + lg;
      size_t gi = (gr + rl)*64 + 4*lr;
      ushort4 tq = *(const ushort4*)(Xqk + gi);
      ushort4 tv = *(const ushort4*)(Xv + gi);
      int si = swz(rl, 4*lr);
      *(ushort4*)&Tw[si] = tq;
      *(ushort4*)&Vw[si] = tv;
      vsp[0] += b2f(tv.x); vsp[1] += b2f(tv.y); vsp[2] += b2f(tv.z); vsp[3] += b2f(tv.w);
    }
    wsync();
    short8v a0 = *(const short8v*)&Tw[swz(lr, lg*8)];
    short8v a1 = *(const short8v*)&Tw[swz(lr, 32 + lg*8)];
    // k-projection + head norm -> kn (C-layout regs), store kn_t to T1
    float kn[4][4];
    #pragma unroll
    for (int nt = 0; nt < 4; nt++){
      floatx4 acc = zz;
      acc = __builtin_amdgcn_mfma_f32_16x16x32_bf16(a0, wkf[nt][0], acc, 0, 0, 0);
      acc = __builtin_amdgcn_mfma_f32_16x16x32_bf16(a1, wkf[nt][1], acc, 0, 0, 0);
      #pragma unroll
      for (int q = 0; q < 4; q++) kn[nt][q] = acc[q] + bk[nt];
    }
    #pragma unroll
    for (int nt = 0; nt < 4; nt++){
      float n0 = kn[nt][0]*kn[nt][0], n1 = kn[nt][1]*kn[nt][1];
      float n2 = kn[nt][2]*kn[nt][2], n3 = kn[nt][3]*kn[nt][3];
      #pragma unroll
      for (int o = 1; o < 16; o <<= 1){
        n0 += __shfl_xor(n0, o, 64); n1 += __shfl_xor(n1, o, 64);
        n2 += __shfl_xor(n2, o, 64); n3 += __shfl_xor(n3, o, 64);
      }
      kn[nt][0] /= fmaxf(sqrtf(n0), 1e-12f);
      kn[nt][1] /= fmaxf(sqrtf(n1), 1e-12f);
      kn[nt][2] /= fmaxf(sqrtf(n2), 1e-12f);
      kn[nt][3] /= fmaxf(sqrtf(n3), 1e-12f);
      ksp[nt] += kn[nt][0] + kn[nt][1] + kn[nt][2] + kn[nt][3];
    }
    wsync();   // a0/a1 consumed; safe to overwrite T1 with kn_t
    #pragma unroll
    for (int nt = 0; nt < 4; nt++){
      int c = lr + 16*nt;
      #pragma unroll
      for (int q = 0; q < 4; q++)
        Tw[c*16 + lg*4 + q] = f2b(kn[nt][q]);
    }
    wsync();
    // kv += kn^T (A) x vx (B), per head, K=16 rows zero-padded to 32
    #pragma unroll
    for (int nt = 0; nt < 4; nt++){
      short8v af = z8, bf = z8;
      if (lg < 2){
        af = *(const short8v*)&Tw[(nt*16 + lr)*16 + lg*8];
        #pragma unroll
        for (int j = 0; j < 8; j++)
          bf[j] = (short)Vw[swz(lg*8 + j, nt*16 + lr)];
      }
      kvacc[nt] = __builtin_amdgcn_mfma_f32_16x16x32_bf16(af, bf, kvacc[nt], 0, 0, 0);
    }
    wsync();   // LDS reads done before next stripe overwrites tiles
  }
  // write per-wave partials
  float* rw = red + wid*1536;
  #pragma unroll
  for (int nt = 0; nt < 4; nt++){
    #pragma unroll
    for (int q = 0; q < 4; q++)
      rw[(nt*16 + lg*4 + q)*16 + lr] = kvacc[nt][q];
    rw[1024 + lg*64 + lr + 16*nt] = ksp[nt];
  }
  #pragma unroll
  for (int m = 0; m < 4; m++)
    rw[1280 + lg*64 + 4*lr + m] = vsp[m];
  __syncthreads();
  float* P = partial + (size_t)blockIdx.x*1152;
  for (int j = tid; j < 1152; j += 256){
    float s = 0.f;
    if (j < 1024){
      #pragma unroll
      for (int wv = 0; wv < 4; wv++) s += red[wv*1536 + j];
    } else if (j < 1088){
      int c = j - 1024;
      #pragma unroll
      for (int wv = 0; wv < 4; wv++)
        #pragma unroll
        for (int gg = 0; gg < 4; gg++) s += red[wv*1536 + 1024 + gg*64 + c];
    } else {
      int c = j - 1088;
      #pragma unroll
      for (int wv = 0; wv < 4; wv++)
        #pragma unroll
        for (int gg = 0; gg < 4; gg++) s += red[wv*1536 + 1280 + gg*64 + c];
    }
    P[j] = s;
  }
}

// ---- reduce kvred partials; also emit bf16 copies for attn fragments ----
__global__ void qkred_kernel(const float* __restrict__ partial,
                             float* __restrict__ kvs, float* __restrict__ ksum, float* __restrict__ vsum,
                             unsigned short* __restrict__ kvsb, unsigned short* __restrict__ ksb){
  int b = blockIdx.x / 5, ch = blockIdx.x % 5;
  int j = ch*256 + threadIdx.x;
  if (j >= 1152) return;
  const float* P = partial + (size_t)b*NBB*1152;
  float s = 0.f;
  for (int t = 0; t < NBB; t++) s += P[(size_t)t*1152 + j];
  if (j < 1024){      kvs[b*1024 + j] = s; kvsb[b*1024 + j] = f2b(s); }
  else if (j < 1088){ ksum[b*64 + (j-1024)] = s; ksb[b*64 + (j-1024)] = f2b(s); }
  else                vsum[b*64 + (j-1088)] = s;
}

// ---- fused attention + final FFN, 2 tiles/block; qn precomputed (no q-proj) ----
__global__ __launch_bounds__(256) void attn_final_kernel(
    const float* __restrict__ x, const bf16* __restrict__ QN, const bf16* __restrict__ Xv,
    const unsigned short* __restrict__ kvsb, const unsigned short* __restrict__ ksb,
    const float* __restrict__ vsum,
    const unsigned short* __restrict__ wb,
    const float* __restrict__ ag, const float* __restrict__ ab,
    const float* __restrict__ fb1, const float* __restrict__ fb2,
    const float* __restrict__ g, const float* __restrict__ bb,
    float* __restrict__ out){
  __shared__ unsigned short Ql[4][2048];
  __shared__ unsigned short Hl[4][1024];
  int tid = threadIdx.x, lane = tid & 63, wid = tid >> 6;
  int lr = lane & 15, lg = lane >> 4;
  // FFN weights (bf16 direct)
  short8v f1f[4][2], f2f[4][2];
  float agl[4], abl[4], b1l[4], b2l[4], gl[4], bl[4];
  const short8v* W1 = (const short8v*)(wb + WB_FW1);
  const short8v* W2 = (const short8v*)(wb + WB_FW2);
  #pragma unroll
  for (int nt = 0; nt < 4; nt++){
    int col = lr + 16*nt;
    agl[nt] = ag[col]; abl[nt] = ab[col];
    b1l[nt] = fb1[col]; b2l[nt] = fb2[col]; gl[nt] = g[col]; bl[nt] = bb[col];
    #pragma unroll
    for (int ks = 0; ks < 2; ks++){
      f1f[nt][ks] = W1[col*8 + ks*4 + lg];
      f2f[nt][ks] = W2[col*8 + ks*4 + lg];
    }
  }
  unsigned short* Qw = Ql[wid];
  unsigned short* Hw = Hl[wid];
  floatx4 zz = {0.f, 0.f, 0.f, 0.f};
  const short8v z8 = {0,0,0,0,0,0,0,0};
  int t0 = blockIdx.x*2;
  // stage both qn tiles (already bf16)
  #pragma unroll
  for (int tt = 0; tt < 2; tt++){
    int row0 = (t0 + tt)*64 + wid*16;
    #pragma unroll
    for (int it = 0; it < 4; it++){
      int rl = it*4 + lg;
      size_t gi = (size_t)(row0 + rl)*64 + 4*lr;
      *(ushort4*)&Qw[tt*1024 + swz(rl, 4*lr)] = *(const ushort4*)(QN + gi);
    }
  }
  wsync();
  #pragma unroll
  for (int tt = 0; tt < 2; tt++){
    int row0 = (t0 + tt)*64 + wid*16;
    int b = row0 / VDIM;                     // wave-uniform (16 | 20000)
    // per-head attention: num/den via zero-padded 16x16x32 MFMAs; kv frags from global
    float y[4][4];
    float s[4] = {0.f,0.f,0.f,0.f}, ss[4] = {0.f,0.f,0.f,0.f};
    #pragma unroll
    for (int nt = 0; nt < 4; nt++){
      short8v af = z8, bn = z8, bd = z8;
      if (lg < 2){
        af = *(const short8v*)&Qw[tt*1024 + swz(lr, nt*16 + lg*8)];
        bd = *(const short8v*)&ksb[b*64 + nt*16 + lg*8];
        #pragma unroll
        for (int j = 0; j < 8; j++)
          bn[j] = (short)kvsb[b*1024 + (nt*16 + lg*8 + j)*16 + lr];
      }
      int c = lr + 16*nt;
      float vsb = vsum[b*64 + c];
      floatx4 numc, denc;
      #pragma unroll
      for (int q = 0; q < 4; q++){
        float vv = ldf(Xv, (size_t)(row0 + lg*4 + q)*64 + c);
        numc[q] = vsb + vv*(float)VDIM;
        denc[q] = 2.0f*(float)VDIM;
      }
      numc = __builtin_amdgcn_mfma_f32_16x16x32_bf16(af, bn, numc, 0, 0, 0);
      denc = __builtin_amdgcn_mfma_f32_16x16x32_bf16(af, bd, denc, 0, 0, 0);
      #pragma unroll
      for (int q = 0; q < 4; q++){
        float xv = x[(size_t)(row0 + lg*4 + q)*64 + c];
        float v = xv + numc[q]/denc[q];
        y[nt][q] = v; s[q] += v; ss[q] += v*v;
      }
    }
    #pragma unroll
    for (int o = 1; o < 16; o <<= 1){
      #pragma unroll
      for (int q = 0; q < 4; q++){
        s[q] += __shfl_xor(s[q], o, 64);
        ss[q] += __shfl_xor(ss[q], o, 64);
      }
    }
    #pragma unroll
    for (int q = 0; q < 4; q++){
      float mu = s[q]*(1.f/64.f);
      float var = fmaxf(ss[q]*(1.f/64.f) - mu*mu, 0.f);
      float rs = rsqrtf(var + LN_EPS);
      #pragma unroll
      for (int nt = 0; nt < 4; nt++)
        y[nt][q] = (y[nt][q] - mu)*rs*agl[nt] + abl[nt];
    }
    // FFN + LN2 (residual y in regs)
    wsync();   // per-head Qw reads done; overwrite tile-tt with xa
    #pragma unroll
    for (int nt = 0; nt < 4; nt++){
      #pragma unroll
      for (int q = 0; q < 4; q++)
        Qw[tt*1024 + swz(lg*4 + q, lr + 16*nt)] = f2b(y[nt][q]);
    }
    wsync();
    short8v xa0 = *(const short8v*)&Qw[tt*1024 + swz(lr, lg*8)];
    short8v xa1 = *(const short8v*)&Qw[tt*1024 + swz(lr, 32 + lg*8)];
    #pragma unroll
    for (int nt = 0; nt < 4; nt++){
      floatx4 acc = zz;
      acc = __builtin_amdgcn_mfma_f32_16x16x32_bf16(xa0, f1f[nt][0], acc, 0, 0, 0);
      acc = __builtin_amdgcn_mfma_f32_16x16x32_bf16(xa1, f1f[nt][1], acc, 0, 0, 0);
      #pragma unroll
      for (int q = 0; q < 4; q++)
        Hw[swz(lg*4 + q, lr + 16*nt)] = f2b(fmaxf(acc[q] + b1l[nt], 0.f));
    }
    wsync();
    short8v h0 = *(const short8v*)&Hw[swz(lr, lg*8)];
    short8v h1 = *(const short8v*)&Hw[swz(lr, 32 + lg*8)];
    float t[4][4];
    float s2[4] = {0.f,0.f,0.f,0.f}, ss2[4] = {0.f,0.f,0.f,0.f};
    #pragma unroll
    for (int nt = 0; nt < 4; nt++){
      floatx4 acc = zz;
      acc = __builtin_amdgcn_mfma_f32_16x16x32_bf16(h0, f2f[nt][0], acc, 0, 0, 0);
      acc = __builtin_amdgcn_mfma_f32_16x16x32_bf16(h1, f2f[nt][1], acc, 0, 0, 0);
      #pragma unroll
      for (int q = 0; q < 4; q++){
        float v = acc[q] + b2l[nt] + y[nt][q];
        t[nt][q] = v; s2[q] += v; ss2[q] += v*v;
      }
    }
    #pragma unroll
    for (int o = 1; o < 16; o <<= 1){
      #pragma unroll
      for (int q = 0; q < 4; q++){
        s2[q] += __shfl_xor(s2[q], o, 64);
        ss2[q] += __shfl_xor(ss2[q], o, 64);
      }
    }
    #pragma unroll
    for (int q = 0; q < 4; q++){
      float mu = s2[q]*(1.f/64.f);
      float var = fmaxf(ss2[q]*(1.f/64.f) - mu*mu, 0.f);
      float rs = rsqrtf(var + LN_EPS);
      #pragma unroll
      for (int nt = 0; nt < 4; nt++){
        int c = lr + 16*nt;
        out[(size_t)(row0 + lg*4 + q)*64 + c] = (t[nt][q] - mu)*rs*gl[nt] + bl[nt];
      }
    }
    wsync();   // Hw reused by next tile
  }
}

// ================= host side =================
static const int DICT_SIZES[42] = {
  5120000,256,256,80000,262144,4096,4160,64,4096,64,
  8192,64,4096,64,8192,128,8192,128,8192,128,
  128,128,128,524288,8192,8192,128,8192,128,128,
  128,128,4096,64,4096,64,64,64,64,64,
  4,600000};

static void run_pipeline(const float* const* N, const int* hi,
                         const int* ei_raw, const int* eflag,
                         int* cursor, int2* pk, const int* row_ptr,
                         float* qk_z, float* zr, float* kvs, float* part,
                         unsigned short* kvsb, unsigned short* wb, float* rsvb,
                         bf16* A, bf16* B, bf16* OA, bf16* OB, bool dual,
                         float* outp, hipStream_t stream){
  float* ksum = kvs + 4096;
  float* vsum = kvs + 4352;
  unsigned short* ksb = kvsb + 4096;

  // fused: scatter (needs scan done) + init_both (independent) in one dispatch
  scatter_init_kernel<<<NSC + NDB, 256, 0, stream>>>(ei_raw, eflag, cursor, pk,
      N[0], N[3], hi, wb, rsvb, N[6], N[7], N[9], N[11], N[13], A, B);

  if (dual){
    for (int i = 0; i < 2; i++){
      rspmm_dual<<<2*NRB2, 256, 0, stream>>>(row_ptr, pk, qk_z, zr + i*16384, A, B, OA, OB);
      loop_dual_kernel<<<2*NDB, 256, 0, stream>>>(OA, A, OB, B,
          N[20] + i*64, wb + WB_QKW1 + i*4096, N[17] + i*64, wb + WB_QKW2 + i*4096, N[19] + i*64, N[21] + i*64, N[22] + i*64,
          N[29] + i*64, wb + WB_VW1 + i*4096, N[26] + i*64, wb + WB_VW2 + i*4096, N[28] + i*64, N[30] + i*64, N[31] + i*64);
    }
  } else {
    for (int i = 0; i < 2; i++){
      rspmm_dual<<<NRB2, 256, 0, stream>>>(row_ptr, pk, qk_z, qk_z, A, A, OA, OA);
      loop_dual_kernel<<<NDB, 256, 0, stream>>>(OA, A, OA, A,
          N[20] + i*64, wb + WB_QKW1 + i*4096, N[17] + i*64, wb + WB_QKW2 + i*4096, N[19] + i*64, N[21] + i*64, N[22] + i*64,
          N[20] + i*64, wb + WB_QKW1 + i*4096, N[17] + i*64, wb + WB_QKW2 + i*4096, N[19] + i*64, N[21] + i*64, N[22] + i*64);
    }
    for (int i = 0; i < 2; i++){
      rspmm_dual<<<NRB2, 256, 0, stream>>>(row_ptr, pk, zr + i*16384, zr + i*16384, B, B, OA, OA);
      loop_dual_kernel<<<NDB, 256, 0, stream>>>(OA, B, OA, B,
          N[29] + i*64, wb + WB_VW1 + i*4096, N[26] + i*64, wb + WB_VW2 + i*4096, N[28] + i*64, N[30] + i*64, N[31] + i*64,
          N[29] + i*64, wb + WB_VW1 + i*4096, N[26] + i*64, wb + WB_VW2 + i*4096, N[28] + i*64, N[30] + i*64, N[31] + i*64);
    }
  }

  // kvred + q-projection (independent block ranges) in one dispatch; qn -> OA (free)
  kvred_qproj_kernel<<<NKV + NTILE, 256, 0, stream>>>(A, B, wb, N[15], part, OA);
  qkred_kernel<<<20, 256, 0, stream>>>(part, kvs, ksum, vsum, kvsb, ksb);
  attn_final_kernel<<<NDB, 256, 0, stream>>>(N[0], OA, B, kvsb, ksb, vsum,
      wb, N[36], N[37], N[33], N[35], N[38], N[39], outp);
}

extern "C" void kernel_launch(void* const* d_in, const int* in_sizes, int n_in,
                              void* d_out, int out_size, void* d_ws, size_t ws_size,
                              hipStream_t stream){
  float* outp = (float*)d_out;
  const int GOUT = (out_size + 255) / 256;

  if (n_in != 42){
    fill_kernel<<<GOUT, 256, 0, stream>>>(outp, 2000.0f + (float)n_in, out_size);
    return;
  }
  auto sz_ok = [&](int s, int e)->bool{
    if (s == e) return true;
    if ((e == 4 || e == 600000) && s == 2*e) return true;
    return false;
  };
  int bad = -1;
  for (int i = 0; i < 42 && bad < 0; i++)
    if (!sz_ok(in_sizes[i], DICT_SIZES[i])) bad = i;
  if (bad >= 0){
    fill_kernel<<<GOUT, 256, 0, stream>>>(outp, 1000.0f + (float)bad, out_size);
    return;
  }

  const float* N[40];
  for (int i = 0; i < 40; i++) N[i] = (const float*)d_in[i];
  const int* hi_raw = (const int*)d_in[40];
  const int* ei_raw = (const int*)d_in[41];

  char* p = (char*)d_ws;
  auto alloc = [&](size_t bytes)->char*{ char* r = p; p += (bytes + 255) / 256 * 256; return r; };
  int* hi      = (int*)alloc(256);
  int* eflag   = (int*)alloc(256);
  int* counts  = (int*)alloc((VDIM+1)*4);
  int* row_ptr = (int*)alloc((VDIM+1)*4);
  int* cursor  = (int*)alloc((VDIM+1)*4);
  int2* pk     = (int2*)alloc((size_t)EDIM*8);
  float* qk_z  = (float*)alloc(16384u*4);
  float* zr    = (float*)alloc(32768u*4);
  float* kvs   = (float*)alloc(4608u*4);
  unsigned short* kvsb = (unsigned short*)alloc(4352u*2);
  unsigned short* wb   = (unsigned short*)alloc((size_t)WB_TOT*2);
  float* rsvb  = (float*)alloc(64*4);
  float* part  = (float*)alloc((size_t)BDIM*NBB*1152*4);
  size_t fixed = (size_t)(p - (char*)d_ws);
  const size_t bufH = (size_t)BV*64*2;

  // setup: detect64 + zero counts + zcalc + weight bf16 conversion, one dispatch
  setup_kernel<<<273 + (WC_TOT+255)/256, 256, 0, stream>>>(ei_raw, eflag, counts,
      N[1], N[4], N[5], N[23], N[24], qk_z, zr,
      N[16], N[18], N[25], N[27], N[6], N[8], N[10], N[12], N[14], N[32], N[34],
      wb, rsvb);
  prep_count_kernel<<<(EDIM+255)/256, 256, 0, stream>>>(ei_raw, hi_raw, eflag, hi, counts);
  scan_kernel<<<1, 256, 0, stream>>>(counts, row_ptr, cursor);

  // bf16 workspace: halves intermediate traffic, makes rspmm X L2-resident.
  if (ws_size >= fixed + 4*bufH + 1024){
    bf16* A  = (bf16*)alloc(bufH);
    bf16* B  = (bf16*)alloc(bufH);
    bf16* OA = (bf16*)alloc(bufH);
    bf16* OB = (bf16*)alloc(bufH);
    run_pipeline(N, hi, ei_raw, eflag, cursor, pk, row_ptr,
                 qk_z, zr, kvs, part, kvsb, wb, rsvb, A, B, OA, OB, true, outp, stream);
  } else {
    bf16* A  = (bf16*)alloc(bufH);
    bf16* B  = (bf16*)alloc(bufH);
    bf16* OA = (bf16*)alloc(bufH);
    run_pipeline(N, hi, ei_raw, eflag, cursor, pk, row_ptr,
                 qk_z, zr, kvs, part, kvsb, wb, rsvb, A, B, OA, OA, false, outp, stream);
  }
}